// Round 14
// baseline (198.378 us; speedup 1.0000x reference)
//
#include <hip/hip_runtime.h>
#include <math.h>

// Problem dims
#define Bn 8
#define Cn 64
#define Hn 128
#define Wn 128
#define HWn 16384

typedef __attribute__((ext_vector_type(8))) __bf16 bf16x8;
typedef __attribute__((ext_vector_type(4))) __bf16 bf16x4;
typedef __attribute__((ext_vector_type(4))) float f32x4;

// XCD-aware bijective swizzle: grid = 8*chunk blocks.
__device__ __forceinline__ int xcd_swz(int bid, int chunk) {
  return (bid & 7) * chunk + (bid >> 3);
}

// ---------------------------------------------------------------------------
// K-wprep: merged weight prep — wfrag + dcnD + weffD + w2frag + beff.
// ---------------------------------------------------------------------------
__global__ __launch_bounds__(256) void k_wprep(
    const float* __restrict__ stn_w1, const float* __restrict__ dcn_w,
    const float* __restrict__ w1, const float* __restrict__ w3,
    const float* __restrict__ w15, const float* __restrict__ w51,
    const float* __restrict__ stn_w2,
    const float* __restrict__ b3, const float* __restrict__ b15,
    const float* __restrict__ b51, const float* __restrict__ b1,
    __bf16* __restrict__ wfrag, __bf16* __restrict__ dcnD,
    __bf16* __restrict__ weffD, __bf16* __restrict__ w2frag,
    float* __restrict__ beff)
{
  int t = blockIdx.x * 256 + threadIdx.x;
  if (t < 100352) {                       // conv1 A-frags
    int e = t & 7, l = (t >> 3) & 63, o16 = (t >> 9) & 1, ck = (t >> 10) & 1;
    int tap = t >> 11;
    int o = o16 * 16 + (l & 15), c = ck * 32 + (l >> 4) * 8 + e;
    wfrag[t] = (__bf16)stn_w1[(o * 64 + c) * 49 + tap];
    return;
  }
  t -= 100352;
  if (t < 36864) {                        // dcn B-frags
    int e = t & 7, l = (t >> 3) & 63, mf = (t >> 9) & 3, s = (t >> 11) & 1;
    int tap = t >> 12;
    int o = mf * 16 + (l & 15), c = s * 32 + (l >> 4) * 8 + e;
    dcnD[t] = (__bf16)dcn_w[(o * 64 + c) * 9 + tap];
    return;
  }
  t -= 36864;
  if (t < 53248) {                        // collapsed ELK B-frags
    const int DY[13] = {-2,-1,-1,-1, 0, 0, 0, 0, 0, 1, 1, 1, 2};
    const int DX[13] = { 0,-1, 0, 1,-2,-1, 0, 1, 2,-1, 0, 1, 0};
    int e = t & 7, l = (t >> 3) & 63, mf = (t >> 9) & 3, s = (t >> 11) & 1;
    int tap = t >> 12;
    int o = mf * 16 + (l & 15), c = s * 32 + (l >> 4) * 8 + e;
    int dy = DY[tap], dx = DX[tap];
    float v = 0.f;
    if (dy >= -1 && dy <= 1 && dx >= -1 && dx <= 1) {
      int k3 = (dy + 1) * 3 + (dx + 1);
      for (int m = 0; m < 64; m++) v = fmaf(w1[o * 192 + m], w3[(m * 64 + c) * 9 + k3], v);
    }
    if (dy == 0) {
      int k15 = dx + 2;
      for (int m = 0; m < 64; m++) v = fmaf(w1[o * 192 + 64 + m], w15[(m * 64 + c) * 5 + k15], v);
    }
    if (dx == 0) {
      int k51 = dy + 2;
      for (int m = 0; m < 64; m++) v = fmaf(w1[o * 192 + 128 + m], w51[(m * 64 + c) * 5 + k51], v);
    }
    weffD[t] = (__bf16)v;
    return;
  }
  t -= 53248;
  if (t < 51200) {                        // conv2 A-frags
    int e = t & 7, l = (t >> 3) & 63, mf = (t >> 9) & 3;
    int tap = t >> 11;
    int o = mf * 16 + (l & 15), c = (l >> 4) * 8 + e;
    w2frag[t] = (__bf16)stn_w2[(o * 32 + c) * 25 + tap];
    return;
  }
  t -= 51200;
  if (t < 64) {                           // beff
    float s = b1[t];
    for (int m = 0; m < 64; m++) {
      s = fmaf(w1[t * 192 + m],       b3[m],  s);
      s = fmaf(w1[t * 192 + 64 + m],  b15[m], s);
      s = fmaf(w1[t * 192 + 128 + m], b51[m], s);
    }
    beff[t] = s;
  }
}

// ---------------------------------------------------------------------------
// K-xt v2: thread per (pixel, channel-half), 32 loads unrolled to regs.
// ---------------------------------------------------------------------------
__global__ __launch_bounds__(256) void k_xt(const float* __restrict__ x,
                                            __bf16* __restrict__ xT,
                                            __bf16* __restrict__ xC)
{
  int t = blockIdx.x * 256 + threadIdx.x;
  if (t >= 8 * 134 * 134 * 2) return;
  int half = t & 1;
  int p  = t >> 1;
  int wp = p % 134;
  int hp = (p / 134) % 134;
  int b  = p / (134 * 134);
  int h = hp - 3, w = wp - 3;
  bool inb = ((unsigned)h < 128u) && ((unsigned)w < 128u);
  const float* xb = x + (size_t)b * Cn * HWn + (size_t)(half * 32) * HWn + h * 128 + w;

  float v[32];
#pragma unroll
  for (int j = 0; j < 32; j++) v[j] = inb ? xb[(size_t)j * HWn] : 0.f;

  __bf16* dstT = xT + (size_t)p * 64 + half * 32;
#pragma unroll
  for (int g = 0; g < 4; g++) {
    bf16x8 r;
#pragma unroll
    for (int j = 0; j < 8; j++) r[j] = (__bf16)v[g * 8 + j];
    *(bf16x8*)(dstT + g * 8) = r;
    int oct = half * 4 + g;
    *(bf16x8*)(xC + ((((size_t)b * 8 + oct) * 134 + hp) * 144 + wp) * 8) = r;
  }
}

// ---------------------------------------------------------------------------
// K1: STN conv1 via MFMA — 4 waves/block, wave = 32 out x 64 px (half row).
// ---------------------------------------------------------------------------
__global__ __launch_bounds__(256) void k_conv1m(
    const __bf16* __restrict__ xC, const __bf16* __restrict__ wfrag,
    const float* __restrict__ b1s, __bf16* __restrict__ t1T)
{
  __shared__ alignas(16) char tile[73728];   // [q4][r8][slot144][16B]
  const int lane = threadIdx.x & 63;
  const int wv   = threadIdx.x >> 6;
  const int swz  = xcd_swz(blockIdx.x, 64);
  const int b    = swz >> 6;
  const int h0   = (swz & 63) * 2;
  const int r    = wv >> 1;
  const int hf   = wv & 1;

  f32x4 acc[2][4];
#pragma unroll
  for (int o16 = 0; o16 < 2; o16++)
#pragma unroll
    for (int nf = 0; nf < 4; nf++) acc[o16][nf] = (f32x4){0.f, 0.f, 0.f, 0.f};

  const bf16x8* wf = (const bf16x8*)wfrag;
  const char* tb = (const char*)tile;
  const char* xCb = (const char*)xC;

  for (int ck = 0; ck < 2; ck++) {
    for (int i = wv; i < 72; i += 4) {
      int q = i / 18;
      int t = i - q * 18;
      const char* src = xCb
          + (((size_t)(b * 8 + ck * 4 + q) * 134 + h0) * 2304) + t * 1024 + lane * 16;
      char* dst = (char*)tile + i * 1024;
      __builtin_amdgcn_global_load_lds(
          (const __attribute__((address_space(1))) void*)src,
          (__attribute__((address_space(3))) void*)dst, 16, 0, 0);
    }
    __syncthreads();

    for (int tap = 0; tap < 49; tap++) {
      int dy7 = tap / 7;
      int dx7 = tap - dy7 * 7;
      bf16x8 a0 = wf[((tap * 2 + ck) * 2 + 0) * 64 + lane];
      bf16x8 a1 = wf[((tap * 2 + ck) * 2 + 1) * 64 + lane];
      const char* bp = tb + (lane >> 4) * 18432 + (r + dy7) * 2304
                          + (dx7 + hf * 64 + (lane & 15)) * 16;
#pragma unroll
      for (int nf = 0; nf < 4; nf++) {
        bf16x8 bv = *(const bf16x8*)(bp + nf * 256);
        acc[0][nf] = __builtin_amdgcn_mfma_f32_16x16x32_bf16(a0, bv, acc[0][nf], 0, 0, 0);
        acc[1][nf] = __builtin_amdgcn_mfma_f32_16x16x32_bf16(a1, bv, acc[1][nf], 0, 0, 0);
      }
    }
    __syncthreads();
  }

  int h = h0 + r;
#pragma unroll
  for (int o16 = 0; o16 < 2; o16++) {
    int ob = o16 * 16 + ((lane >> 4) << 2);
    float bb0 = b1s[ob], bb1 = b1s[ob + 1], bb2 = b1s[ob + 2], bb3 = b1s[ob + 3];
#pragma unroll
    for (int nf = 0; nf < 4; nf++) {
      int px = hf * 64 + nf * 16 + (lane & 15);
      bf16x4 rr;
      rr[0] = (__bf16)fmaxf(acc[o16][nf][0] + bb0, 0.f);
      rr[1] = (__bf16)fmaxf(acc[o16][nf][1] + bb1, 0.f);
      rr[2] = (__bf16)fmaxf(acc[o16][nf][2] + bb2, 0.f);
      rr[3] = (__bf16)fmaxf(acc[o16][nf][3] + bb3, 0.f);
      *(bf16x4*)(t1T + (((size_t)(b * 128 + h) * 128 + px)) * 32 + ob) = rr;
    }
  }
}

// ---------------------------------------------------------------------------
// K2: maxpool 2x2 -> p1T[b][hp68][wp68][32ch] bf16, zero-padded 2 ring.
// ---------------------------------------------------------------------------
__global__ __launch_bounds__(256) void k_pool(const __bf16* __restrict__ t1T,
                                              __bf16* __restrict__ p1T)
{
  int id = blockIdx.x * 256 + threadIdx.x;
  if (id >= 8 * 68 * 68) return;
  int wp = id % 68, hp = (id / 68) % 68, b = id / (68 * 68);
  __bf16* dst = p1T + (size_t)id * 32;
  int ph = hp - 2, pw = wp - 2;
  if (((unsigned)ph >= 64u) || ((unsigned)pw >= 64u)) {
    bf16x8 z = {};
#pragma unroll
    for (int g = 0; g < 4; g++) *(bf16x8*)(dst + g * 8) = z;
    return;
  }
  const __bf16* s = t1T + (((size_t)(b * 128) + ph * 2) * 128 + pw * 2) * 32;
#pragma unroll
  for (int g = 0; g < 4; g++) {
    bf16x8 v0 = *(const bf16x8*)(s + g * 8);
    bf16x8 v1 = *(const bf16x8*)(s + 32 + g * 8);
    bf16x8 v2 = *(const bf16x8*)(s + 4096 + g * 8);
    bf16x8 v3 = *(const bf16x8*)(s + 4128 + g * 8);
    bf16x8 r;
#pragma unroll
    for (int j = 0; j < 8; j++) {
      float m = fmaxf(fmaxf((float)v0[j], (float)v1[j]),
                      fmaxf((float)v2[j], (float)v3[j]));
      r[j] = (__bf16)m;
    }
    *(bf16x8*)(dst + g * 8) = r;
  }
}

// ---------------------------------------------------------------------------
// K3: conv2 via MFMA.
// ---------------------------------------------------------------------------
__global__ __launch_bounds__(256) void k_conv2m(
    const __bf16* __restrict__ p1T, const __bf16* __restrict__ w2frag,
    const float* __restrict__ b2s, float* __restrict__ t2)
{
  __shared__ alignas(16) char tile[34816];   // 8*68*64
  const int lane = threadIdx.x & 63;
  const int wv   = threadIdx.x >> 6;
  const int b    = blockIdx.x >> 4;
  const int h0   = (blockIdx.x & 15) * 4;

  f32x4 acc[4][4];
#pragma unroll
  for (int mf = 0; mf < 4; mf++)
#pragma unroll
    for (int nf = 0; nf < 4; nf++) acc[mf][nf] = (f32x4){0.f, 0.f, 0.f, 0.f};

  const char* src0 = (const char*)p1T + (((size_t)b * 68 + h0) * 68) * 64;
  for (int i = wv; i < 34; i += 4) {
    __builtin_amdgcn_global_load_lds(
        (const __attribute__((address_space(1))) void*)(src0 + i * 1024 + lane * 16),
        (__attribute__((address_space(3))) void*)((char*)tile + i * 1024), 16, 0, 0);
  }
  __syncthreads();

  const bf16x8* wf = (const bf16x8*)w2frag;
  const char* tb = (const char*)tile;
  for (int tap = 0; tap < 25; tap++) {
    int ky = tap / 5, kx = tap - ky * 5;
    bf16x8 a0 = wf[(tap * 4 + 0) * 64 + lane];
    bf16x8 a1 = wf[(tap * 4 + 1) * 64 + lane];
    bf16x8 a2 = wf[(tap * 4 + 2) * 64 + lane];
    bf16x8 a3 = wf[(tap * 4 + 3) * 64 + lane];
    const char* bp = tb + (((wv + ky) * 68 + kx + (lane & 15)) * 64) + (lane >> 4) * 16;
#pragma unroll
    for (int nf = 0; nf < 4; nf++) {
      bf16x8 bv = *(const bf16x8*)(bp + nf * 1024);
      acc[0][nf] = __builtin_amdgcn_mfma_f32_16x16x32_bf16(a0, bv, acc[0][nf], 0, 0, 0);
      acc[1][nf] = __builtin_amdgcn_mfma_f32_16x16x32_bf16(a1, bv, acc[1][nf], 0, 0, 0);
      acc[2][nf] = __builtin_amdgcn_mfma_f32_16x16x32_bf16(a2, bv, acc[2][nf], 0, 0, 0);
      acc[3][nf] = __builtin_amdgcn_mfma_f32_16x16x32_bf16(a3, bv, acc[3][nf], 0, 0, 0);
    }
  }

  int h = h0 + wv;
#pragma unroll
  for (int mf = 0; mf < 4; mf++) {
    int ob = mf * 16 + ((lane >> 4) << 2);
#pragma unroll
    for (int r = 0; r < 4; r++) {
      float bb = b2s[ob + r];
      float* orow = t2 + ((size_t)(b * 64 + ob + r)) * 4096 + h * 64 + (lane & 15);
#pragma unroll
      for (int nf = 0; nf < 4; nf++)
        orow[nf * 16] = fmaxf(acc[mf][nf][r] + bb, 0.f);
    }
  }
}

// ---------------------------------------------------------------------------
// K3b: deterministic spatial sum -> feat[b*64+co].
// ---------------------------------------------------------------------------
__global__ __launch_bounds__(256) void k_feat(const float* __restrict__ t2, float* __restrict__ feat)
{
  __shared__ float red[256];
  int bc = blockIdx.x;
  const float* s = t2 + (size_t)bc * 4096;
  float v = 0.f;
  for (int i = threadIdx.x; i < 4096; i += 256) v += s[i];
  red[threadIdx.x] = v;
  __syncthreads();
  for (int st = 128; st > 0; st >>= 1) {
    if (threadIdx.x < st) red[threadIdx.x] += red[threadIdx.x + st];
    __syncthreads();
  }
  if (threadIdx.x == 0) feat[bc] = red[0];
}

// ---------------------------------------------------------------------------
// K4: theta
// ---------------------------------------------------------------------------
__global__ void k_theta(const float* __restrict__ feat, const float* __restrict__ fc_w,
                        const float* __restrict__ fc_b, float* __restrict__ theta)
{
  int tid = threadIdx.x;
  if (tid >= 48) return;
  int b = tid / 6, i = tid - b * 6;
  float s = 0.f;
  for (int k = 0; k < 64; k++) s = fmaf(feat[b * 64 + k], fc_w[i * 64 + k], s);
  theta[tid] = fmaf(s, 1.f / 4096.f, fc_b[i]);
}

// ---------------------------------------------------------------------------
// Shared bilinear corner-address helper (clamped + masked weights).
// ---------------------------------------------------------------------------
__device__ __forceinline__ void bilin_setup(
    const __bf16* __restrict__ xb, float sy, float sx,
    const __bf16*& c00, const __bf16*& c01,
    const __bf16*& c10, const __bf16*& c11,
    float& w00, float& w01, float& w10, float& w11)
{
  float y0f = floorf(sy), x0f = floorf(sx);
  float wy1 = sy - y0f, wy0 = 1.f - wy1;
  float wx1 = sx - x0f, wx0 = 1.f - wx1;
  bool vy0 = (y0f >= 0.f) && (y0f <= 127.f);
  bool vy1 = (y0f >= -1.f) && (y0f <= 126.f);
  bool vx0 = (x0f >= 0.f) && (x0f <= 127.f);
  bool vx1 = (x0f >= -1.f) && (x0f <= 126.f);
  int yi0 = (int)fminf(fmaxf(y0f, 0.f), 127.f);
  int yi1 = (int)fminf(fmaxf(y0f + 1.f, 0.f), 127.f);
  int xi0 = (int)fminf(fmaxf(x0f, 0.f), 127.f);
  int xi1 = (int)fminf(fmaxf(x0f + 1.f, 0.f), 127.f);
  w00 = wy0 * wx0 * ((vy0 && vx0) ? 1.f : 0.f);
  w01 = wy0 * wx1 * ((vy0 && vx1) ? 1.f : 0.f);
  w10 = wy1 * wx0 * ((vy1 && vx0) ? 1.f : 0.f);
  w11 = wy1 * wx1 * ((vy1 && vx1) ? 1.f : 0.f);
  c00 = xb + ((size_t)((yi0 + 3) * 134) + xi0 + 3) * 64;
  c01 = xb + ((size_t)((yi0 + 3) * 134) + xi1 + 3) * 64;
  c10 = xb + ((size_t)((yi1 + 3) * 134) + xi0 + 3) * 64;
  c11 = xb + ((size_t)((yi1 + 3) * 134) + xi1 + 3) * 64;
}

// ---------------------------------------------------------------------------
// K6: deformable conv + fused STN sample — R14: L2 WARM-UP PREFETCH.
// Diagnosis (R13): FETCH ~13MB/dispatch => xT is evicted between k_xt and
// dcnm; gathers are COLD (~900cy) and the per-tap chain serializes on them
// (five scheduling attacks nulled). Fix: each wave issues 18 global_load_lds
// prefetches (write-only 1KB LDS dump, zero VGPR) covering its 6-row x 24-px
// xT band BEFORE the offset loads. First vmcnt wait = one-time warm-up;
// subsequent gathers hit L2 (~200cy). Quad-coalesced gathers retained.
// ---------------------------------------------------------------------------
__global__ __launch_bounds__(64) void k_dcnm(
    const __bf16* __restrict__ xT, const float* __restrict__ off,
    const float* __restrict__ theta,
    const __bf16* __restrict__ dcnD, const float* __restrict__ dcn_b,
    __bf16* __restrict__ FdT, __bf16* __restrict__ FsT)
{
  __shared__ alignas(16) char smem[2][2048];
  __shared__ alignas(16) char dump[1024];     // prefetch sink (never read)
  const int lane = threadIdx.x;
  const int swz  = xcd_swz(blockIdx.x, 1024);
  const int b    = swz >> 10;
  const int rem  = swz & 1023;
  const int h    = rem >> 3;
  const int px0  = (rem & 7) * 16;
  const int l15  = lane & 15;
  const int g    = lane >> 4;
  const int pg   = lane >> 2;          // gather pixel 0..15
  const int q    = lane & 3;           // 16B chunk within 64B half
  const int wg   = px0 + pg;           // gather lane's pixel column

  const __bf16* xb = xT + (size_t)b * 134 * 134 * 64;

  // ---- L2 warm-up: 6 rows x 24 px band, 18 x 1KB streamed prefetches ----
  {
    int col0 = px0 + 3 - 8;
    col0 = col0 < 0 ? 0 : col0;
    if (col0 > 134 - 24) col0 = 134 - 24;
    const char* xbb = (const char*)xb;
#pragma unroll
    for (int rr = 0; rr < 6; rr++) {
      const char* rb = xbb + ((size_t)((h + 1 + rr) * 134 + col0)) * 128 + lane * 16;
#pragma unroll
      for (int i = 0; i < 3; i++) {
        __builtin_amdgcn_global_load_lds(
            (const __attribute__((address_space(1))) void*)(rb + i * 1024),
            (__attribute__((address_space(3))) void*)dump, 16, 0, 0);
      }
    }
  }

  // offsets for the gather pixel (quad-uniform -> broadcast)
  const float* ob = off + (size_t)b * 18 * HWn + h * 128 + wg;
  float offs[18];
#pragma unroll
  for (int i = 0; i < 18; i++) offs[i] = ob[(size_t)i * HWn];

  // ---- fused STN sample: blend + coalesced store to FsT ----
  {
    const float* t = theta + b * 6;
    float xn = (float)(2 * wg + 1) * (1.f / 128.f) - 1.f;
    float yn = (float)(2 * h + 1) * (1.f / 128.f) - 1.f;
    float gxv = t[0] * xn + t[1] * yn + t[2];
    float gyv = t[3] * xn + t[4] * yn + t[5];
    float ix = fmaf(gxv, 64.f, 63.5f);
    float iy = fmaf(gyv, 64.f, 63.5f);
    const __bf16 *c00, *c01, *c10, *c11;
    float w00, w01, w10, w11;
    bilin_setup(xb, iy, ix, c00, c01, c10, c11, w00, w01, w10, w11);
    __bf16* dst = FsT + ((size_t)b * HWn + h * 128 + wg) * 64;
#pragma unroll
    for (int s = 0; s < 2; s++) {
      int eo = q * 8 + s * 32;
      bf16x8 v00 = *(const bf16x8*)(c00 + eo);
      bf16x8 v01 = *(const bf16x8*)(c01 + eo);
      bf16x8 v10 = *(const bf16x8*)(c10 + eo);
      bf16x8 v11 = *(const bf16x8*)(c11 + eo);
      bf16x8 r;
#pragma unroll
      for (int j = 0; j < 8; j++) {
        float f = w00 * (float)v00[j] + w01 * (float)v01[j]
                + w10 * (float)v10[j] + w11 * (float)v11[j];
        r[j] = (__bf16)f;
      }
      *(bf16x8*)(dst + eo) = r;
    }
  }

  // ---- deformable conv: 9 taps, double-buffered LDS ----
  f32x4 acc[4];
#pragma unroll
  for (int mf = 0; mf < 4; mf++) acc[mf] = (f32x4){0.f, 0.f, 0.f, 0.f};
  const bf16x8* aD = (const bf16x8*)dcnD;

#pragma unroll
  for (int k = 0; k < 9; k++) {
    char* sm = smem[k & 1];
    float sy = (float)(h + k / 3 - 1) + offs[2 * k];
    float sx = (float)(wg + k % 3 - 1) + offs[2 * k + 1];
    const __bf16 *c00, *c01, *c10, *c11;
    float w00, w01, w10, w11;
    bilin_setup(xb, sy, sx, c00, c01, c10, c11, w00, w01, w10, w11);

    // gather (quad-coalesced), blend, LDS write (swizzled)
#pragma unroll
    for (int s = 0; s < 2; s++) {
      int eo = q * 8 + s * 32;
      bf16x8 v00 = *(const bf16x8*)(c00 + eo);
      bf16x8 v01 = *(const bf16x8*)(c01 + eo);
      bf16x8 v10 = *(const bf16x8*)(c10 + eo);
      bf16x8 v11 = *(const bf16x8*)(c11 + eo);
      bf16x8 r;
#pragma unroll
      for (int j = 0; j < 8; j++) {
        float f = w00 * (float)v00[j] + w01 * (float)v01[j]
                + w10 * (float)v10[j] + w11 * (float)v11[j];
        r[j] = (__bf16)f;
      }
      int c = s * 4 + q;
      *(bf16x8*)(sm + pg * 128 + ((c ^ (pg & 7)) * 16)) = r;
    }

    // fragment read (swizzled) + MFMA; same-wave lockstep, no barrier
#pragma unroll
    for (int s = 0; s < 2; s++) {
      int c = s * 4 + g;
      bf16x8 a = *(const bf16x8*)(sm + l15 * 128 + ((c ^ (l15 & 7)) * 16));
      acc[0] = __builtin_amdgcn_mfma_f32_16x16x32_bf16(
          a, aD[((k * 2 + s) * 4 + 0) * 64 + lane], acc[0], 0, 0, 0);
      acc[1] = __builtin_amdgcn_mfma_f32_16x16x32_bf16(
          a, aD[((k * 2 + s) * 4 + 1) * 64 + lane], acc[1], 0, 0, 0);
      acc[2] = __builtin_amdgcn_mfma_f32_16x16x32_bf16(
          a, aD[((k * 2 + s) * 4 + 2) * 64 + lane], acc[2], 0, 0, 0);
      acc[3] = __builtin_amdgcn_mfma_f32_16x16x32_bf16(
          a, aD[((k * 2 + s) * 4 + 3) * 64 + lane], acc[3], 0, 0, 0);
    }
  }

  // ---- epilogue: D row(pixel)=g*4+r, col(out)=mf*16+l15 ----
  __bf16* fb = FdT + ((size_t)b * HWn + h * 128 + px0) * 64;
#pragma unroll
  for (int mf = 0; mf < 4; mf++) {
    int o = mf * 16 + l15;
    float bias = dcn_b[o];
#pragma unroll
    for (int r = 0; r < 4; r++) {
      int pxl = g * 4 + r;
      fb[(size_t)pxl * 64 + o] = (__bf16)(acc[mf][r] + bias);
    }
  }
}

// ---------------------------------------------------------------------------
// K7: fusion -> fusedT bf16 OCTET-PLANAR [b][oct8][132][132][8ch], 2-pad ring.
// ---------------------------------------------------------------------------
#define FPL ((size_t)132 * 132 * 8)
__global__ __launch_bounds__(256) void k_fuseT(
    const __bf16* __restrict__ FsT, const __bf16* __restrict__ FdT,
    const float* __restrict__ wg_w, const float* __restrict__ wg_b,
    __bf16* __restrict__ fusedT)
{
  int id = blockIdx.x * 256 + threadIdx.x;
  if (id >= 8 * 132 * 132) return;
  int wp = id % 132;
  int hp = (id / 132) % 132;
  int b  = id / (132 * 132);
  size_t ppix = (size_t)(hp * 132 + wp) * 8;
  int h = hp - 2, w = wp - 2;
  if (((unsigned)h >= 128u) || ((unsigned)w >= 128u)) {
    bf16x8 z = {};
#pragma unroll
    for (int oct = 0; oct < 8; oct++)
      *(bf16x8*)(fusedT + ((size_t)b * 8 + oct) * FPL + ppix) = z;
    return;
  }
  const bf16x8* fs = (const bf16x8*)(FsT + ((size_t)b * HWn + h * 128 + w) * 64);
  const bf16x8* fd = (const bf16x8*)(FdT + ((size_t)b * HWn + h * 128 + w) * 64);
  bf16x8 fsv[8], fdv[8];
  float s0 = wg_b[0], s1 = wg_b[1];
#pragma unroll
  for (int oct = 0; oct < 8; oct++) {
    fsv[oct] = fs[oct];
    fdv[oct] = fd[oct];
#pragma unroll
    for (int j = 0; j < 8; j++) {
      int c = oct * 8 + j;
      float a = (float)fsv[oct][j], d = (float)fdv[oct][j];
      s0 = fmaf(wg_w[c],       a, fmaf(wg_w[64 + c],  d, s0));
      s1 = fmaf(wg_w[128 + c], a, fmaf(wg_w[192 + c], d, s1));
    }
  }
  float p0 = 1.f / (1.f + __expf(s1 - s0));
  float p1 = 1.f - p0;
#pragma unroll
  for (int oct = 0; oct < 8; oct++) {
    bf16x8 r;
#pragma unroll
    for (int j = 0; j < 8; j++)
      r[j] = (__bf16)(p0 * (float)fsv[oct][j] + p1 * (float)fdv[oct][j]);
    *(bf16x8*)(fusedT + ((size_t)b * 8 + oct) * FPL + ppix) = r;
  }
}

// ---------------------------------------------------------------------------
// K8: collapsed ELK via MFMA, planar fusedT reads (quad-coalesced).
// ---------------------------------------------------------------------------
__global__ __launch_bounds__(256) void k_elkm(
    const __bf16* __restrict__ fusedT, const __bf16* __restrict__ weffD,
    const float* __restrict__ beff, float* __restrict__ out)
{
  const int DY[13] = {-2,-1,-1,-1, 0, 0, 0, 0, 0, 1, 1, 1, 2};
  const int DX[13] = { 0,-1, 0, 1,-2,-1, 0, 1, 2,-1, 0, 1, 0};
  const int lane = threadIdx.x & 63;
  const int wv   = threadIdx.x >> 6;
  const int swz  = xcd_swz(blockIdx.x, 64);
  const int b    = swz >> 6;
  const int h    = (swz & 63) * 2 + (wv >> 1);
  const int half = wv & 1;
  const int l15  = lane & 15;
  const int g    = lane >> 4;

  f32x4 acc[4][4];
#pragma unroll
  for (int mf = 0; mf < 4; mf++)
#pragma unroll
    for (int nf = 0; nf < 4; nf++) acc[mf][nf] = (f32x4){0.f, 0.f, 0.f, 0.f};

  const bf16x8* aD = (const bf16x8*)weffD;
  const __bf16* pl0 = fusedT + ((size_t)b * 8 + g) * FPL;      // s=0 plane
  const __bf16* pl1 = pl0 + 4 * FPL;                            // s=1 plane

  for (int t = 0; t < 13; t++) {
    int hp = h + 2 + DY[t];
    size_t rowb = (size_t)(hp * 132 + half * 64 + 2 + DX[t] + l15) * 8;
#pragma unroll
    for (int s = 0; s < 2; s++) {
      const __bf16* pl = s ? pl1 : pl0;
      bf16x8 a0 = aD[((t * 2 + s) * 4 + 0) * 64 + lane];
      bf16x8 a1 = aD[((t * 2 + s) * 4 + 1) * 64 + lane];
      bf16x8 a2 = aD[((t * 2 + s) * 4 + 2) * 64 + lane];
      bf16x8 a3 = aD[((t * 2 + s) * 4 + 3) * 64 + lane];
#pragma unroll
      for (int nf = 0; nf < 4; nf++) {
        bf16x8 bv = *(const bf16x8*)(pl + rowb + (size_t)nf * 128);
        acc[0][nf] = __builtin_amdgcn_mfma_f32_16x16x32_bf16(a0, bv, acc[0][nf], 0, 0, 0);
        acc[1][nf] = __builtin_amdgcn_mfma_f32_16x16x32_bf16(a1, bv, acc[1][nf], 0, 0, 0);
        acc[2][nf] = __builtin_amdgcn_mfma_f32_16x16x32_bf16(a2, bv, acc[2][nf], 0, 0, 0);
        acc[3][nf] = __builtin_amdgcn_mfma_f32_16x16x32_bf16(a3, bv, acc[3][nf], 0, 0, 0);
      }
    }
  }

#pragma unroll
  for (int mf = 0; mf < 4; mf++) {
    int ob = mf * 16 + (g << 2);
#pragma unroll
    for (int r = 0; r < 4; r++) {
      int o = ob + r;
      float bb = beff[o];
      float* orow = out + ((size_t)(b * 64 + o)) * HWn + h * 128 + half * 64 + l15;
#pragma unroll
      for (int nf = 0; nf < 4; nf++)
        orow[nf * 16] = acc[mf][nf][r] + bb;
    }
  }
}

// ---------------------------------------------------------------------------
// Workspace layout unchanged (sizes verified in floats):
// Region A [0, 4,596,736): xT -> fusedT (after dcnm).
// Region B [4,596,736, 9,536,512): xC -> FsT (after conv1m).
// Region C [9,536,512, 14,322,688): t1T/p1T/t2 -> FdT (after k_feat).
// Tail: feat/theta/wfrag/w2frag/beff/dcnD/weffD @14,322,688.. end 14,444,160.
// ---------------------------------------------------------------------------
extern "C" void kernel_launch(void* const* d_in, const int* in_sizes, int n_in,
                              void* d_out, int out_size, void* d_ws, size_t ws_size,
                              hipStream_t stream)
{
  (void)in_sizes; (void)n_in; (void)out_size; (void)ws_size;
  const float* x      = (const float*)d_in[0];
  const float* offset = (const float*)d_in[1];
  const float* stn_w1 = (const float*)d_in[2];
  const float* stn_b1 = (const float*)d_in[3];
  const float* stn_w2 = (const float*)d_in[4];
  const float* stn_b2 = (const float*)d_in[5];
  const float* fc_w   = (const float*)d_in[6];
  const float* fc_b   = (const float*)d_in[7];
  const float* dcn_w  = (const float*)d_in[8];
  const float* dcn_b  = (const float*)d_in[9];
  const float* wg_w   = (const float*)d_in[10];
  const float* wg_b   = (const float*)d_in[11];
  const float* w3     = (const float*)d_in[12];
  const float* b3     = (const float*)d_in[13];
  const float* w15    = (const float*)d_in[14];
  const float* b15    = (const float*)d_in[15];
  const float* w51    = (const float*)d_in[16];
  const float* b51    = (const float*)d_in[17];
  const float* w1     = (const float*)d_in[18];
  const float* b1     = (const float*)d_in[19];

  float* ws      = (float*)d_ws;
  __bf16* xT     = (__bf16*)ws;
  __bf16* fusedT = (__bf16*)ws;
  __bf16* xC     = (__bf16*)(ws + 4596736);
  __bf16* FsT    = (__bf16*)(ws + 4596736);
  __bf16* t1T    = (__bf16*)(ws + 9536512);
  __bf16* FdT    = (__bf16*)(ws + 9536512);
  __bf16* p1T    = (__bf16*)(ws + 11633664);
  float*  t2     = ws + 12225536;
  float*  feat   = ws + 14322688;
  float*  theta  = ws + 14323200;
  __bf16* wfrag  = (__bf16*)(ws + 14323264);
  __bf16* w2frag = (__bf16*)(ws + 14373440);
  float*  beff   = ws + 14399040;
  __bf16* dcnD   = (__bf16*)(ws + 14399104);
  __bf16* weffD  = (__bf16*)(ws + 14417536);
  float*  out    = (float*)d_out;

  k_wprep <<<945,  256, 0, stream>>>(stn_w1, dcn_w, w1, w3, w15, w51, stn_w2,
                                     b3, b15, b51, b1,
                                     wfrag, dcnD, weffD, w2frag, beff);
  k_xt    <<<1123, 256, 0, stream>>>(x, xT, xC);
  k_conv1m<<<512,  256, 0, stream>>>(xC, wfrag, stn_b1, t1T);
  k_pool  <<<145,  256, 0, stream>>>(t1T, p1T);
  k_conv2m<<<128,  256, 0, stream>>>(p1T, w2frag, stn_b2, t2);
  k_feat  <<<512,  256, 0, stream>>>(t2, feat);
  k_theta <<<1,    64,  0, stream>>>(feat, fc_w, fc_b, theta);
  k_dcnm  <<<8192, 64,  0, stream>>>(xT, offset, theta, dcnD, dcn_b, FdT, FsT);
  k_fuseT <<<545,  256, 0, stream>>>(FsT, FdT, wg_w, wg_b, fusedT);
  k_elkm  <<<512,  256, 0, stream>>>(fusedT, weffD, beff, out);
}

// Round 15
// 178.960 us; speedup vs baseline: 1.1085x; 1.1085x over previous
//
#include <hip/hip_runtime.h>
#include <math.h>

// Problem dims
#define Bn 8
#define Cn 64
#define Hn 128
#define Wn 128
#define HWn 16384

typedef __attribute__((ext_vector_type(8))) __bf16 bf16x8;
typedef __attribute__((ext_vector_type(4))) __bf16 bf16x4;
typedef __attribute__((ext_vector_type(4))) float f32x4;

__device__ __forceinline__ int xcd_swz(int bid, int chunk) {
  return (bid & 7) * chunk + (bid >> 3);
}

// ---------------------------------------------------------------------------
// K-wprep: merged weight prep + p1T pad zeroing.
// Sections: wfrag 100,352 | dcnD 36,864 | weffD 53,248 | w2frag 51,200 |
// beff 64 | p1T zero 73,984 (16 bf16 each).  Total 315,712 threads.
// ---------------------------------------------------------------------------
__global__ __launch_bounds__(256) void k_wprep(
    const float* __restrict__ stn_w1, const float* __restrict__ dcn_w,
    const float* __restrict__ w1, const float* __restrict__ w3,
    const float* __restrict__ w15, const float* __restrict__ w51,
    const float* __restrict__ stn_w2,
    const float* __restrict__ b3, const float* __restrict__ b15,
    const float* __restrict__ b51, const float* __restrict__ b1,
    __bf16* __restrict__ wfrag, __bf16* __restrict__ dcnD,
    __bf16* __restrict__ weffD, __bf16* __restrict__ w2frag,
    float* __restrict__ beff, __bf16* __restrict__ p1T)
{
  int t = blockIdx.x * 256 + threadIdx.x;
  if (t < 100352) {
    int e = t & 7, l = (t >> 3) & 63, o16 = (t >> 9) & 1, ck = (t >> 10) & 1;
    int tap = t >> 11;
    int o = o16 * 16 + (l & 15), c = ck * 32 + (l >> 4) * 8 + e;
    wfrag[t] = (__bf16)stn_w1[(o * 64 + c) * 49 + tap];
    return;
  }
  t -= 100352;
  if (t < 36864) {
    int e = t & 7, l = (t >> 3) & 63, mf = (t >> 9) & 3, s = (t >> 11) & 1;
    int tap = t >> 12;
    int o = mf * 16 + (l & 15), c = s * 32 + (l >> 4) * 8 + e;
    dcnD[t] = (__bf16)dcn_w[(o * 64 + c) * 9 + tap];
    return;
  }
  t -= 36864;
  if (t < 53248) {
    const int DY[13] = {-2,-1,-1,-1, 0, 0, 0, 0, 0, 1, 1, 1, 2};
    const int DX[13] = { 0,-1, 0, 1,-2,-1, 0, 1, 2,-1, 0, 1, 0};
    int e = t & 7, l = (t >> 3) & 63, mf = (t >> 9) & 3, s = (t >> 11) & 1;
    int tap = t >> 12;
    int o = mf * 16 + (l & 15), c = s * 32 + (l >> 4) * 8 + e;
    int dy = DY[tap], dx = DX[tap];
    float v = 0.f;
    if (dy >= -1 && dy <= 1 && dx >= -1 && dx <= 1) {
      int k3 = (dy + 1) * 3 + (dx + 1);
      for (int m = 0; m < 64; m++) v = fmaf(w1[o * 192 + m], w3[(m * 64 + c) * 9 + k3], v);
    }
    if (dy == 0) {
      int k15 = dx + 2;
      for (int m = 0; m < 64; m++) v = fmaf(w1[o * 192 + 64 + m], w15[(m * 64 + c) * 5 + k15], v);
    }
    if (dx == 0) {
      int k51 = dy + 2;
      for (int m = 0; m < 64; m++) v = fmaf(w1[o * 192 + 128 + m], w51[(m * 64 + c) * 5 + k51], v);
    }
    weffD[t] = (__bf16)v;
    return;
  }
  t -= 53248;
  if (t < 51200) {
    int e = t & 7, l = (t >> 3) & 63, mf = (t >> 9) & 3;
    int tap = t >> 11;
    int o = mf * 16 + (l & 15), c = (l >> 4) * 8 + e;
    w2frag[t] = (__bf16)stn_w2[(o * 32 + c) * 25 + tap];
    return;
  }
  t -= 51200;
  if (t < 64) {
    float s = b1[t];
    for (int m = 0; m < 64; m++) {
      s = fmaf(w1[t * 192 + m],       b3[m],  s);
      s = fmaf(w1[t * 192 + 64 + m],  b15[m], s);
      s = fmaf(w1[t * 192 + 128 + m], b51[m], s);
    }
    beff[t] = s;
    return;
  }
  t -= 64;
  if (t < 73984) {                        // zero all of p1T (pad ring stays 0)
    bf16x8 z = {};
    *(bf16x8*)(p1T + (size_t)t * 16) = z;
    *(bf16x8*)(p1T + (size_t)t * 16 + 8) = z;
  }
}

// ---------------------------------------------------------------------------
// K-xt v2: thread per (pixel, channel-half), 32 loads unrolled to regs.
// ---------------------------------------------------------------------------
__global__ __launch_bounds__(256) void k_xt(const float* __restrict__ x,
                                            __bf16* __restrict__ xT,
                                            __bf16* __restrict__ xC)
{
  int t = blockIdx.x * 256 + threadIdx.x;
  if (t >= 8 * 134 * 134 * 2) return;
  int half = t & 1;
  int p  = t >> 1;
  int wp = p % 134;
  int hp = (p / 134) % 134;
  int b  = p / (134 * 134);
  int h = hp - 3, w = wp - 3;
  bool inb = ((unsigned)h < 128u) && ((unsigned)w < 128u);
  const float* xb = x + (size_t)b * Cn * HWn + (size_t)(half * 32) * HWn + h * 128 + w;

  float v[32];
#pragma unroll
  for (int j = 0; j < 32; j++) v[j] = inb ? xb[(size_t)j * HWn] : 0.f;

  __bf16* dstT = xT + (size_t)p * 64 + half * 32;
#pragma unroll
  for (int g = 0; g < 4; g++) {
    bf16x8 r;
#pragma unroll
    for (int j = 0; j < 8; j++) r[j] = (__bf16)v[g * 8 + j];
    *(bf16x8*)(dstT + g * 8) = r;
    int oct = half * 4 + g;
    *(bf16x8*)(xC + ((((size_t)b * 8 + oct) * 134 + hp) * 144 + wp) * 8) = r;
  }
}

// ---------------------------------------------------------------------------
// K1: STN conv1 via MFMA + FUSED 2x2 MAXPOOL (R15).
// Block owns rows h0,h0+1 = exactly one pool row. After the MFMA loop the
// LDS tile is dead: stage relu'd bf16 output there, pool in-block, write
// p1T directly. t1T global buffer eliminated.
// ---------------------------------------------------------------------------
__global__ __launch_bounds__(256) void k_conv1m(
    const __bf16* __restrict__ xC, const __bf16* __restrict__ wfrag,
    const float* __restrict__ b1s, __bf16* __restrict__ p1T)
{
  __shared__ alignas(16) char tile[73728];   // staging + (later) pool buffer
  const int lane = threadIdx.x & 63;
  const int wv   = threadIdx.x >> 6;
  const int swz  = xcd_swz(blockIdx.x, 64);
  const int b    = swz >> 6;
  const int h0   = (swz & 63) * 2;
  const int r    = wv >> 1;
  const int hf   = wv & 1;
  const int l15  = lane & 15;

  f32x4 acc[2][4];
#pragma unroll
  for (int o16 = 0; o16 < 2; o16++)
#pragma unroll
    for (int nf = 0; nf < 4; nf++) acc[o16][nf] = (f32x4){0.f, 0.f, 0.f, 0.f};

  const bf16x8* wf = (const bf16x8*)wfrag;
  const char* tb = (const char*)tile;
  const char* xCb = (const char*)xC;

  for (int ck = 0; ck < 2; ck++) {
    for (int i = wv; i < 72; i += 4) {
      int q = i / 18;
      int t = i - q * 18;
      const char* src = xCb
          + (((size_t)(b * 8 + ck * 4 + q) * 134 + h0) * 2304) + t * 1024 + lane * 16;
      char* dst = (char*)tile + i * 1024;
      __builtin_amdgcn_global_load_lds(
          (const __attribute__((address_space(1))) void*)src,
          (__attribute__((address_space(3))) void*)dst, 16, 0, 0);
    }
    __syncthreads();

    for (int tap = 0; tap < 49; tap++) {
      int dy7 = tap / 7;
      int dx7 = tap - dy7 * 7;
      bf16x8 a0 = wf[((tap * 2 + ck) * 2 + 0) * 64 + lane];
      bf16x8 a1 = wf[((tap * 2 + ck) * 2 + 1) * 64 + lane];
      const char* bp = tb + (lane >> 4) * 18432 + (r + dy7) * 2304
                          + (dx7 + hf * 64 + l15) * 16;
#pragma unroll
      for (int nf = 0; nf < 4; nf++) {
        bf16x8 bv = *(const bf16x8*)(bp + nf * 256);
        acc[0][nf] = __builtin_amdgcn_mfma_f32_16x16x32_bf16(a0, bv, acc[0][nf], 0, 0, 0);
        acc[1][nf] = __builtin_amdgcn_mfma_f32_16x16x32_bf16(a1, bv, acc[1][nf], 0, 0, 0);
      }
    }
    __syncthreads();
  }

  // ---- stage relu'd output in LDS: [row2][px128][ch32] bf16 (16KB) ----
#pragma unroll
  for (int o16 = 0; o16 < 2; o16++) {
    int ob = o16 * 16 + ((lane >> 4) << 2);
    float bb0 = b1s[ob], bb1 = b1s[ob + 1], bb2 = b1s[ob + 2], bb3 = b1s[ob + 3];
#pragma unroll
    for (int nf = 0; nf < 4; nf++) {
      int px = hf * 64 + nf * 16 + l15;
      bf16x4 rr;
      rr[0] = (__bf16)fmaxf(acc[o16][nf][0] + bb0, 0.f);
      rr[1] = (__bf16)fmaxf(acc[o16][nf][1] + bb1, 0.f);
      rr[2] = (__bf16)fmaxf(acc[o16][nf][2] + bb2, 0.f);
      rr[3] = (__bf16)fmaxf(acc[o16][nf][3] + bb3, 0.f);
      *(bf16x4*)((char*)tile + (size_t)(r * 128 + px) * 64 + ob * 2) = rr;
    }
  }
  __syncthreads();

  // ---- 2x2 maxpool -> p1T row (swz&63)+2, cols 2..65 ----
  {
    int tid = threadIdx.x;
    int wp = tid >> 2, cg = tid & 3;
    const char* base = (const char*)tile;
    bf16x8 v00 = *(const bf16x8*)(base + (size_t)(0 * 128 + 2 * wp) * 64 + cg * 16);
    bf16x8 v01 = *(const bf16x8*)(base + (size_t)(0 * 128 + 2 * wp + 1) * 64 + cg * 16);
    bf16x8 v10 = *(const bf16x8*)(base + (size_t)(1 * 128 + 2 * wp) * 64 + cg * 16);
    bf16x8 v11 = *(const bf16x8*)(base + (size_t)(1 * 128 + 2 * wp + 1) * 64 + cg * 16);
    bf16x8 rr;
#pragma unroll
    for (int j = 0; j < 8; j++) {
      float m = fmaxf(fmaxf((float)v00[j], (float)v01[j]),
                      fmaxf((float)v10[j], (float)v11[j]));
      rr[j] = (__bf16)m;
    }
    int hp = (swz & 63) + 2;
    *(bf16x8*)(p1T + (((size_t)b * 68 + hp) * 68 + wp + 2) * 32 + cg * 8) = rr;
  }
}

// ---------------------------------------------------------------------------
// K3: conv2 via MFMA + FUSED deterministic feat reduction (R15).
// Block reduces relu(conv2+bias) over its 4x64-pixel tile in LDS and writes
// partial[b*16+tile][64]; t2 buffer and k_feat eliminated.
// ---------------------------------------------------------------------------
__global__ __launch_bounds__(256) void k_conv2m(
    const __bf16* __restrict__ p1T, const __bf16* __restrict__ w2frag,
    const float* __restrict__ b2s, float* __restrict__ partial)
{
  __shared__ alignas(16) char tile[34816];   // 8*68*64
  __shared__ float sm2[4][16][64];
  const int lane = threadIdx.x & 63;
  const int wv   = threadIdx.x >> 6;
  const int b    = blockIdx.x >> 4;
  const int tl   = blockIdx.x & 15;
  const int h0   = tl * 4;
  const int l15  = lane & 15;

  f32x4 acc[4][4];
#pragma unroll
  for (int mf = 0; mf < 4; mf++)
#pragma unroll
    for (int nf = 0; nf < 4; nf++) acc[mf][nf] = (f32x4){0.f, 0.f, 0.f, 0.f};

  const char* src0 = (const char*)p1T + (((size_t)b * 68 + h0) * 68) * 64;
  for (int i = wv; i < 34; i += 4) {
    __builtin_amdgcn_global_load_lds(
        (const __attribute__((address_space(1))) void*)(src0 + i * 1024 + lane * 16),
        (__attribute__((address_space(3))) void*)((char*)tile + i * 1024), 16, 0, 0);
  }
  __syncthreads();

  const bf16x8* wf = (const bf16x8*)w2frag;
  const char* tb = (const char*)tile;
  for (int tap = 0; tap < 25; tap++) {
    int ky = tap / 5, kx = tap - ky * 5;
    bf16x8 a0 = wf[(tap * 4 + 0) * 64 + lane];
    bf16x8 a1 = wf[(tap * 4 + 1) * 64 + lane];
    bf16x8 a2 = wf[(tap * 4 + 2) * 64 + lane];
    bf16x8 a3 = wf[(tap * 4 + 3) * 64 + lane];
    const char* bp = tb + (((wv + ky) * 68 + kx + l15) * 64) + (lane >> 4) * 16;
#pragma unroll
    for (int nf = 0; nf < 4; nf++) {
      bf16x8 bv = *(const bf16x8*)(bp + nf * 1024);
      acc[0][nf] = __builtin_amdgcn_mfma_f32_16x16x32_bf16(a0, bv, acc[0][nf], 0, 0, 0);
      acc[1][nf] = __builtin_amdgcn_mfma_f32_16x16x32_bf16(a1, bv, acc[1][nf], 0, 0, 0);
      acc[2][nf] = __builtin_amdgcn_mfma_f32_16x16x32_bf16(a2, bv, acc[2][nf], 0, 0, 0);
      acc[3][nf] = __builtin_amdgcn_mfma_f32_16x16x32_bf16(a3, bv, acc[3][nf], 0, 0, 0);
    }
  }

  // per-thread partial: sum over its 4 pixels (nf) per (mf,r) channel
#pragma unroll
  for (int mf = 0; mf < 4; mf++) {
    int ob = mf * 16 + ((lane >> 4) << 2);
#pragma unroll
    for (int rr = 0; rr < 4; rr++) {
      float bb = b2s[ob + rr];
      float s = 0.f;
#pragma unroll
      for (int nf = 0; nf < 4; nf++)
        s += fmaxf(acc[mf][nf][rr] + bb, 0.f);
      sm2[wv][l15][ob + rr] = s;
    }
  }
  __syncthreads();
  if (threadIdx.x < 64) {
    float s = 0.f;
#pragma unroll
    for (int w2 = 0; w2 < 4; w2++)
      for (int l = 0; l < 16; l++) s += sm2[w2][l][threadIdx.x];
    partial[(size_t)(b * 16 + tl) * 64 + threadIdx.x] = s;
  }
}

// ---------------------------------------------------------------------------
// K4: theta (feat = sum of 16 partials, then FC).  512 threads, 1 block.
// ---------------------------------------------------------------------------
__global__ __launch_bounds__(512) void k_theta(
    const float* __restrict__ partial, const float* __restrict__ fc_w,
    const float* __restrict__ fc_b, float* __restrict__ theta)
{
  __shared__ float featL[512];
  int tid = threadIdx.x;
  {
    int b = tid >> 6, co = tid & 63;
    float s = 0.f;
#pragma unroll
    for (int t = 0; t < 16; t++) s += partial[(size_t)(b * 16 + t) * 64 + co];
    featL[tid] = s;
  }
  __syncthreads();
  if (tid < 48) {
    int b = tid / 6, i = tid - b * 6;
    float s = 0.f;
    for (int k = 0; k < 64; k++) s = fmaf(featL[b * 64 + k], fc_w[i * 64 + k], s);
    theta[tid] = fmaf(s, 1.f / 4096.f, fc_b[i]);
  }
}

// ---------------------------------------------------------------------------
// Shared bilinear corner-address helper (clamped + masked weights).
// ---------------------------------------------------------------------------
__device__ __forceinline__ void bilin_setup(
    const __bf16* __restrict__ xb, float sy, float sx,
    const __bf16*& c00, const __bf16*& c01,
    const __bf16*& c10, const __bf16*& c11,
    float& w00, float& w01, float& w10, float& w11)
{
  float y0f = floorf(sy), x0f = floorf(sx);
  float wy1 = sy - y0f, wy0 = 1.f - wy1;
  float wx1 = sx - x0f, wx0 = 1.f - wx1;
  bool vy0 = (y0f >= 0.f) && (y0f <= 127.f);
  bool vy1 = (y0f >= -1.f) && (y0f <= 126.f);
  bool vx0 = (x0f >= 0.f) && (x0f <= 127.f);
  bool vx1 = (x0f >= -1.f) && (x0f <= 126.f);
  int yi0 = (int)fminf(fmaxf(y0f, 0.f), 127.f);
  int yi1 = (int)fminf(fmaxf(y0f + 1.f, 0.f), 127.f);
  int xi0 = (int)fminf(fmaxf(x0f, 0.f), 127.f);
  int xi1 = (int)fminf(fmaxf(x0f + 1.f, 0.f), 127.f);
  w00 = wy0 * wx0 * ((vy0 && vx0) ? 1.f : 0.f);
  w01 = wy0 * wx1 * ((vy0 && vx1) ? 1.f : 0.f);
  w10 = wy1 * wx0 * ((vy1 && vx0) ? 1.f : 0.f);
  w11 = wy1 * wx1 * ((vy1 && vx1) ? 1.f : 0.f);
  c00 = xb + ((size_t)((yi0 + 3) * 134) + xi0 + 3) * 64;
  c01 = xb + ((size_t)((yi0 + 3) * 134) + xi1 + 3) * 64;
  c10 = xb + ((size_t)((yi1 + 3) * 134) + xi0 + 3) * 64;
  c11 = xb + ((size_t)((yi1 + 3) * 134) + xi1 + 3) * 64;
}

// ---------------------------------------------------------------------------
// K6: deformable conv + fused STN sample — R13 structure (best measured):
// 1-wave blocks, quad-coalesced gathers, tap-parity LDS double-buffer.
// R14's L2 prefetch REVERTED (it regressed: +9us issue overhead, gathers
// were already mostly L2-hits per FETCH accounting).
// ---------------------------------------------------------------------------
__global__ __launch_bounds__(64) void k_dcnm(
    const __bf16* __restrict__ xT, const float* __restrict__ off,
    const float* __restrict__ theta,
    const __bf16* __restrict__ dcnD, const float* __restrict__ dcn_b,
    __bf16* __restrict__ FdT, __bf16* __restrict__ FsT)
{
  __shared__ alignas(16) char smem[2][2048];
  const int lane = threadIdx.x;
  const int swz  = xcd_swz(blockIdx.x, 1024);
  const int b    = swz >> 10;
  const int rem  = swz & 1023;
  const int h    = rem >> 3;
  const int px0  = (rem & 7) * 16;
  const int l15  = lane & 15;
  const int g    = lane >> 4;
  const int pg   = lane >> 2;
  const int q    = lane & 3;
  const int wg   = px0 + pg;

  const __bf16* xb = xT + (size_t)b * 134 * 134 * 64;

  const float* ob = off + (size_t)b * 18 * HWn + h * 128 + wg;
  float offs[18];
#pragma unroll
  for (int i = 0; i < 18; i++) offs[i] = ob[(size_t)i * HWn];

  // ---- fused STN sample ----
  {
    const float* t = theta + b * 6;
    float xn = (float)(2 * wg + 1) * (1.f / 128.f) - 1.f;
    float yn = (float)(2 * h + 1) * (1.f / 128.f) - 1.f;
    float gxv = t[0] * xn + t[1] * yn + t[2];
    float gyv = t[3] * xn + t[4] * yn + t[5];
    float ix = fmaf(gxv, 64.f, 63.5f);
    float iy = fmaf(gyv, 64.f, 63.5f);
    const __bf16 *c00, *c01, *c10, *c11;
    float w00, w01, w10, w11;
    bilin_setup(xb, iy, ix, c00, c01, c10, c11, w00, w01, w10, w11);
    __bf16* dst = FsT + ((size_t)b * HWn + h * 128 + wg) * 64;
#pragma unroll
    for (int s = 0; s < 2; s++) {
      int eo = q * 8 + s * 32;
      bf16x8 v00 = *(const bf16x8*)(c00 + eo);
      bf16x8 v01 = *(const bf16x8*)(c01 + eo);
      bf16x8 v10 = *(const bf16x8*)(c10 + eo);
      bf16x8 v11 = *(const bf16x8*)(c11 + eo);
      bf16x8 r;
#pragma unroll
      for (int j = 0; j < 8; j++) {
        float f = w00 * (float)v00[j] + w01 * (float)v01[j]
                + w10 * (float)v10[j] + w11 * (float)v11[j];
        r[j] = (__bf16)f;
      }
      *(bf16x8*)(dst + eo) = r;
    }
  }

  // ---- deformable conv: 9 taps ----
  f32x4 acc[4];
#pragma unroll
  for (int mf = 0; mf < 4; mf++) acc[mf] = (f32x4){0.f, 0.f, 0.f, 0.f};
  const bf16x8* aD = (const bf16x8*)dcnD;

#pragma unroll
  for (int k = 0; k < 9; k++) {
    char* sm = smem[k & 1];
    float sy = (float)(h + k / 3 - 1) + offs[2 * k];
    float sx = (float)(wg + k % 3 - 1) + offs[2 * k + 1];
    const __bf16 *c00, *c01, *c10, *c11;
    float w00, w01, w10, w11;
    bilin_setup(xb, sy, sx, c00, c01, c10, c11, w00, w01, w10, w11);

#pragma unroll
    for (int s = 0; s < 2; s++) {
      int eo = q * 8 + s * 32;
      bf16x8 v00 = *(const bf16x8*)(c00 + eo);
      bf16x8 v01 = *(const bf16x8*)(c01 + eo);
      bf16x8 v10 = *(const bf16x8*)(c10 + eo);
      bf16x8 v11 = *(const bf16x8*)(c11 + eo);
      bf16x8 r;
#pragma unroll
      for (int j = 0; j < 8; j++) {
        float f = w00 * (float)v00[j] + w01 * (float)v01[j]
                + w10 * (float)v10[j] + w11 * (float)v11[j];
        r[j] = (__bf16)f;
      }
      int c = s * 4 + q;
      *(bf16x8*)(sm + pg * 128 + ((c ^ (pg & 7)) * 16)) = r;
    }

#pragma unroll
    for (int s = 0; s < 2; s++) {
      int c = s * 4 + g;
      bf16x8 a = *(const bf16x8*)(sm + l15 * 128 + ((c ^ (l15 & 7)) * 16));
      acc[0] = __builtin_amdgcn_mfma_f32_16x16x32_bf16(
          a, aD[((k * 2 + s) * 4 + 0) * 64 + lane], acc[0], 0, 0, 0);
      acc[1] = __builtin_amdgcn_mfma_f32_16x16x32_bf16(
          a, aD[((k * 2 + s) * 4 + 1) * 64 + lane], acc[1], 0, 0, 0);
      acc[2] = __builtin_amdgcn_mfma_f32_16x16x32_bf16(
          a, aD[((k * 2 + s) * 4 + 2) * 64 + lane], acc[2], 0, 0, 0);
      acc[3] = __builtin_amdgcn_mfma_f32_16x16x32_bf16(
          a, aD[((k * 2 + s) * 4 + 3) * 64 + lane], acc[3], 0, 0, 0);
    }
  }

  __bf16* fb = FdT + ((size_t)b * HWn + h * 128 + px0) * 64;
#pragma unroll
  for (int mf = 0; mf < 4; mf++) {
    int o = mf * 16 + l15;
    float bias = dcn_b[o];
#pragma unroll
    for (int r = 0; r < 4; r++) {
      int pxl = g * 4 + r;
      fb[(size_t)pxl * 64 + o] = (__bf16)(acc[mf][r] + bias);
    }
  }
}

// ---------------------------------------------------------------------------
// K7: fusion -> fusedT bf16 OCTET-PLANAR [b][oct8][132][132][8ch], 2-pad ring.
// ---------------------------------------------------------------------------
#define FPL ((size_t)132 * 132 * 8)
__global__ __launch_bounds__(256) void k_fuseT(
    const __bf16* __restrict__ FsT, const __bf16* __restrict__ FdT,
    const float* __restrict__ wg_w, const float* __restrict__ wg_b,
    __bf16* __restrict__ fusedT)
{
  int id = blockIdx.x * 256 + threadIdx.x;
  if (id >= 8 * 132 * 132) return;
  int wp = id % 132;
  int hp = (id / 132) % 132;
  int b  = id / (132 * 132);
  size_t ppix = (size_t)(hp * 132 + wp) * 8;
  int h = hp - 2, w = wp - 2;
  if (((unsigned)h >= 128u) || ((unsigned)w >= 128u)) {
    bf16x8 z = {};
#pragma unroll
    for (int oct = 0; oct < 8; oct++)
      *(bf16x8*)(fusedT + ((size_t)b * 8 + oct) * FPL + ppix) = z;
    return;
  }
  const bf16x8* fs = (const bf16x8*)(FsT + ((size_t)b * HWn + h * 128 + w) * 64);
  const bf16x8* fd = (const bf16x8*)(FdT + ((size_t)b * HWn + h * 128 + w) * 64);
  bf16x8 fsv[8], fdv[8];
  float s0 = wg_b[0], s1 = wg_b[1];
#pragma unroll
  for (int oct = 0; oct < 8; oct++) {
    fsv[oct] = fs[oct];
    fdv[oct] = fd[oct];
#pragma unroll
    for (int j = 0; j < 8; j++) {
      int c = oct * 8 + j;
      float a = (float)fsv[oct][j], d = (float)fdv[oct][j];
      s0 = fmaf(wg_w[c],       a, fmaf(wg_w[64 + c],  d, s0));
      s1 = fmaf(wg_w[128 + c], a, fmaf(wg_w[192 + c], d, s1));
    }
  }
  float p0 = 1.f / (1.f + __expf(s1 - s0));
  float p1 = 1.f - p0;
#pragma unroll
  for (int oct = 0; oct < 8; oct++) {
    bf16x8 r;
#pragma unroll
    for (int j = 0; j < 8; j++)
      r[j] = (__bf16)(p0 * (float)fsv[oct][j] + p1 * (float)fdv[oct][j]);
    *(bf16x8*)(fusedT + ((size_t)b * 8 + oct) * FPL + ppix) = r;
  }
}

// ---------------------------------------------------------------------------
// K8: collapsed ELK via MFMA, planar fusedT reads (quad-coalesced).
// ---------------------------------------------------------------------------
__global__ __launch_bounds__(256) void k_elkm(
    const __bf16* __restrict__ fusedT, const __bf16* __restrict__ weffD,
    const float* __restrict__ beff, float* __restrict__ out)
{
  const int DY[13] = {-2,-1,-1,-1, 0, 0, 0, 0, 0, 1, 1, 1, 2};
  const int DX[13] = { 0,-1, 0, 1,-2,-1, 0, 1, 2,-1, 0, 1, 0};
  const int lane = threadIdx.x & 63;
  const int wv   = threadIdx.x >> 6;
  const int swz  = xcd_swz(blockIdx.x, 64);
  const int b    = swz >> 6;
  const int h    = (swz & 63) * 2 + (wv >> 1);
  const int half = wv & 1;
  const int l15  = lane & 15;
  const int g    = lane >> 4;

  f32x4 acc[4][4];
#pragma unroll
  for (int mf = 0; mf < 4; mf++)
#pragma unroll
    for (int nf = 0; nf < 4; nf++) acc[mf][nf] = (f32x4){0.f, 0.f, 0.f, 0.f};

  const bf16x8* aD = (const bf16x8*)weffD;
  const __bf16* pl0 = fusedT + ((size_t)b * 8 + g) * FPL;
  const __bf16* pl1 = pl0 + 4 * FPL;

  for (int t = 0; t < 13; t++) {
    int hp = h + 2 + DY[t];
    size_t rowb = (size_t)(hp * 132 + half * 64 + 2 + DX[t] + l15) * 8;
#pragma unroll
    for (int s = 0; s < 2; s++) {
      const __bf16* pl = s ? pl1 : pl0;
      bf16x8 a0 = aD[((t * 2 + s) * 4 + 0) * 64 + lane];
      bf16x8 a1 = aD[((t * 2 + s) * 4 + 1) * 64 + lane];
      bf16x8 a2 = aD[((t * 2 + s) * 4 + 2) * 64 + lane];
      bf16x8 a3 = aD[((t * 2 + s) * 4 + 3) * 64 + lane];
#pragma unroll
      for (int nf = 0; nf < 4; nf++) {
        bf16x8 bv = *(const bf16x8*)(pl + rowb + (size_t)nf * 128);
        acc[0][nf] = __builtin_amdgcn_mfma_f32_16x16x32_bf16(a0, bv, acc[0][nf], 0, 0, 0);
        acc[1][nf] = __builtin_amdgcn_mfma_f32_16x16x32_bf16(a1, bv, acc[1][nf], 0, 0, 0);
        acc[2][nf] = __builtin_amdgcn_mfma_f32_16x16x32_bf16(a2, bv, acc[2][nf], 0, 0, 0);
        acc[3][nf] = __builtin_amdgcn_mfma_f32_16x16x32_bf16(a3, bv, acc[3][nf], 0, 0, 0);
      }
    }
  }

#pragma unroll
  for (int mf = 0; mf < 4; mf++) {
    int ob = mf * 16 + (g << 2);
#pragma unroll
    for (int r = 0; r < 4; r++) {
      int o = ob + r;
      float bb = beff[o];
      float* orow = out + ((size_t)(b * 64 + o)) * HWn + h * 128 + half * 64 + l15;
#pragma unroll
      for (int nf = 0; nf < 4; nf++)
        orow[nf * 16] = acc[mf][nf][r] + bb;
    }
  }
}

// ---------------------------------------------------------------------------
// Workspace (FLOAT offsets, sizes verified):
// Region A [0, 4,596,736): xT -> fusedT (after dcnm).
// Region B [4,596,736, 9,536,512): xC -> FsT (after conv1m).
// Region C [9,536,512, 14,322,688):
//   p1T @11,633,664 (591,872 fl; zeroed by wprep, written conv1m, read conv2m)
//   partial @12,225,536 (8,192 fl; conv2m -> theta)
//   FdT @9,536,512 (4,194,304 fl; written by dcnm AFTER theta)  OK.
// Tail: wfrag @14,323,264 | w2frag @14,373,440 | beff @14,399,040 |
//       dcnD @14,399,104 | weffD @14,417,536 | theta @14,323,200.
// ---------------------------------------------------------------------------
extern "C" void kernel_launch(void* const* d_in, const int* in_sizes, int n_in,
                              void* d_out, int out_size, void* d_ws, size_t ws_size,
                              hipStream_t stream)
{
  (void)in_sizes; (void)n_in; (void)out_size; (void)ws_size;
  const float* x      = (const float*)d_in[0];
  const float* offset = (const float*)d_in[1];
  const float* stn_w1 = (const float*)d_in[2];
  const float* stn_b1 = (const float*)d_in[3];
  const float* stn_w2 = (const float*)d_in[4];
  const float* stn_b2 = (const float*)d_in[5];
  const float* fc_w   = (const float*)d_in[6];
  const float* fc_b   = (const float*)d_in[7];
  const float* dcn_w  = (const float*)d_in[8];
  const float* dcn_b  = (const float*)d_in[9];
  const float* wg_w   = (const float*)d_in[10];
  const float* wg_b   = (const float*)d_in[11];
  const float* w3     = (const float*)d_in[12];
  const float* b3     = (const float*)d_in[13];
  const float* w15    = (const float*)d_in[14];
  const float* b15    = (const float*)d_in[15];
  const float* w51    = (const float*)d_in[16];
  const float* b51    = (const float*)d_in[17];
  const float* w1     = (const float*)d_in[18];
  const float* b1     = (const float*)d_in[19];

  float* ws      = (float*)d_ws;
  __bf16* xT     = (__bf16*)ws;
  __bf16* fusedT = (__bf16*)ws;
  __bf16* xC     = (__bf16*)(ws + 4596736);
  __bf16* FsT    = (__bf16*)(ws + 4596736);
  __bf16* FdT    = (__bf16*)(ws + 9536512);
  __bf16* p1T    = (__bf16*)(ws + 11633664);
  float*  partial= ws + 12225536;
  float*  theta  = ws + 14323200;
  __bf16* wfrag  = (__bf16*)(ws + 14323264);
  __bf16* w2frag = (__bf16*)(ws + 14373440);
  float*  beff   = ws + 14399040;
  __bf16* dcnD   = (__bf16*)(ws + 14399104);
  __bf16* weffD  = (__bf16*)(ws + 14417536);
  float*  out    = (float*)d_out;

  k_wprep <<<1234, 256, 0, stream>>>(stn_w1, dcn_w, w1, w3, w15, w51, stn_w2,
                                     b3, b15, b51, b1,
                                     wfrag, dcnD, weffD, w2frag, beff, p1T);
  k_xt    <<<1123, 256, 0, stream>>>(x, xT, xC);
  k_conv1m<<<512,  256, 0, stream>>>(xC, wfrag, stn_b1, p1T);
  k_conv2m<<<128,  256, 0, stream>>>(p1T, w2frag, stn_b2, partial);
  k_theta <<<1,    512, 0, stream>>>(partial, fc_w, fc_b, theta);
  k_dcnm  <<<8192, 64,  0, stream>>>(xT, offset, theta, dcnD, dcn_b, FdT, FsT);
  k_fuseT <<<545,  256, 0, stream>>>(FsT, FdT, wg_w, wg_b, fusedT);
  k_elkm  <<<512,  256, 0, stream>>>(fusedT, weffD, beff, out);
}

// Round 16
// 168.070 us; speedup vs baseline: 1.1803x; 1.0648x over previous
//
#include <hip/hip_runtime.h>
#include <math.h>

// Problem dims
#define Bn 8
#define Cn 64
#define Hn 128
#define Wn 128
#define HWn 16384

typedef __attribute__((ext_vector_type(8))) __bf16 bf16x8;
typedef __attribute__((ext_vector_type(4))) __bf16 bf16x4;
typedef __attribute__((ext_vector_type(4))) float f32x4;

__device__ __forceinline__ int xcd_swz(int bid, int chunk) {
  return (bid & 7) * chunk + (bid >> 3);
}

// ---------------------------------------------------------------------------
// K-wprep: merged weight prep + p1T pad zeroing.
// ---------------------------------------------------------------------------
__global__ __launch_bounds__(256) void k_wprep(
    const float* __restrict__ stn_w1, const float* __restrict__ dcn_w,
    const float* __restrict__ w1, const float* __restrict__ w3,
    const float* __restrict__ w15, const float* __restrict__ w51,
    const float* __restrict__ stn_w2,
    const float* __restrict__ b3, const float* __restrict__ b15,
    const float* __restrict__ b51, const float* __restrict__ b1,
    __bf16* __restrict__ wfrag, __bf16* __restrict__ dcnD,
    __bf16* __restrict__ weffD, __bf16* __restrict__ w2frag,
    float* __restrict__ beff, __bf16* __restrict__ p1T)
{
  int t = blockIdx.x * 256 + threadIdx.x;
  if (t < 100352) {
    int e = t & 7, l = (t >> 3) & 63, o16 = (t >> 9) & 1, ck = (t >> 10) & 1;
    int tap = t >> 11;
    int o = o16 * 16 + (l & 15), c = ck * 32 + (l >> 4) * 8 + e;
    wfrag[t] = (__bf16)stn_w1[(o * 64 + c) * 49 + tap];
    return;
  }
  t -= 100352;
  if (t < 36864) {
    int e = t & 7, l = (t >> 3) & 63, mf = (t >> 9) & 3, s = (t >> 11) & 1;
    int tap = t >> 12;
    int o = mf * 16 + (l & 15), c = s * 32 + (l >> 4) * 8 + e;
    dcnD[t] = (__bf16)dcn_w[(o * 64 + c) * 9 + tap];
    return;
  }
  t -= 36864;
  if (t < 53248) {
    const int DY[13] = {-2,-1,-1,-1, 0, 0, 0, 0, 0, 1, 1, 1, 2};
    const int DX[13] = { 0,-1, 0, 1,-2,-1, 0, 1, 2,-1, 0, 1, 0};
    int e = t & 7, l = (t >> 3) & 63, mf = (t >> 9) & 3, s = (t >> 11) & 1;
    int tap = t >> 12;
    int o = mf * 16 + (l & 15), c = s * 32 + (l >> 4) * 8 + e;
    int dy = DY[tap], dx = DX[tap];
    float v = 0.f;
    if (dy >= -1 && dy <= 1 && dx >= -1 && dx <= 1) {
      int k3 = (dy + 1) * 3 + (dx + 1);
      for (int m = 0; m < 64; m++) v = fmaf(w1[o * 192 + m], w3[(m * 64 + c) * 9 + k3], v);
    }
    if (dy == 0) {
      int k15 = dx + 2;
      for (int m = 0; m < 64; m++) v = fmaf(w1[o * 192 + 64 + m], w15[(m * 64 + c) * 5 + k15], v);
    }
    if (dx == 0) {
      int k51 = dy + 2;
      for (int m = 0; m < 64; m++) v = fmaf(w1[o * 192 + 128 + m], w51[(m * 64 + c) * 5 + k51], v);
    }
    weffD[t] = (__bf16)v;
    return;
  }
  t -= 53248;
  if (t < 51200) {
    int e = t & 7, l = (t >> 3) & 63, mf = (t >> 9) & 3;
    int tap = t >> 11;
    int o = mf * 16 + (l & 15), c = (l >> 4) * 8 + e;
    w2frag[t] = (__bf16)stn_w2[(o * 32 + c) * 25 + tap];
    return;
  }
  t -= 51200;
  if (t < 64) {
    float s = b1[t];
    for (int m = 0; m < 64; m++) {
      s = fmaf(w1[t * 192 + m],       b3[m],  s);
      s = fmaf(w1[t * 192 + 64 + m],  b15[m], s);
      s = fmaf(w1[t * 192 + 128 + m], b51[m], s);
    }
    beff[t] = s;
    return;
  }
  t -= 64;
  if (t < 73984) {                        // zero all of p1T
    bf16x8 z = {};
    *(bf16x8*)(p1T + (size_t)t * 16) = z;
    *(bf16x8*)(p1T + (size_t)t * 16 + 8) = z;
  }
}

// ---------------------------------------------------------------------------
// K-zpad (R16): zero the fusedT pad ring (region B reused; must run after
// conv1m's last xC read and before k_dcnm writes the interior).
// pad pixels/plane: rows {0,1,130,131} full (528) + cols {0,1,130,131} of
// rows 2..129 (512) = 1040.  Total 8b x 8oct x 1040 = 66,560 bf16x8 stores.
// ---------------------------------------------------------------------------
#define FPL ((size_t)132 * 132 * 8)
__global__ __launch_bounds__(256) void k_zpad(__bf16* __restrict__ fusedT)
{
  int t = blockIdx.x * 256 + threadIdx.x;
  if (t >= 66560) return;
  int pp = t % 1040;
  int po = (t / 1040) & 7;
  int b  = t / 8320;
  int row, col;
  if (pp < 528) {
    int rr = pp / 132;
    row = (rr < 2) ? rr : 128 + rr;
    col = pp % 132;
  } else {
    int q2 = pp - 528;
    row = 2 + (q2 >> 2);
    int cs = q2 & 3;
    col = (cs < 2) ? cs : 128 + cs;
  }
  bf16x8 z = {};
  *(bf16x8*)(fusedT + ((size_t)b * 8 + po) * FPL + ((size_t)(row * 132 + col)) * 8) = z;
}

// ---------------------------------------------------------------------------
// K-xt v2: thread per (pixel, channel-half), 32 loads unrolled to regs.
// ---------------------------------------------------------------------------
__global__ __launch_bounds__(256) void k_xt(const float* __restrict__ x,
                                            __bf16* __restrict__ xT,
                                            __bf16* __restrict__ xC)
{
  int t = blockIdx.x * 256 + threadIdx.x;
  if (t >= 8 * 134 * 134 * 2) return;
  int half = t & 1;
  int p  = t >> 1;
  int wp = p % 134;
  int hp = (p / 134) % 134;
  int b  = p / (134 * 134);
  int h = hp - 3, w = wp - 3;
  bool inb = ((unsigned)h < 128u) && ((unsigned)w < 128u);
  const float* xb = x + (size_t)b * Cn * HWn + (size_t)(half * 32) * HWn + h * 128 + w;

  float v[32];
#pragma unroll
  for (int j = 0; j < 32; j++) v[j] = inb ? xb[(size_t)j * HWn] : 0.f;

  __bf16* dstT = xT + (size_t)p * 64 + half * 32;
#pragma unroll
  for (int g = 0; g < 4; g++) {
    bf16x8 r;
#pragma unroll
    for (int j = 0; j < 8; j++) r[j] = (__bf16)v[g * 8 + j];
    *(bf16x8*)(dstT + g * 8) = r;
    int oct = half * 4 + g;
    *(bf16x8*)(xC + ((((size_t)b * 8 + oct) * 134 + hp) * 144 + wp) * 8) = r;
  }
}

// ---------------------------------------------------------------------------
// K1: STN conv1 via MFMA + fused 2x2 maxpool.
// ---------------------------------------------------------------------------
__global__ __launch_bounds__(256) void k_conv1m(
    const __bf16* __restrict__ xC, const __bf16* __restrict__ wfrag,
    const float* __restrict__ b1s, __bf16* __restrict__ p1T)
{
  __shared__ alignas(16) char tile[73728];
  const int lane = threadIdx.x & 63;
  const int wv   = threadIdx.x >> 6;
  const int swz  = xcd_swz(blockIdx.x, 64);
  const int b    = swz >> 6;
  const int h0   = (swz & 63) * 2;
  const int r    = wv >> 1;
  const int hf   = wv & 1;
  const int l15  = lane & 15;

  f32x4 acc[2][4];
#pragma unroll
  for (int o16 = 0; o16 < 2; o16++)
#pragma unroll
    for (int nf = 0; nf < 4; nf++) acc[o16][nf] = (f32x4){0.f, 0.f, 0.f, 0.f};

  const bf16x8* wf = (const bf16x8*)wfrag;
  const char* tb = (const char*)tile;
  const char* xCb = (const char*)xC;

  for (int ck = 0; ck < 2; ck++) {
    for (int i = wv; i < 72; i += 4) {
      int q = i / 18;
      int t = i - q * 18;
      const char* src = xCb
          + (((size_t)(b * 8 + ck * 4 + q) * 134 + h0) * 2304) + t * 1024 + lane * 16;
      char* dst = (char*)tile + i * 1024;
      __builtin_amdgcn_global_load_lds(
          (const __attribute__((address_space(1))) void*)src,
          (__attribute__((address_space(3))) void*)dst, 16, 0, 0);
    }
    __syncthreads();

    for (int tap = 0; tap < 49; tap++) {
      int dy7 = tap / 7;
      int dx7 = tap - dy7 * 7;
      bf16x8 a0 = wf[((tap * 2 + ck) * 2 + 0) * 64 + lane];
      bf16x8 a1 = wf[((tap * 2 + ck) * 2 + 1) * 64 + lane];
      const char* bp = tb + (lane >> 4) * 18432 + (r + dy7) * 2304
                          + (dx7 + hf * 64 + l15) * 16;
#pragma unroll
      for (int nf = 0; nf < 4; nf++) {
        bf16x8 bv = *(const bf16x8*)(bp + nf * 256);
        acc[0][nf] = __builtin_amdgcn_mfma_f32_16x16x32_bf16(a0, bv, acc[0][nf], 0, 0, 0);
        acc[1][nf] = __builtin_amdgcn_mfma_f32_16x16x32_bf16(a1, bv, acc[1][nf], 0, 0, 0);
      }
    }
    __syncthreads();
  }

#pragma unroll
  for (int o16 = 0; o16 < 2; o16++) {
    int ob = o16 * 16 + ((lane >> 4) << 2);
    float bb0 = b1s[ob], bb1 = b1s[ob + 1], bb2 = b1s[ob + 2], bb3 = b1s[ob + 3];
#pragma unroll
    for (int nf = 0; nf < 4; nf++) {
      int px = hf * 64 + nf * 16 + l15;
      bf16x4 rr;
      rr[0] = (__bf16)fmaxf(acc[o16][nf][0] + bb0, 0.f);
      rr[1] = (__bf16)fmaxf(acc[o16][nf][1] + bb1, 0.f);
      rr[2] = (__bf16)fmaxf(acc[o16][nf][2] + bb2, 0.f);
      rr[3] = (__bf16)fmaxf(acc[o16][nf][3] + bb3, 0.f);
      *(bf16x4*)((char*)tile + (size_t)(r * 128 + px) * 64 + ob * 2) = rr;
    }
  }
  __syncthreads();

  {
    int tid = threadIdx.x;
    int wp = tid >> 2, cg = tid & 3;
    const char* base = (const char*)tile;
    bf16x8 v00 = *(const bf16x8*)(base + (size_t)(0 * 128 + 2 * wp) * 64 + cg * 16);
    bf16x8 v01 = *(const bf16x8*)(base + (size_t)(0 * 128 + 2 * wp + 1) * 64 + cg * 16);
    bf16x8 v10 = *(const bf16x8*)(base + (size_t)(1 * 128 + 2 * wp) * 64 + cg * 16);
    bf16x8 v11 = *(const bf16x8*)(base + (size_t)(1 * 128 + 2 * wp + 1) * 64 + cg * 16);
    bf16x8 rr;
#pragma unroll
    for (int j = 0; j < 8; j++) {
      float m = fmaxf(fmaxf((float)v00[j], (float)v01[j]),
                      fmaxf((float)v10[j], (float)v11[j]));
      rr[j] = (__bf16)m;
    }
    int hp = (swz & 63) + 2;
    *(bf16x8*)(p1T + (((size_t)b * 68 + hp) * 68 + wp + 2) * 32 + cg * 8) = rr;
  }
}

// ---------------------------------------------------------------------------
// K3: conv2 via MFMA + fused deterministic feat reduction.
// ---------------------------------------------------------------------------
__global__ __launch_bounds__(256) void k_conv2m(
    const __bf16* __restrict__ p1T, const __bf16* __restrict__ w2frag,
    const float* __restrict__ b2s, float* __restrict__ partial)
{
  __shared__ alignas(16) char tile[34816];
  __shared__ float sm2[4][16][64];
  const int lane = threadIdx.x & 63;
  const int wv   = threadIdx.x >> 6;
  const int b    = blockIdx.x >> 4;
  const int tl   = blockIdx.x & 15;
  const int h0   = tl * 4;
  const int l15  = lane & 15;

  f32x4 acc[4][4];
#pragma unroll
  for (int mf = 0; mf < 4; mf++)
#pragma unroll
    for (int nf = 0; nf < 4; nf++) acc[mf][nf] = (f32x4){0.f, 0.f, 0.f, 0.f};

  const char* src0 = (const char*)p1T + (((size_t)b * 68 + h0) * 68) * 64;
  for (int i = wv; i < 34; i += 4) {
    __builtin_amdgcn_global_load_lds(
        (const __attribute__((address_space(1))) void*)(src0 + i * 1024 + lane * 16),
        (__attribute__((address_space(3))) void*)((char*)tile + i * 1024), 16, 0, 0);
  }
  __syncthreads();

  const bf16x8* wf = (const bf16x8*)w2frag;
  const char* tb = (const char*)tile;
  for (int tap = 0; tap < 25; tap++) {
    int ky = tap / 5, kx = tap - ky * 5;
    bf16x8 a0 = wf[(tap * 4 + 0) * 64 + lane];
    bf16x8 a1 = wf[(tap * 4 + 1) * 64 + lane];
    bf16x8 a2 = wf[(tap * 4 + 2) * 64 + lane];
    bf16x8 a3 = wf[(tap * 4 + 3) * 64 + lane];
    const char* bp = tb + (((wv + ky) * 68 + kx + l15) * 64) + (lane >> 4) * 16;
#pragma unroll
    for (int nf = 0; nf < 4; nf++) {
      bf16x8 bv = *(const bf16x8*)(bp + nf * 1024);
      acc[0][nf] = __builtin_amdgcn_mfma_f32_16x16x32_bf16(a0, bv, acc[0][nf], 0, 0, 0);
      acc[1][nf] = __builtin_amdgcn_mfma_f32_16x16x32_bf16(a1, bv, acc[1][nf], 0, 0, 0);
      acc[2][nf] = __builtin_amdgcn_mfma_f32_16x16x32_bf16(a2, bv, acc[2][nf], 0, 0, 0);
      acc[3][nf] = __builtin_amdgcn_mfma_f32_16x16x32_bf16(a3, bv, acc[3][nf], 0, 0, 0);
    }
  }

#pragma unroll
  for (int mf = 0; mf < 4; mf++) {
    int ob = mf * 16 + ((lane >> 4) << 2);
#pragma unroll
    for (int rr = 0; rr < 4; rr++) {
      float bb = b2s[ob + rr];
      float s = 0.f;
#pragma unroll
      for (int nf = 0; nf < 4; nf++)
        s += fmaxf(acc[mf][nf][rr] + bb, 0.f);
      sm2[wv][l15][ob + rr] = s;
    }
  }
  __syncthreads();
  if (threadIdx.x < 64) {
    float s = 0.f;
#pragma unroll
    for (int w2 = 0; w2 < 4; w2++)
      for (int l = 0; l < 16; l++) s += sm2[w2][l][threadIdx.x];
    partial[(size_t)(b * 16 + tl) * 64 + threadIdx.x] = s;
  }
}

// ---------------------------------------------------------------------------
// K4: theta.
// ---------------------------------------------------------------------------
__global__ __launch_bounds__(512) void k_theta(
    const float* __restrict__ partial, const float* __restrict__ fc_w,
    const float* __restrict__ fc_b, float* __restrict__ theta)
{
  __shared__ float featL[512];
  int tid = threadIdx.x;
  {
    int b = tid >> 6, co = tid & 63;
    float s = 0.f;
#pragma unroll
    for (int t = 0; t < 16; t++) s += partial[(size_t)(b * 16 + t) * 64 + co];
    featL[tid] = s;
  }
  __syncthreads();
  if (tid < 48) {
    int b = tid / 6, i = tid - b * 6;
    float s = 0.f;
    for (int k = 0; k < 64; k++) s = fmaf(featL[b * 64 + k], fc_w[i * 64 + k], s);
    theta[tid] = fmaf(s, 1.f / 4096.f, fc_b[i]);
  }
}

// ---------------------------------------------------------------------------
// Shared bilinear corner-address helper.
// ---------------------------------------------------------------------------
__device__ __forceinline__ void bilin_setup(
    const __bf16* __restrict__ xb, float sy, float sx,
    const __bf16*& c00, const __bf16*& c01,
    const __bf16*& c10, const __bf16*& c11,
    float& w00, float& w01, float& w10, float& w11)
{
  float y0f = floorf(sy), x0f = floorf(sx);
  float wy1 = sy - y0f, wy0 = 1.f - wy1;
  float wx1 = sx - x0f, wx0 = 1.f - wx1;
  bool vy0 = (y0f >= 0.f) && (y0f <= 127.f);
  bool vy1 = (y0f >= -1.f) && (y0f <= 126.f);
  bool vx0 = (x0f >= 0.f) && (x0f <= 127.f);
  bool vx1 = (x0f >= -1.f) && (x0f <= 126.f);
  int yi0 = (int)fminf(fmaxf(y0f, 0.f), 127.f);
  int yi1 = (int)fminf(fmaxf(y0f + 1.f, 0.f), 127.f);
  int xi0 = (int)fminf(fmaxf(x0f, 0.f), 127.f);
  int xi1 = (int)fminf(fmaxf(x0f + 1.f, 0.f), 127.f);
  w00 = wy0 * wx0 * ((vy0 && vx0) ? 1.f : 0.f);
  w01 = wy0 * wx1 * ((vy0 && vx1) ? 1.f : 0.f);
  w10 = wy1 * wx0 * ((vy1 && vx0) ? 1.f : 0.f);
  w11 = wy1 * wx1 * ((vy1 && vx1) ? 1.f : 0.f);
  c00 = xb + ((size_t)((yi0 + 3) * 134) + xi0 + 3) * 64;
  c01 = xb + ((size_t)((yi0 + 3) * 134) + xi1 + 3) * 64;
  c10 = xb + ((size_t)((yi1 + 3) * 134) + xi0 + 3) * 64;
  c11 = xb + ((size_t)((yi1 + 3) * 134) + xi1 + 3) * 64;
}

// ---------------------------------------------------------------------------
// K6 (R16): dcn + STN sample + FUSED SOFTMAX-WEIGHTED FUSION -> fusedT.
// Fs kept in regs; Fd in acc. s0/s1 built by quad-reduce (Fs) + 16-lane
// group reduce (Fd) + cross-layout shuffles; fd goes through a 2KB LDS
// transpose ([ch64][px16]) so Fs-layout lanes can read it; fused written
// directly to octet-planar fusedT. FsT/FdT buffers and k_fuseT eliminated.
// bf16-round of fs/fd BEFORE the fusion dot preserves prior numerics.
// ---------------------------------------------------------------------------
__global__ __launch_bounds__(64) void k_dcnm(
    const __bf16* __restrict__ xT, const float* __restrict__ off,
    const float* __restrict__ theta,
    const __bf16* __restrict__ dcnD, const float* __restrict__ dcn_b,
    const float* __restrict__ wg_w, const float* __restrict__ wg_b,
    __bf16* __restrict__ fusedT)
{
  __shared__ alignas(16) char smem[2][2048];
  const int lane = threadIdx.x;
  const int swz  = xcd_swz(blockIdx.x, 1024);
  const int b    = swz >> 10;
  const int rem  = swz & 1023;
  const int h    = rem >> 3;
  const int px0  = (rem & 7) * 16;
  const int l15  = lane & 15;
  const int g    = lane >> 4;
  const int pg   = lane >> 2;
  const int q    = lane & 3;
  const int wg   = px0 + pg;

  const __bf16* xb = xT + (size_t)b * 134 * 134 * 64;

  const float* ob = off + (size_t)b * 18 * HWn + h * 128 + wg;
  float offs[18];
#pragma unroll
  for (int i = 0; i < 18; i++) offs[i] = ob[(size_t)i * HWn];

  // ---- STN sample: keep in registers, accumulate Fs logit partials ----
  bf16x8 fs0c, fs1c;
  float s0s = 0.f, s1s = 0.f;
  {
    const float* t = theta + b * 6;
    float xn = (float)(2 * wg + 1) * (1.f / 128.f) - 1.f;
    float yn = (float)(2 * h + 1) * (1.f / 128.f) - 1.f;
    float gxv = t[0] * xn + t[1] * yn + t[2];
    float gyv = t[3] * xn + t[4] * yn + t[5];
    float ix = fmaf(gxv, 64.f, 63.5f);
    float iy = fmaf(gyv, 64.f, 63.5f);
    const __bf16 *c00, *c01, *c10, *c11;
    float w00, w01, w10, w11;
    bilin_setup(xb, iy, ix, c00, c01, c10, c11, w00, w01, w10, w11);
    {
      int eo = q * 8;
      bf16x8 v00 = *(const bf16x8*)(c00 + eo);
      bf16x8 v01 = *(const bf16x8*)(c01 + eo);
      bf16x8 v10 = *(const bf16x8*)(c10 + eo);
      bf16x8 v11 = *(const bf16x8*)(c11 + eo);
#pragma unroll
      for (int j = 0; j < 8; j++) {
        float f = w00 * (float)v00[j] + w01 * (float)v01[j]
                + w10 * (float)v10[j] + w11 * (float)v11[j];
        fs0c[j] = (__bf16)f;
      }
    }
    {
      int eo = q * 8 + 32;
      bf16x8 v00 = *(const bf16x8*)(c00 + eo);
      bf16x8 v01 = *(const bf16x8*)(c01 + eo);
      bf16x8 v10 = *(const bf16x8*)(c10 + eo);
      bf16x8 v11 = *(const bf16x8*)(c11 + eo);
#pragma unroll
      for (int j = 0; j < 8; j++) {
        float f = w00 * (float)v00[j] + w01 * (float)v01[j]
                + w10 * (float)v10[j] + w11 * (float)v11[j];
        fs1c[j] = (__bf16)f;
      }
    }
#pragma unroll
    for (int j = 0; j < 8; j++) {
      float f0 = (float)fs0c[j], f1 = (float)fs1c[j];
      s0s = fmaf(wg_w[q * 8 + j],       f0, fmaf(wg_w[32 + q * 8 + j],  f1, s0s));
      s1s = fmaf(wg_w[128 + q * 8 + j], f0, fmaf(wg_w[160 + q * 8 + j], f1, s1s));
    }
    s0s += __shfl_xor(s0s, 1); s0s += __shfl_xor(s0s, 2);
    s1s += __shfl_xor(s1s, 1); s1s += __shfl_xor(s1s, 2);
  }

  // ---- deformable conv: 9 taps (unchanged) ----
  f32x4 acc[4];
#pragma unroll
  for (int mf = 0; mf < 4; mf++) acc[mf] = (f32x4){0.f, 0.f, 0.f, 0.f};
  const bf16x8* aD = (const bf16x8*)dcnD;

#pragma unroll
  for (int k = 0; k < 9; k++) {
    char* sm = smem[k & 1];
    float sy = (float)(h + k / 3 - 1) + offs[2 * k];
    float sx = (float)(wg + k % 3 - 1) + offs[2 * k + 1];
    const __bf16 *c00, *c01, *c10, *c11;
    float w00, w01, w10, w11;
    bilin_setup(xb, sy, sx, c00, c01, c10, c11, w00, w01, w10, w11);

#pragma unroll
    for (int s = 0; s < 2; s++) {
      int eo = q * 8 + s * 32;
      bf16x8 v00 = *(const bf16x8*)(c00 + eo);
      bf16x8 v01 = *(const bf16x8*)(c01 + eo);
      bf16x8 v10 = *(const bf16x8*)(c10 + eo);
      bf16x8 v11 = *(const bf16x8*)(c11 + eo);
      bf16x8 r;
#pragma unroll
      for (int j = 0; j < 8; j++) {
        float f = w00 * (float)v00[j] + w01 * (float)v01[j]
                + w10 * (float)v10[j] + w11 * (float)v11[j];
        r[j] = (__bf16)f;
      }
      int c = s * 4 + q;
      *(bf16x8*)(sm + pg * 128 + ((c ^ (pg & 7)) * 16)) = r;
    }

#pragma unroll
    for (int s = 0; s < 2; s++) {
      int c = s * 4 + g;
      bf16x8 a = *(const bf16x8*)(sm + l15 * 128 + ((c ^ (l15 & 7)) * 16));
      acc[0] = __builtin_amdgcn_mfma_f32_16x16x32_bf16(
          a, aD[((k * 2 + s) * 4 + 0) * 64 + lane], acc[0], 0, 0, 0);
      acc[1] = __builtin_amdgcn_mfma_f32_16x16x32_bf16(
          a, aD[((k * 2 + s) * 4 + 1) * 64 + lane], acc[1], 0, 0, 0);
      acc[2] = __builtin_amdgcn_mfma_f32_16x16x32_bf16(
          a, aD[((k * 2 + s) * 4 + 2) * 64 + lane], acc[2], 0, 0, 0);
      acc[3] = __builtin_amdgcn_mfma_f32_16x16x32_bf16(
          a, aD[((k * 2 + s) * 4 + 3) * 64 + lane], acc[3], 0, 0, 0);
    }
  }

  // ---- fused epilogue ----
  // fd (rounded) + Fd logit partials per pixel r of group g
  float fdb_f[4][4];
  float s0d[4] = {0.f, 0.f, 0.f, 0.f};
  float s1d[4] = {0.f, 0.f, 0.f, 0.f};
#pragma unroll
  for (int mf = 0; mf < 4; mf++) {
    int o = mf * 16 + l15;
    float bias = dcn_b[o];
    float w0 = wg_w[64 + o], w1 = wg_w[192 + o];
#pragma unroll
    for (int r = 0; r < 4; r++) {
      __bf16 fb = (__bf16)(acc[mf][r] + bias);
      float fv = (float)fb;
      fdb_f[mf][r] = fv;
      s0d[r] = fmaf(w0, fv, s0d[r]);
      s1d[r] = fmaf(w1, fv, s1d[r]);
    }
  }
#pragma unroll
  for (int m = 1; m < 16; m <<= 1) {
#pragma unroll
    for (int r = 0; r < 4; r++) {
      s0d[r] += __shfl_xor(s0d[r], m);
      s1d[r] += __shfl_xor(s1d[r], m);
    }
  }

  // combine logits per pixel (g*4+r); fetch Fs totals from quad leader
  float p0v0, p0v1, p0v2, p0v3;
  {
    float ss0, ss1, S0, S1;
    ss0 = __shfl(s0s, (g * 4 + 0) * 4); ss1 = __shfl(s1s, (g * 4 + 0) * 4);
    S0 = ss0 + s0d[0] + wg_b[0]; S1 = ss1 + s1d[0] + wg_b[1];
    p0v0 = 1.f / (1.f + __expf(S1 - S0));
    ss0 = __shfl(s0s, (g * 4 + 1) * 4); ss1 = __shfl(s1s, (g * 4 + 1) * 4);
    S0 = ss0 + s0d[1] + wg_b[0]; S1 = ss1 + s1d[1] + wg_b[1];
    p0v1 = 1.f / (1.f + __expf(S1 - S0));
    ss0 = __shfl(s0s, (g * 4 + 2) * 4); ss1 = __shfl(s1s, (g * 4 + 2) * 4);
    S0 = ss0 + s0d[2] + wg_b[0]; S1 = ss1 + s1d[2] + wg_b[1];
    p0v2 = 1.f / (1.f + __expf(S1 - S0));
    ss0 = __shfl(s0s, (g * 4 + 3) * 4); ss1 = __shfl(s1s, (g * 4 + 3) * 4);
    S0 = ss0 + s0d[3] + wg_b[0]; S1 = ss1 + s1d[3] + wg_b[1];
    p0v3 = 1.f / (1.f + __expf(S1 - S0));
  }

  // fd -> LDS transpose [ch64][px16] bf16 (reuse smem[0]); p0 -> smem[1]
  __bf16* fdb16 = (__bf16*)smem[0];
#pragma unroll
  for (int mf = 0; mf < 4; mf++) {
    bf16x4 v;
#pragma unroll
    for (int r = 0; r < 4; r++) v[r] = (__bf16)fdb_f[mf][r];
    *(bf16x4*)(fdb16 + (mf * 16 + l15) * 16 + g * 4) = v;
  }
  float* p0b = (float*)smem[1];
  if (l15 == 0) p0b[g * 4 + 0] = p0v0;
  if (l15 == 1) p0b[g * 4 + 1] = p0v1;
  if (l15 == 2) p0b[g * 4 + 2] = p0v2;
  if (l15 == 3) p0b[g * 4 + 3] = p0v3;

  float p0 = p0b[pg];
  float p1 = 1.f - p0;

  // fused chunk in Fs layout; write octet-planar fusedT (pad ring pre-zeroed)
  bf16x8 o0, o1;
#pragma unroll
  for (int j = 0; j < 8; j++) {
    float fd0 = (float)fdb16[(q * 8 + j) * 16 + pg];
    float fd1 = (float)fdb16[(32 + q * 8 + j) * 16 + pg];
    o0[j] = (__bf16)(p0 * (float)fs0c[j] + p1 * fd0);
    o1[j] = (__bf16)(p0 * (float)fs1c[j] + p1 * fd1);
  }
  size_t ppix = (size_t)((h + 2) * 132 + wg + 2) * 8;
  *(bf16x8*)(fusedT + ((size_t)b * 8 + q) * FPL + ppix) = o0;
  *(bf16x8*)(fusedT + ((size_t)b * 8 + 4 + q) * FPL + ppix) = o1;
}

// ---------------------------------------------------------------------------
// K8: collapsed ELK via MFMA, planar fusedT reads (unchanged).
// ---------------------------------------------------------------------------
__global__ __launch_bounds__(256) void k_elkm(
    const __bf16* __restrict__ fusedT, const __bf16* __restrict__ weffD,
    const float* __restrict__ beff, float* __restrict__ out)
{
  const int DY[13] = {-2,-1,-1,-1, 0, 0, 0, 0, 0, 1, 1, 1, 2};
  const int DX[13] = { 0,-1, 0, 1,-2,-1, 0, 1, 2,-1, 0, 1, 0};
  const int lane = threadIdx.x & 63;
  const int wv   = threadIdx.x >> 6;
  const int swz  = xcd_swz(blockIdx.x, 64);
  const int b    = swz >> 6;
  const int h    = (swz & 63) * 2 + (wv >> 1);
  const int half = wv & 1;
  const int l15  = lane & 15;
  const int g    = lane >> 4;

  f32x4 acc[4][4];
#pragma unroll
  for (int mf = 0; mf < 4; mf++)
#pragma unroll
    for (int nf = 0; nf < 4; nf++) acc[mf][nf] = (f32x4){0.f, 0.f, 0.f, 0.f};

  const bf16x8* aD = (const bf16x8*)weffD;
  const __bf16* pl0 = fusedT + ((size_t)b * 8 + g) * FPL;
  const __bf16* pl1 = pl0 + 4 * FPL;

  for (int t = 0; t < 13; t++) {
    int hp = h + 2 + DY[t];
    size_t rowb = (size_t)(hp * 132 + half * 64 + 2 + DX[t] + l15) * 8;
#pragma unroll
    for (int s = 0; s < 2; s++) {
      const __bf16* pl = s ? pl1 : pl0;
      bf16x8 a0 = aD[((t * 2 + s) * 4 + 0) * 64 + lane];
      bf16x8 a1 = aD[((t * 2 + s) * 4 + 1) * 64 + lane];
      bf16x8 a2 = aD[((t * 2 + s) * 4 + 2) * 64 + lane];
      bf16x8 a3 = aD[((t * 2 + s) * 4 + 3) * 64 + lane];
#pragma unroll
      for (int nf = 0; nf < 4; nf++) {
        bf16x8 bv = *(const bf16x8*)(pl + rowb + (size_t)nf * 128);
        acc[0][nf] = __builtin_amdgcn_mfma_f32_16x16x32_bf16(a0, bv, acc[0][nf], 0, 0, 0);
        acc[1][nf] = __builtin_amdgcn_mfma_f32_16x16x32_bf16(a1, bv, acc[1][nf], 0, 0, 0);
        acc[2][nf] = __builtin_amdgcn_mfma_f32_16x16x32_bf16(a2, bv, acc[2][nf], 0, 0, 0);
        acc[3][nf] = __builtin_amdgcn_mfma_f32_16x16x32_bf16(a3, bv, acc[3][nf], 0, 0, 0);
      }
    }
  }

#pragma unroll
  for (int mf = 0; mf < 4; mf++) {
    int ob = mf * 16 + (g << 2);
#pragma unroll
    for (int r = 0; r < 4; r++) {
      int o = ob + r;
      float bb = beff[o];
      float* orow = out + ((size_t)(b * 64 + o)) * HWn + h * 128 + half * 64 + l15;
#pragma unroll
      for (int nf = 0; nf < 4; nf++)
        orow[nf * 16] = acc[mf][nf][r] + bb;
    }
  }
}

// ---------------------------------------------------------------------------
// Workspace (FLOAT offsets, sizes verified):
// Region A [0, 4,596,736): xT (k_xt .. k_dcnm).
// Region B [4,596,736, 9,536,512): xC (k_xt .. conv1m) -> fusedT (4,460,544
//   fl; pads zeroed by k_zpad after conv1m; interior by k_dcnm) -> elkm.
// Region C: p1T @11,633,664 (591,872 fl); partial @12,225,536 (8,192 fl).
// Tail: theta @14,323,200 | wfrag @14,323,264 | w2frag @14,373,440 |
//       beff @14,399,040 | dcnD @14,399,104 | weffD @14,417,536.
// ---------------------------------------------------------------------------
extern "C" void kernel_launch(void* const* d_in, const int* in_sizes, int n_in,
                              void* d_out, int out_size, void* d_ws, size_t ws_size,
                              hipStream_t stream)
{
  (void)in_sizes; (void)n_in; (void)out_size; (void)ws_size;
  const float* x      = (const float*)d_in[0];
  const float* offset = (const float*)d_in[1];
  const float* stn_w1 = (const float*)d_in[2];
  const float* stn_b1 = (const float*)d_in[3];
  const float* stn_w2 = (const float*)d_in[4];
  const float* stn_b2 = (const float*)d_in[5];
  const float* fc_w   = (const float*)d_in[6];
  const float* fc_b   = (const float*)d_in[7];
  const float* dcn_w  = (const float*)d_in[8];
  const float* dcn_b  = (const float*)d_in[9];
  const float* wg_w   = (const float*)d_in[10];
  const float* wg_b   = (const float*)d_in[11];
  const float* w3     = (const float*)d_in[12];
  const float* b3     = (const float*)d_in[13];
  const float* w15    = (const float*)d_in[14];
  const float* b15    = (const float*)d_in[15];
  const float* w51    = (const float*)d_in[16];
  const float* b51    = (const float*)d_in[17];
  const float* w1     = (const float*)d_in[18];
  const float* b1     = (const float*)d_in[19];

  float* ws      = (float*)d_ws;
  __bf16* xT     = (__bf16*)ws;
  __bf16* xC     = (__bf16*)(ws + 4596736);
  __bf16* fusedT = (__bf16*)(ws + 4596736);
  __bf16* p1T    = (__bf16*)(ws + 11633664);
  float*  partial= ws + 12225536;
  float*  theta  = ws + 14323200;
  __bf16* wfrag  = (__bf16*)(ws + 14323264);
  __bf16* w2frag = (__bf16*)(ws + 14373440);
  float*  beff   = ws + 14399040;
  __bf16* dcnD   = (__bf16*)(ws + 14399104);
  __bf16* weffD  = (__bf16*)(ws + 14417536);
  float*  out    = (float*)d_out;

  k_wprep <<<1234, 256, 0, stream>>>(stn_w1, dcn_w, w1, w3, w15, w51, stn_w2,
                                     b3, b15, b51, b1,
                                     wfrag, dcnD, weffD, w2frag, beff, p1T);
  k_xt    <<<1123, 256, 0, stream>>>(x, xT, xC);
  k_conv1m<<<512,  256, 0, stream>>>(xC, wfrag, stn_b1, p1T);
  k_conv2m<<<128,  256, 0, stream>>>(p1T, w2frag, stn_b2, partial);
  k_theta <<<1,    512, 0, stream>>>(partial, fc_w, fc_b, theta);
  k_zpad  <<<260,  256, 0, stream>>>(fusedT);
  k_dcnm  <<<8192, 64,  0, stream>>>(xT, offset, theta, dcnD, dcn_b,
                                     wg_w, wg_b, fusedT);
  k_elkm  <<<512,  256, 0, stream>>>(fusedT, weffD, beff, out);
}

// Round 17
// 166.400 us; speedup vs baseline: 1.1922x; 1.0100x over previous
//
#include <hip/hip_runtime.h>
#include <math.h>

// Problem dims
#define Bn 8
#define Cn 64
#define Hn 128
#define Wn 128
#define HWn 16384

typedef __attribute__((ext_vector_type(8))) __bf16 bf16x8;
typedef __attribute__((ext_vector_type(4))) __bf16 bf16x4;
typedef __attribute__((ext_vector_type(4))) float f32x4;

__device__ __forceinline__ int xcd_swz(int bid, int chunk) {
  return (bid & 7) * chunk + (bid >> 3);
}

// ---------------------------------------------------------------------------
// K-wprep: merged weight prep + p1T pad zeroing.
// ---------------------------------------------------------------------------
__global__ __launch_bounds__(256) void k_wprep(
    const float* __restrict__ stn_w1, const float* __restrict__ dcn_w,
    const float* __restrict__ w1, const float* __restrict__ w3,
    const float* __restrict__ w15, const float* __restrict__ w51,
    const float* __restrict__ stn_w2,
    const float* __restrict__ b3, const float* __restrict__ b15,
    const float* __restrict__ b51, const float* __restrict__ b1,
    __bf16* __restrict__ wfrag, __bf16* __restrict__ dcnD,
    __bf16* __restrict__ weffD, __bf16* __restrict__ w2frag,
    float* __restrict__ beff, __bf16* __restrict__ p1T)
{
  int t = blockIdx.x * 256 + threadIdx.x;
  if (t < 100352) {
    int e = t & 7, l = (t >> 3) & 63, o16 = (t >> 9) & 1, ck = (t >> 10) & 1;
    int tap = t >> 11;
    int o = o16 * 16 + (l & 15), c = ck * 32 + (l >> 4) * 8 + e;
    wfrag[t] = (__bf16)stn_w1[(o * 64 + c) * 49 + tap];
    return;
  }
  t -= 100352;
  if (t < 36864) {
    int e = t & 7, l = (t >> 3) & 63, mf = (t >> 9) & 3, s = (t >> 11) & 1;
    int tap = t >> 12;
    int o = mf * 16 + (l & 15), c = s * 32 + (l >> 4) * 8 + e;
    dcnD[t] = (__bf16)dcn_w[(o * 64 + c) * 9 + tap];
    return;
  }
  t -= 36864;
  if (t < 53248) {
    const int DY[13] = {-2,-1,-1,-1, 0, 0, 0, 0, 0, 1, 1, 1, 2};
    const int DX[13] = { 0,-1, 0, 1,-2,-1, 0, 1, 2,-1, 0, 1, 0};
    int e = t & 7, l = (t >> 3) & 63, mf = (t >> 9) & 3, s = (t >> 11) & 1;
    int tap = t >> 12;
    int o = mf * 16 + (l & 15), c = s * 32 + (l >> 4) * 8 + e;
    int dy = DY[tap], dx = DX[tap];
    float v = 0.f;
    if (dy >= -1 && dy <= 1 && dx >= -1 && dx <= 1) {
      int k3 = (dy + 1) * 3 + (dx + 1);
      for (int m = 0; m < 64; m++) v = fmaf(w1[o * 192 + m], w3[(m * 64 + c) * 9 + k3], v);
    }
    if (dy == 0) {
      int k15 = dx + 2;
      for (int m = 0; m < 64; m++) v = fmaf(w1[o * 192 + 64 + m], w15[(m * 64 + c) * 5 + k15], v);
    }
    if (dx == 0) {
      int k51 = dy + 2;
      for (int m = 0; m < 64; m++) v = fmaf(w1[o * 192 + 128 + m], w51[(m * 64 + c) * 5 + k51], v);
    }
    weffD[t] = (__bf16)v;
    return;
  }
  t -= 53248;
  if (t < 51200) {
    int e = t & 7, l = (t >> 3) & 63, mf = (t >> 9) & 3;
    int tap = t >> 11;
    int o = mf * 16 + (l & 15), c = (l >> 4) * 8 + e;
    w2frag[t] = (__bf16)stn_w2[(o * 32 + c) * 25 + tap];
    return;
  }
  t -= 51200;
  if (t < 64) {
    float s = b1[t];
    for (int m = 0; m < 64; m++) {
      s = fmaf(w1[t * 192 + m],       b3[m],  s);
      s = fmaf(w1[t * 192 + 64 + m],  b15[m], s);
      s = fmaf(w1[t * 192 + 128 + m], b51[m], s);
    }
    beff[t] = s;
    return;
  }
  t -= 64;
  if (t < 73984) {                        // zero all of p1T
    bf16x8 z = {};
    *(bf16x8*)(p1T + (size_t)t * 16) = z;
    *(bf16x8*)(p1T + (size_t)t * 16 + 8) = z;
  }
}

// ---------------------------------------------------------------------------
// K-xt v3 (R17): half selected by BLOCK range (blocks 0..561 = ch 0..31,
// 562..1123 = ch 32..63) so a 4-lane quad covers 4 consecutive pixels of one
// channel-half: x reads become 16B/line/quad (4x fewer TA requests; R11
// quad-coalescing model), xC writes 64B/quad.
// ---------------------------------------------------------------------------
__global__ __launch_bounds__(256) void k_xt(const float* __restrict__ x,
                                            __bf16* __restrict__ xT,
                                            __bf16* __restrict__ xC)
{
  int half = (blockIdx.x >= 562) ? 1 : 0;
  int p = (blockIdx.x - half * 562) * 256 + threadIdx.x;
  if (p >= 8 * 134 * 134) return;
  int wp = p % 134;
  int hp = (p / 134) % 134;
  int b  = p / (134 * 134);
  int h = hp - 3, w = wp - 3;
  bool inb = ((unsigned)h < 128u) && ((unsigned)w < 128u);
  const float* xb = x + (size_t)b * Cn * HWn + (size_t)(half * 32) * HWn + h * 128 + w;

  float v[32];
#pragma unroll
  for (int j = 0; j < 32; j++) v[j] = inb ? xb[(size_t)j * HWn] : 0.f;

  __bf16* dstT = xT + (size_t)p * 64 + half * 32;
#pragma unroll
  for (int g = 0; g < 4; g++) {
    bf16x8 r;
#pragma unroll
    for (int j = 0; j < 8; j++) r[j] = (__bf16)v[g * 8 + j];
    *(bf16x8*)(dstT + g * 8) = r;
    int oct = half * 4 + g;
    *(bf16x8*)(xC + ((((size_t)b * 8 + oct) * 134 + hp) * 144 + wp) * 8) = r;
  }
}

// ---------------------------------------------------------------------------
// K1: STN conv1 via MFMA + fused 2x2 maxpool (unchanged from R16).
// ---------------------------------------------------------------------------
__global__ __launch_bounds__(256) void k_conv1m(
    const __bf16* __restrict__ xC, const __bf16* __restrict__ wfrag,
    const float* __restrict__ b1s, __bf16* __restrict__ p1T)
{
  __shared__ alignas(16) char tile[73728];
  const int lane = threadIdx.x & 63;
  const int wv   = threadIdx.x >> 6;
  const int swz  = xcd_swz(blockIdx.x, 64);
  const int b    = swz >> 6;
  const int h0   = (swz & 63) * 2;
  const int r    = wv >> 1;
  const int hf   = wv & 1;
  const int l15  = lane & 15;

  f32x4 acc[2][4];
#pragma unroll
  for (int o16 = 0; o16 < 2; o16++)
#pragma unroll
    for (int nf = 0; nf < 4; nf++) acc[o16][nf] = (f32x4){0.f, 0.f, 0.f, 0.f};

  const bf16x8* wf = (const bf16x8*)wfrag;
  const char* tb = (const char*)tile;
  const char* xCb = (const char*)xC;

  for (int ck = 0; ck < 2; ck++) {
    for (int i = wv; i < 72; i += 4) {
      int q = i / 18;
      int t = i - q * 18;
      const char* src = xCb
          + (((size_t)(b * 8 + ck * 4 + q) * 134 + h0) * 2304) + t * 1024 + lane * 16;
      char* dst = (char*)tile + i * 1024;
      __builtin_amdgcn_global_load_lds(
          (const __attribute__((address_space(1))) void*)src,
          (__attribute__((address_space(3))) void*)dst, 16, 0, 0);
    }
    __syncthreads();

    for (int tap = 0; tap < 49; tap++) {
      int dy7 = tap / 7;
      int dx7 = tap - dy7 * 7;
      bf16x8 a0 = wf[((tap * 2 + ck) * 2 + 0) * 64 + lane];
      bf16x8 a1 = wf[((tap * 2 + ck) * 2 + 1) * 64 + lane];
      const char* bp = tb + (lane >> 4) * 18432 + (r + dy7) * 2304
                          + (dx7 + hf * 64 + l15) * 16;
#pragma unroll
      for (int nf = 0; nf < 4; nf++) {
        bf16x8 bv = *(const bf16x8*)(bp + nf * 256);
        acc[0][nf] = __builtin_amdgcn_mfma_f32_16x16x32_bf16(a0, bv, acc[0][nf], 0, 0, 0);
        acc[1][nf] = __builtin_amdgcn_mfma_f32_16x16x32_bf16(a1, bv, acc[1][nf], 0, 0, 0);
      }
    }
    __syncthreads();
  }

#pragma unroll
  for (int o16 = 0; o16 < 2; o16++) {
    int ob = o16 * 16 + ((lane >> 4) << 2);
    float bb0 = b1s[ob], bb1 = b1s[ob + 1], bb2 = b1s[ob + 2], bb3 = b1s[ob + 3];
#pragma unroll
    for (int nf = 0; nf < 4; nf++) {
      int px = hf * 64 + nf * 16 + l15;
      bf16x4 rr;
      rr[0] = (__bf16)fmaxf(acc[o16][nf][0] + bb0, 0.f);
      rr[1] = (__bf16)fmaxf(acc[o16][nf][1] + bb1, 0.f);
      rr[2] = (__bf16)fmaxf(acc[o16][nf][2] + bb2, 0.f);
      rr[3] = (__bf16)fmaxf(acc[o16][nf][3] + bb3, 0.f);
      *(bf16x4*)((char*)tile + (size_t)(r * 128 + px) * 64 + ob * 2) = rr;
    }
  }
  __syncthreads();

  {
    int tid = threadIdx.x;
    int wp = tid >> 2, cg = tid & 3;
    const char* base = (const char*)tile;
    bf16x8 v00 = *(const bf16x8*)(base + (size_t)(0 * 128 + 2 * wp) * 64 + cg * 16);
    bf16x8 v01 = *(const bf16x8*)(base + (size_t)(0 * 128 + 2 * wp + 1) * 64 + cg * 16);
    bf16x8 v10 = *(const bf16x8*)(base + (size_t)(1 * 128 + 2 * wp) * 64 + cg * 16);
    bf16x8 v11 = *(const bf16x8*)(base + (size_t)(1 * 128 + 2 * wp + 1) * 64 + cg * 16);
    bf16x8 rr;
#pragma unroll
    for (int j = 0; j < 8; j++) {
      float m = fmaxf(fmaxf((float)v00[j], (float)v01[j]),
                      fmaxf((float)v10[j], (float)v11[j]));
      rr[j] = (__bf16)m;
    }
    int hp = (swz & 63) + 2;
    *(bf16x8*)(p1T + (((size_t)b * 68 + hp) * 68 + wp + 2) * 32 + cg * 8) = rr;
  }
}

// ---------------------------------------------------------------------------
// K3 (R17): conv2 via MFMA + fused feat reduction + ABSORBED fusedT pad
// zeroing (former k_zpad; same dependency point: after conv1m).
// Blocks 0..127: conv2; blocks 128..387: pad zeroing.
// ---------------------------------------------------------------------------
#define FPL ((size_t)132 * 132 * 8)
__global__ __launch_bounds__(256) void k_conv2m(
    const __bf16* __restrict__ p1T, const __bf16* __restrict__ w2frag,
    const float* __restrict__ b2s, float* __restrict__ partial,
    __bf16* __restrict__ fusedT)
{
  if (blockIdx.x >= 128) {                // ---- pad-zero section ----
    int t = (blockIdx.x - 128) * 256 + threadIdx.x;
    if (t >= 66560) return;
    int pp = t % 1040;
    int po = (t / 1040) & 7;
    int b  = t / 8320;
    int row, col;
    if (pp < 528) {
      int rr = pp / 132;
      row = (rr < 2) ? rr : 128 + rr;
      col = pp % 132;
    } else {
      int q2 = pp - 528;
      row = 2 + (q2 >> 2);
      int cs = q2 & 3;
      col = (cs < 2) ? cs : 128 + cs;
    }
    bf16x8 z = {};
    *(bf16x8*)(fusedT + ((size_t)b * 8 + po) * FPL + ((size_t)(row * 132 + col)) * 8) = z;
    return;
  }

  __shared__ alignas(16) char tile[34816];
  __shared__ float sm2[4][16][64];
  const int lane = threadIdx.x & 63;
  const int wv   = threadIdx.x >> 6;
  const int b    = blockIdx.x >> 4;
  const int tl   = blockIdx.x & 15;
  const int h0   = tl * 4;
  const int l15  = lane & 15;

  f32x4 acc[4][4];
#pragma unroll
  for (int mf = 0; mf < 4; mf++)
#pragma unroll
    for (int nf = 0; nf < 4; nf++) acc[mf][nf] = (f32x4){0.f, 0.f, 0.f, 0.f};

  const char* src0 = (const char*)p1T + (((size_t)b * 68 + h0) * 68) * 64;
  for (int i = wv; i < 34; i += 4) {
    __builtin_amdgcn_global_load_lds(
        (const __attribute__((address_space(1))) void*)(src0 + i * 1024 + lane * 16),
        (__attribute__((address_space(3))) void*)((char*)tile + i * 1024), 16, 0, 0);
  }
  __syncthreads();

  const bf16x8* wf = (const bf16x8*)w2frag;
  const char* tb = (const char*)tile;
  for (int tap = 0; tap < 25; tap++) {
    int ky = tap / 5, kx = tap - ky * 5;
    bf16x8 a0 = wf[(tap * 4 + 0) * 64 + lane];
    bf16x8 a1 = wf[(tap * 4 + 1) * 64 + lane];
    bf16x8 a2 = wf[(tap * 4 + 2) * 64 + lane];
    bf16x8 a3 = wf[(tap * 4 + 3) * 64 + lane];
    const char* bp = tb + (((wv + ky) * 68 + kx + l15) * 64) + (lane >> 4) * 16;
#pragma unroll
    for (int nf = 0; nf < 4; nf++) {
      bf16x8 bv = *(const bf16x8*)(bp + nf * 1024);
      acc[0][nf] = __builtin_amdgcn_mfma_f32_16x16x32_bf16(a0, bv, acc[0][nf], 0, 0, 0);
      acc[1][nf] = __builtin_amdgcn_mfma_f32_16x16x32_bf16(a1, bv, acc[1][nf], 0, 0, 0);
      acc[2][nf] = __builtin_amdgcn_mfma_f32_16x16x32_bf16(a2, bv, acc[2][nf], 0, 0, 0);
      acc[3][nf] = __builtin_amdgcn_mfma_f32_16x16x32_bf16(a3, bv, acc[3][nf], 0, 0, 0);
    }
  }

#pragma unroll
  for (int mf = 0; mf < 4; mf++) {
    int ob = mf * 16 + ((lane >> 4) << 2);
#pragma unroll
    for (int rr = 0; rr < 4; rr++) {
      float bb = b2s[ob + rr];
      float s = 0.f;
#pragma unroll
      for (int nf = 0; nf < 4; nf++)
        s += fmaxf(acc[mf][nf][rr] + bb, 0.f);
      sm2[wv][l15][ob + rr] = s;
    }
  }
  __syncthreads();
  if (threadIdx.x < 64) {
    float s = 0.f;
#pragma unroll
    for (int w2 = 0; w2 < 4; w2++)
      for (int l = 0; l < 16; l++) s += sm2[w2][l][threadIdx.x];
    partial[(size_t)(b * 16 + tl) * 64 + threadIdx.x] = s;
  }
}

// ---------------------------------------------------------------------------
// K4: theta.
// ---------------------------------------------------------------------------
__global__ __launch_bounds__(512) void k_theta(
    const float* __restrict__ partial, const float* __restrict__ fc_w,
    const float* __restrict__ fc_b, float* __restrict__ theta)
{
  __shared__ float featL[512];
  int tid = threadIdx.x;
  {
    int b = tid >> 6, co = tid & 63;
    float s = 0.f;
#pragma unroll
    for (int t = 0; t < 16; t++) s += partial[(size_t)(b * 16 + t) * 64 + co];
    featL[tid] = s;
  }
  __syncthreads();
  if (tid < 48) {
    int b = tid / 6, i = tid - b * 6;
    float s = 0.f;
    for (int k = 0; k < 64; k++) s = fmaf(featL[b * 64 + k], fc_w[i * 64 + k], s);
    theta[tid] = fmaf(s, 1.f / 4096.f, fc_b[i]);
  }
}

// ---------------------------------------------------------------------------
// Shared bilinear corner-address helper.
// ---------------------------------------------------------------------------
__device__ __forceinline__ void bilin_setup(
    const __bf16* __restrict__ xb, float sy, float sx,
    const __bf16*& c00, const __bf16*& c01,
    const __bf16*& c10, const __bf16*& c11,
    float& w00, float& w01, float& w10, float& w11)
{
  float y0f = floorf(sy), x0f = floorf(sx);
  float wy1 = sy - y0f, wy0 = 1.f - wy1;
  float wx1 = sx - x0f, wx0 = 1.f - wx1;
  bool vy0 = (y0f >= 0.f) && (y0f <= 127.f);
  bool vy1 = (y0f >= -1.f) && (y0f <= 126.f);
  bool vx0 = (x0f >= 0.f) && (x0f <= 127.f);
  bool vx1 = (x0f >= -1.f) && (x0f <= 126.f);
  int yi0 = (int)fminf(fmaxf(y0f, 0.f), 127.f);
  int yi1 = (int)fminf(fmaxf(y0f + 1.f, 0.f), 127.f);
  int xi0 = (int)fminf(fmaxf(x0f, 0.f), 127.f);
  int xi1 = (int)fminf(fmaxf(x0f + 1.f, 0.f), 127.f);
  w00 = wy0 * wx0 * ((vy0 && vx0) ? 1.f : 0.f);
  w01 = wy0 * wx1 * ((vy0 && vx1) ? 1.f : 0.f);
  w10 = wy1 * wx0 * ((vy1 && vx0) ? 1.f : 0.f);
  w11 = wy1 * wx1 * ((vy1 && vx1) ? 1.f : 0.f);
  c00 = xb + ((size_t)((yi0 + 3) * 134) + xi0 + 3) * 64;
  c01 = xb + ((size_t)((yi0 + 3) * 134) + xi1 + 3) * 64;
  c10 = xb + ((size_t)((yi1 + 3) * 134) + xi0 + 3) * 64;
  c11 = xb + ((size_t)((yi1 + 3) * 134) + xi1 + 3) * 64;
}

// ---------------------------------------------------------------------------
// K6: dcn + STN sample + fused softmax fusion -> fusedT.
// R17: fdb16 re-laid at stride-20 elements (40B rows): read banks
// q*16+j*10+(pg>>1) are <=2-way (free); 8B-aligned writes. Bank conflicts
// 2.36M -> ~1.2M expected.
// ---------------------------------------------------------------------------
__global__ __launch_bounds__(64) void k_dcnm(
    const __bf16* __restrict__ xT, const float* __restrict__ off,
    const float* __restrict__ theta,
    const __bf16* __restrict__ dcnD, const float* __restrict__ dcn_b,
    const float* __restrict__ wg_w, const float* __restrict__ wg_b,
    __bf16* __restrict__ fusedT)
{
  __shared__ alignas(16) char smem[4096];
  const int lane = threadIdx.x;
  const int swz  = xcd_swz(blockIdx.x, 1024);
  const int b    = swz >> 10;
  const int rem  = swz & 1023;
  const int h    = rem >> 3;
  const int px0  = (rem & 7) * 16;
  const int l15  = lane & 15;
  const int g    = lane >> 4;
  const int pg   = lane >> 2;
  const int q    = lane & 3;
  const int wg   = px0 + pg;

  const __bf16* xb = xT + (size_t)b * 134 * 134 * 64;

  const float* ob = off + (size_t)b * 18 * HWn + h * 128 + wg;
  float offs[18];
#pragma unroll
  for (int i = 0; i < 18; i++) offs[i] = ob[(size_t)i * HWn];

  // ---- STN sample: keep in registers, accumulate Fs logit partials ----
  bf16x8 fs0c, fs1c;
  float s0s = 0.f, s1s = 0.f;
  {
    const float* t = theta + b * 6;
    float xn = (float)(2 * wg + 1) * (1.f / 128.f) - 1.f;
    float yn = (float)(2 * h + 1) * (1.f / 128.f) - 1.f;
    float gxv = t[0] * xn + t[1] * yn + t[2];
    float gyv = t[3] * xn + t[4] * yn + t[5];
    float ix = fmaf(gxv, 64.f, 63.5f);
    float iy = fmaf(gyv, 64.f, 63.5f);
    const __bf16 *c00, *c01, *c10, *c11;
    float w00, w01, w10, w11;
    bilin_setup(xb, iy, ix, c00, c01, c10, c11, w00, w01, w10, w11);
    {
      int eo = q * 8;
      bf16x8 v00 = *(const bf16x8*)(c00 + eo);
      bf16x8 v01 = *(const bf16x8*)(c01 + eo);
      bf16x8 v10 = *(const bf16x8*)(c10 + eo);
      bf16x8 v11 = *(const bf16x8*)(c11 + eo);
#pragma unroll
      for (int j = 0; j < 8; j++) {
        float f = w00 * (float)v00[j] + w01 * (float)v01[j]
                + w10 * (float)v10[j] + w11 * (float)v11[j];
        fs0c[j] = (__bf16)f;
      }
    }
    {
      int eo = q * 8 + 32;
      bf16x8 v00 = *(const bf16x8*)(c00 + eo);
      bf16x8 v01 = *(const bf16x8*)(c01 + eo);
      bf16x8 v10 = *(const bf16x8*)(c10 + eo);
      bf16x8 v11 = *(const bf16x8*)(c11 + eo);
#pragma unroll
      for (int j = 0; j < 8; j++) {
        float f = w00 * (float)v00[j] + w01 * (float)v01[j]
                + w10 * (float)v10[j] + w11 * (float)v11[j];
        fs1c[j] = (__bf16)f;
      }
    }
#pragma unroll
    for (int j = 0; j < 8; j++) {
      float f0 = (float)fs0c[j], f1 = (float)fs1c[j];
      s0s = fmaf(wg_w[q * 8 + j],       f0, fmaf(wg_w[32 + q * 8 + j],  f1, s0s));
      s1s = fmaf(wg_w[128 + q * 8 + j], f0, fmaf(wg_w[160 + q * 8 + j], f1, s1s));
    }
    s0s += __shfl_xor(s0s, 1); s0s += __shfl_xor(s0s, 2);
    s1s += __shfl_xor(s1s, 1); s1s += __shfl_xor(s1s, 2);
  }

  // ---- deformable conv: 9 taps ----
  f32x4 acc[4];
#pragma unroll
  for (int mf = 0; mf < 4; mf++) acc[mf] = (f32x4){0.f, 0.f, 0.f, 0.f};
  const bf16x8* aD = (const bf16x8*)dcnD;

#pragma unroll
  for (int k = 0; k < 9; k++) {
    char* sm = smem + (k & 1) * 2048;
    float sy = (float)(h + k / 3 - 1) + offs[2 * k];
    float sx = (float)(wg + k % 3 - 1) + offs[2 * k + 1];
    const __bf16 *c00, *c01, *c10, *c11;
    float w00, w01, w10, w11;
    bilin_setup(xb, sy, sx, c00, c01, c10, c11, w00, w01, w10, w11);

#pragma unroll
    for (int s = 0; s < 2; s++) {
      int eo = q * 8 + s * 32;
      bf16x8 v00 = *(const bf16x8*)(c00 + eo);
      bf16x8 v01 = *(const bf16x8*)(c01 + eo);
      bf16x8 v10 = *(const bf16x8*)(c10 + eo);
      bf16x8 v11 = *(const bf16x8*)(c11 + eo);
      bf16x8 r;
#pragma unroll
      for (int j = 0; j < 8; j++) {
        float f = w00 * (float)v00[j] + w01 * (float)v01[j]
                + w10 * (float)v10[j] + w11 * (float)v11[j];
        r[j] = (__bf16)f;
      }
      int c = s * 4 + q;
      *(bf16x8*)(sm + pg * 128 + ((c ^ (pg & 7)) * 16)) = r;
    }

#pragma unroll
    for (int s = 0; s < 2; s++) {
      int c = s * 4 + g;
      bf16x8 a = *(const bf16x8*)(sm + l15 * 128 + ((c ^ (l15 & 7)) * 16));
      acc[0] = __builtin_amdgcn_mfma_f32_16x16x32_bf16(
          a, aD[((k * 2 + s) * 4 + 0) * 64 + lane], acc[0], 0, 0, 0);
      acc[1] = __builtin_amdgcn_mfma_f32_16x16x32_bf16(
          a, aD[((k * 2 + s) * 4 + 1) * 64 + lane], acc[1], 0, 0, 0);
      acc[2] = __builtin_amdgcn_mfma_f32_16x16x32_bf16(
          a, aD[((k * 2 + s) * 4 + 2) * 64 + lane], acc[2], 0, 0, 0);
      acc[3] = __builtin_amdgcn_mfma_f32_16x16x32_bf16(
          a, aD[((k * 2 + s) * 4 + 3) * 64 + lane], acc[3], 0, 0, 0);
    }
  }

  // ---- fused epilogue ----
  float fdb_f[4][4];
  float s0d[4] = {0.f, 0.f, 0.f, 0.f};
  float s1d[4] = {0.f, 0.f, 0.f, 0.f};
#pragma unroll
  for (int mf = 0; mf < 4; mf++) {
    int o = mf * 16 + l15;
    float bias = dcn_b[o];
    float w0 = wg_w[64 + o], w1 = wg_w[192 + o];
#pragma unroll
    for (int r = 0; r < 4; r++) {
      __bf16 fb = (__bf16)(acc[mf][r] + bias);
      float fv = (float)fb;
      fdb_f[mf][r] = fv;
      s0d[r] = fmaf(w0, fv, s0d[r]);
      s1d[r] = fmaf(w1, fv, s1d[r]);
    }
  }
#pragma unroll
  for (int m = 1; m < 16; m <<= 1) {
#pragma unroll
    for (int r = 0; r < 4; r++) {
      s0d[r] += __shfl_xor(s0d[r], m);
      s1d[r] += __shfl_xor(s1d[r], m);
    }
  }

  float p0v0, p0v1, p0v2, p0v3;
  {
    float ss0, ss1, S0, S1;
    ss0 = __shfl(s0s, (g * 4 + 0) * 4); ss1 = __shfl(s1s, (g * 4 + 0) * 4);
    S0 = ss0 + s0d[0] + wg_b[0]; S1 = ss1 + s1d[0] + wg_b[1];
    p0v0 = 1.f / (1.f + __expf(S1 - S0));
    ss0 = __shfl(s0s, (g * 4 + 1) * 4); ss1 = __shfl(s1s, (g * 4 + 1) * 4);
    S0 = ss0 + s0d[1] + wg_b[0]; S1 = ss1 + s1d[1] + wg_b[1];
    p0v1 = 1.f / (1.f + __expf(S1 - S0));
    ss0 = __shfl(s0s, (g * 4 + 2) * 4); ss1 = __shfl(s1s, (g * 4 + 2) * 4);
    S0 = ss0 + s0d[2] + wg_b[0]; S1 = ss1 + s1d[2] + wg_b[1];
    p0v2 = 1.f / (1.f + __expf(S1 - S0));
    ss0 = __shfl(s0s, (g * 4 + 3) * 4); ss1 = __shfl(s1s, (g * 4 + 3) * 4);
    S0 = ss0 + s0d[3] + wg_b[0]; S1 = ss1 + s1d[3] + wg_b[1];
    p0v3 = 1.f / (1.f + __expf(S1 - S0));
  }

  // fd -> LDS [ch64][stride 20] bf16 (2560B @ smem); p0 -> smem+2816
  __bf16* fdb16 = (__bf16*)smem;
#pragma unroll
  for (int mf = 0; mf < 4; mf++) {
    bf16x4 v;
#pragma unroll
    for (int r = 0; r < 4; r++) v[r] = (__bf16)fdb_f[mf][r];
    *(bf16x4*)(fdb16 + (mf * 16 + l15) * 20 + g * 4) = v;
  }
  float* p0b = (float*)(smem + 2816);
  if (l15 == 0) p0b[g * 4 + 0] = p0v0;
  if (l15 == 1) p0b[g * 4 + 1] = p0v1;
  if (l15 == 2) p0b[g * 4 + 2] = p0v2;
  if (l15 == 3) p0b[g * 4 + 3] = p0v3;

  float p0 = p0b[pg];
  float p1 = 1.f - p0;

  bf16x8 o0, o1;
#pragma unroll
  for (int j = 0; j < 8; j++) {
    float fd0 = (float)fdb16[(q * 8 + j) * 20 + pg];
    float fd1 = (float)fdb16[(32 + q * 8 + j) * 20 + pg];
    o0[j] = (__bf16)(p0 * (float)fs0c[j] + p1 * fd0);
    o1[j] = (__bf16)(p0 * (float)fs1c[j] + p1 * fd1);
  }
  size_t ppix = (size_t)((h + 2) * 132 + wg + 2) * 8;
  *(bf16x8*)(fusedT + ((size_t)b * 8 + q) * FPL + ppix) = o0;
  *(bf16x8*)(fusedT + ((size_t)b * 8 + 4 + q) * FPL + ppix) = o1;
}

// ---------------------------------------------------------------------------
// K8: collapsed ELK via MFMA, planar fusedT reads (unchanged).
// ---------------------------------------------------------------------------
__global__ __launch_bounds__(256) void k_elkm(
    const __bf16* __restrict__ fusedT, const __bf16* __restrict__ weffD,
    const float* __restrict__ beff, float* __restrict__ out)
{
  const int DY[13] = {-2,-1,-1,-1, 0, 0, 0, 0, 0, 1, 1, 1, 2};
  const int DX[13] = { 0,-1, 0, 1,-2,-1, 0, 1, 2,-1, 0, 1, 0};
  const int lane = threadIdx.x & 63;
  const int wv   = threadIdx.x >> 6;
  const int swz  = xcd_swz(blockIdx.x, 64);
  const int b    = swz >> 6;
  const int h    = (swz & 63) * 2 + (wv >> 1);
  const int half = wv & 1;
  const int l15  = lane & 15;
  const int g    = lane >> 4;

  f32x4 acc[4][4];
#pragma unroll
  for (int mf = 0; mf < 4; mf++)
#pragma unroll
    for (int nf = 0; nf < 4; nf++) acc[mf][nf] = (f32x4){0.f, 0.f, 0.f, 0.f};

  const bf16x8* aD = (const bf16x8*)weffD;
  const __bf16* pl0 = fusedT + ((size_t)b * 8 + g) * FPL;
  const __bf16* pl1 = pl0 + 4 * FPL;

  for (int t = 0; t < 13; t++) {
    int hp = h + 2 + DY[t];
    size_t rowb = (size_t)(hp * 132 + half * 64 + 2 + DX[t] + l15) * 8;
#pragma unroll
    for (int s = 0; s < 2; s++) {
      const __bf16* pl = s ? pl1 : pl0;
      bf16x8 a0 = aD[((t * 2 + s) * 4 + 0) * 64 + lane];
      bf16x8 a1 = aD[((t * 2 + s) * 4 + 1) * 64 + lane];
      bf16x8 a2 = aD[((t * 2 + s) * 4 + 2) * 64 + lane];
      bf16x8 a3 = aD[((t * 2 + s) * 4 + 3) * 64 + lane];
#pragma unroll
      for (int nf = 0; nf < 4; nf++) {
        bf16x8 bv = *(const bf16x8*)(pl + rowb + (size_t)nf * 128);
        acc[0][nf] = __builtin_amdgcn_mfma_f32_16x16x32_bf16(a0, bv, acc[0][nf], 0, 0, 0);
        acc[1][nf] = __builtin_amdgcn_mfma_f32_16x16x32_bf16(a1, bv, acc[1][nf], 0, 0, 0);
        acc[2][nf] = __builtin_amdgcn_mfma_f32_16x16x32_bf16(a2, bv, acc[2][nf], 0, 0, 0);
        acc[3][nf] = __builtin_amdgcn_mfma_f32_16x16x32_bf16(a3, bv, acc[3][nf], 0, 0, 0);
      }
    }
  }

#pragma unroll
  for (int mf = 0; mf < 4; mf++) {
    int ob = mf * 16 + (g << 2);
#pragma unroll
    for (int r = 0; r < 4; r++) {
      int o = ob + r;
      float bb = beff[o];
      float* orow = out + ((size_t)(b * 64 + o)) * HWn + h * 128 + half * 64 + l15;
#pragma unroll
      for (int nf = 0; nf < 4; nf++)
        orow[nf * 16] = acc[mf][nf][r] + bb;
    }
  }
}

// ---------------------------------------------------------------------------
// Workspace (FLOAT offsets, sizes verified; unchanged from R16):
// Region A [0, 4,596,736): xT (k_xt .. k_dcnm).
// Region B [4,596,736, 9,536,512): xC (k_xt .. conv1m) -> fusedT (pads zeroed
//   by conv2m's extra blocks; interior by k_dcnm) -> elkm.
// Region C: p1T @11,633,664 (591,872 fl); partial @12,225,536 (8,192 fl).
// Tail: theta @14,323,200 | wfrag @14,323,264 | w2frag @14,373,440 |
//       beff @14,399,040 | dcnD @14,399,104 | weffD @14,417,536.
// ---------------------------------------------------------------------------
extern "C" void kernel_launch(void* const* d_in, const int* in_sizes, int n_in,
                              void* d_out, int out_size, void* d_ws, size_t ws_size,
                              hipStream_t stream)
{
  (void)in_sizes; (void)n_in; (void)out_size; (void)ws_size;
  const float* x      = (const float*)d_in[0];
  const float* offset = (const float*)d_in[1];
  const float* stn_w1 = (const float*)d_in[2];
  const float* stn_b1 = (const float*)d_in[3];
  const float* stn_w2 = (const float*)d_in[4];
  const float* stn_b2 = (const float*)d_in[5];
  const float* fc_w   = (const float*)d_in[6];
  const float* fc_b   = (const float*)d_in[7];
  const float* dcn_w  = (const float*)d_in[8];
  const float* dcn_b  = (const float*)d_in[9];
  const float* wg_w   = (const float*)d_in[10];
  const float* wg_b   = (const float*)d_in[11];
  const float* w3     = (const float*)d_in[12];
  const float* b3     = (const float*)d_in[13];
  const float* w15    = (const float*)d_in[14];
  const float* b15    = (const float*)d_in[15];
  const float* w51    = (const float*)d_in[16];
  const float* b51    = (const float*)d_in[17];
  const float* w1     = (const float*)d_in[18];
  const float* b1     = (const float*)d_in[19];

  float* ws      = (float*)d_ws;
  __bf16* xT     = (__bf16*)ws;
  __bf16* xC     = (__bf16*)(ws + 4596736);
  __bf16* fusedT = (__bf16*)(ws + 4596736);
  __bf16* p1T    = (__bf16*)(ws + 11633664);
  float*  partial= ws + 12225536;
  float*  theta  = ws + 14323200;
  __bf16* wfrag  = (__bf16*)(ws + 14323264);
  __bf16* w2frag = (__bf16*)(ws + 14373440);
  float*  beff   = ws + 14399040;
  __bf16* dcnD   = (__bf16*)(ws + 14399104);
  __bf16* weffD  = (__bf16*)(ws + 14417536);
  float*  out    = (float*)d_out;

  k_wprep <<<1234, 256, 0, stream>>>(stn_w1, dcn_w, w1, w3, w15, w51, stn_w2,
                                     b3, b15, b51, b1,
                                     wfrag, dcnD, weffD, w2frag, beff, p1T);
  k_xt    <<<1124, 256, 0, stream>>>(x, xT, xC);
  k_conv1m<<<512,  256, 0, stream>>>(xC, wfrag, stn_b1, p1T);
  k_conv2m<<<388,  256, 0, stream>>>(p1T, w2frag, stn_b2, partial, fusedT);
  k_theta <<<1,    512, 0, stream>>>(partial, fc_w, fc_b, theta);
  k_dcnm  <<<8192, 64,  0, stream>>>(xT, offset, theta, dcnD, dcn_b,
                                     wg_w, wg_b, fusedT);
  k_elkm  <<<512,  256, 0, stream>>>(fusedT, weffD, beff, out);
}

// Round 18
// 165.446 us; speedup vs baseline: 1.1990x; 1.0058x over previous
//
#include <hip/hip_runtime.h>
#include <math.h>

// Problem dims
#define Bn 8
#define Cn 64
#define Hn 128
#define Wn 128
#define HWn 16384

typedef __attribute__((ext_vector_type(8))) __bf16 bf16x8;
typedef __attribute__((ext_vector_type(4))) __bf16 bf16x4;
typedef __attribute__((ext_vector_type(4))) float f32x4;

__device__ __forceinline__ int xcd_swz(int bid, int chunk) {
  return (bid & 7) * chunk + (bid >> 3);
}

// ---------------------------------------------------------------------------
// K-wprep: merged weight prep + p1T pad zeroing.
// ---------------------------------------------------------------------------
__global__ __launch_bounds__(256) void k_wprep(
    const float* __restrict__ stn_w1, const float* __restrict__ dcn_w,
    const float* __restrict__ w1, const float* __restrict__ w3,
    const float* __restrict__ w15, const float* __restrict__ w51,
    const float* __restrict__ stn_w2,
    const float* __restrict__ b3, const float* __restrict__ b15,
    const float* __restrict__ b51, const float* __restrict__ b1,
    __bf16* __restrict__ wfrag, __bf16* __restrict__ dcnD,
    __bf16* __restrict__ weffD, __bf16* __restrict__ w2frag,
    float* __restrict__ beff, __bf16* __restrict__ p1T)
{
  int t = blockIdx.x * 256 + threadIdx.x;
  if (t < 100352) {
    int e = t & 7, l = (t >> 3) & 63, o16 = (t >> 9) & 1, ck = (t >> 10) & 1;
    int tap = t >> 11;
    int o = o16 * 16 + (l & 15), c = ck * 32 + (l >> 4) * 8 + e;
    wfrag[t] = (__bf16)stn_w1[(o * 64 + c) * 49 + tap];
    return;
  }
  t -= 100352;
  if (t < 36864) {
    int e = t & 7, l = (t >> 3) & 63, mf = (t >> 9) & 3, s = (t >> 11) & 1;
    int tap = t >> 12;
    int o = mf * 16 + (l & 15), c = s * 32 + (l >> 4) * 8 + e;
    dcnD[t] = (__bf16)dcn_w[(o * 64 + c) * 9 + tap];
    return;
  }
  t -= 36864;
  if (t < 53248) {
    const int DY[13] = {-2,-1,-1,-1, 0, 0, 0, 0, 0, 1, 1, 1, 2};
    const int DX[13] = { 0,-1, 0, 1,-2,-1, 0, 1, 2,-1, 0, 1, 0};
    int e = t & 7, l = (t >> 3) & 63, mf = (t >> 9) & 3, s = (t >> 11) & 1;
    int tap = t >> 12;
    int o = mf * 16 + (l & 15), c = s * 32 + (l >> 4) * 8 + e;
    int dy = DY[tap], dx = DX[tap];
    float v = 0.f;
    if (dy >= -1 && dy <= 1 && dx >= -1 && dx <= 1) {
      int k3 = (dy + 1) * 3 + (dx + 1);
      for (int m = 0; m < 64; m++) v = fmaf(w1[o * 192 + m], w3[(m * 64 + c) * 9 + k3], v);
    }
    if (dy == 0) {
      int k15 = dx + 2;
      for (int m = 0; m < 64; m++) v = fmaf(w1[o * 192 + 64 + m], w15[(m * 64 + c) * 5 + k15], v);
    }
    if (dx == 0) {
      int k51 = dy + 2;
      for (int m = 0; m < 64; m++) v = fmaf(w1[o * 192 + 128 + m], w51[(m * 64 + c) * 5 + k51], v);
    }
    weffD[t] = (__bf16)v;
    return;
  }
  t -= 53248;
  if (t < 51200) {
    int e = t & 7, l = (t >> 3) & 63, mf = (t >> 9) & 3;
    int tap = t >> 11;
    int o = mf * 16 + (l & 15), c = (l >> 4) * 8 + e;
    w2frag[t] = (__bf16)stn_w2[(o * 32 + c) * 25 + tap];
    return;
  }
  t -= 51200;
  if (t < 64) {
    float s = b1[t];
    for (int m = 0; m < 64; m++) {
      s = fmaf(w1[t * 192 + m],       b3[m],  s);
      s = fmaf(w1[t * 192 + 64 + m],  b15[m], s);
      s = fmaf(w1[t * 192 + 128 + m], b51[m], s);
    }
    beff[t] = s;
    return;
  }
  t -= 64;
  if (t < 73984) {                        // zero all of p1T
    bf16x8 z = {};
    *(bf16x8*)(p1T + (size_t)t * 16) = z;
    *(bf16x8*)(p1T + (size_t)t * 16 + 8) = z;
  }
}

// ---------------------------------------------------------------------------
// K-xt v3 (R17): half selected by BLOCK range (blocks 0..561 = ch 0..31,
// 562..1123 = ch 32..63) so a 4-lane quad covers 4 consecutive pixels of one
// channel-half: x reads become 16B/line/quad (4x fewer TA requests; R11
// quad-coalescing model), xC writes 64B/quad.
// ---------------------------------------------------------------------------
__global__ __launch_bounds__(256) void k_xt(const float* __restrict__ x,
                                            __bf16* __restrict__ xT,
                                            __bf16* __restrict__ xC)
{
  int half = (blockIdx.x >= 562) ? 1 : 0;
  int p = (blockIdx.x - half * 562) * 256 + threadIdx.x;
  if (p >= 8 * 134 * 134) return;
  int wp = p % 134;
  int hp = (p / 134) % 134;
  int b  = p / (134 * 134);
  int h = hp - 3, w = wp - 3;
  bool inb = ((unsigned)h < 128u) && ((unsigned)w < 128u);
  const float* xb = x + (size_t)b * Cn * HWn + (size_t)(half * 32) * HWn + h * 128 + w;

  float v[32];
#pragma unroll
  for (int j = 0; j < 32; j++) v[j] = inb ? xb[(size_t)j * HWn] : 0.f;

  __bf16* dstT = xT + (size_t)p * 64 + half * 32;
#pragma unroll
  for (int g = 0; g < 4; g++) {
    bf16x8 r;
#pragma unroll
    for (int j = 0; j < 8; j++) r[j] = (__bf16)v[g * 8 + j];
    *(bf16x8*)(dstT + g * 8) = r;
    int oct = half * 4 + g;
    *(bf16x8*)(xC + ((((size_t)b * 8 + oct) * 134 + hp) * 144 + wp) * 8) = r;
  }
}

// ---------------------------------------------------------------------------
// K1: STN conv1 via MFMA + fused 2x2 maxpool (unchanged from R16).
// ---------------------------------------------------------------------------
__global__ __launch_bounds__(256) void k_conv1m(
    const __bf16* __restrict__ xC, const __bf16* __restrict__ wfrag,
    const float* __restrict__ b1s, __bf16* __restrict__ p1T)
{
  __shared__ alignas(16) char tile[73728];
  const int lane = threadIdx.x & 63;
  const int wv   = threadIdx.x >> 6;
  const int swz  = xcd_swz(blockIdx.x, 64);
  const int b    = swz >> 6;
  const int h0   = (swz & 63) * 2;
  const int r    = wv >> 1;
  const int hf   = wv & 1;
  const int l15  = lane & 15;

  f32x4 acc[2][4];
#pragma unroll
  for (int o16 = 0; o16 < 2; o16++)
#pragma unroll
    for (int nf = 0; nf < 4; nf++) acc[o16][nf] = (f32x4){0.f, 0.f, 0.f, 0.f};

  const bf16x8* wf = (const bf16x8*)wfrag;
  const char* tb = (const char*)tile;
  const char* xCb = (const char*)xC;

  for (int ck = 0; ck < 2; ck++) {
    for (int i = wv; i < 72; i += 4) {
      int q = i / 18;
      int t = i - q * 18;
      const char* src = xCb
          + (((size_t)(b * 8 + ck * 4 + q) * 134 + h0) * 2304) + t * 1024 + lane * 16;
      char* dst = (char*)tile + i * 1024;
      __builtin_amdgcn_global_load_lds(
          (const __attribute__((address_space(1))) void*)src,
          (__attribute__((address_space(3))) void*)dst, 16, 0, 0);
    }
    __syncthreads();

    for (int tap = 0; tap < 49; tap++) {
      int dy7 = tap / 7;
      int dx7 = tap - dy7 * 7;
      bf16x8 a0 = wf[((tap * 2 + ck) * 2 + 0) * 64 + lane];
      bf16x8 a1 = wf[((tap * 2 + ck) * 2 + 1) * 64 + lane];
      const char* bp = tb + (lane >> 4) * 18432 + (r + dy7) * 2304
                          + (dx7 + hf * 64 + l15) * 16;
#pragma unroll
      for (int nf = 0; nf < 4; nf++) {
        bf16x8 bv = *(const bf16x8*)(bp + nf * 256);
        acc[0][nf] = __builtin_amdgcn_mfma_f32_16x16x32_bf16(a0, bv, acc[0][nf], 0, 0, 0);
        acc[1][nf] = __builtin_amdgcn_mfma_f32_16x16x32_bf16(a1, bv, acc[1][nf], 0, 0, 0);
      }
    }
    __syncthreads();
  }

#pragma unroll
  for (int o16 = 0; o16 < 2; o16++) {
    int ob = o16 * 16 + ((lane >> 4) << 2);
    float bb0 = b1s[ob], bb1 = b1s[ob + 1], bb2 = b1s[ob + 2], bb3 = b1s[ob + 3];
#pragma unroll
    for (int nf = 0; nf < 4; nf++) {
      int px = hf * 64 + nf * 16 + l15;
      bf16x4 rr;
      rr[0] = (__bf16)fmaxf(acc[o16][nf][0] + bb0, 0.f);
      rr[1] = (__bf16)fmaxf(acc[o16][nf][1] + bb1, 0.f);
      rr[2] = (__bf16)fmaxf(acc[o16][nf][2] + bb2, 0.f);
      rr[3] = (__bf16)fmaxf(acc[o16][nf][3] + bb3, 0.f);
      *(bf16x4*)((char*)tile + (size_t)(r * 128 + px) * 64 + ob * 2) = rr;
    }
  }
  __syncthreads();

  {
    int tid = threadIdx.x;
    int wp = tid >> 2, cg = tid & 3;
    const char* base = (const char*)tile;
    bf16x8 v00 = *(const bf16x8*)(base + (size_t)(0 * 128 + 2 * wp) * 64 + cg * 16);
    bf16x8 v01 = *(const bf16x8*)(base + (size_t)(0 * 128 + 2 * wp + 1) * 64 + cg * 16);
    bf16x8 v10 = *(const bf16x8*)(base + (size_t)(1 * 128 + 2 * wp) * 64 + cg * 16);
    bf16x8 v11 = *(const bf16x8*)(base + (size_t)(1 * 128 + 2 * wp + 1) * 64 + cg * 16);
    bf16x8 rr;
#pragma unroll
    for (int j = 0; j < 8; j++) {
      float m = fmaxf(fmaxf((float)v00[j], (float)v01[j]),
                      fmaxf((float)v10[j], (float)v11[j]));
      rr[j] = (__bf16)m;
    }
    int hp = (swz & 63) + 2;
    *(bf16x8*)(p1T + (((size_t)b * 68 + hp) * 68 + wp + 2) * 32 + cg * 8) = rr;
  }
}

// ---------------------------------------------------------------------------
// K3 (R17): conv2 via MFMA + fused feat reduction + ABSORBED fusedT pad
// zeroing (former k_zpad; same dependency point: after conv1m).
// Blocks 0..127: conv2; blocks 128..387: pad zeroing.
// ---------------------------------------------------------------------------
#define FPL ((size_t)132 * 132 * 8)
__global__ __launch_bounds__(256) void k_conv2m(
    const __bf16* __restrict__ p1T, const __bf16* __restrict__ w2frag,
    const float* __restrict__ b2s, float* __restrict__ partial,
    __bf16* __restrict__ fusedT)
{
  if (blockIdx.x >= 128) {                // ---- pad-zero section ----
    int t = (blockIdx.x - 128) * 256 + threadIdx.x;
    if (t >= 66560) return;
    int pp = t % 1040;
    int po = (t / 1040) & 7;
    int b  = t / 8320;
    int row, col;
    if (pp < 528) {
      int rr = pp / 132;
      row = (rr < 2) ? rr : 128 + rr;
      col = pp % 132;
    } else {
      int q2 = pp - 528;
      row = 2 + (q2 >> 2);
      int cs = q2 & 3;
      col = (cs < 2) ? cs : 128 + cs;
    }
    bf16x8 z = {};
    *(bf16x8*)(fusedT + ((size_t)b * 8 + po) * FPL + ((size_t)(row * 132 + col)) * 8) = z;
    return;
  }

  __shared__ alignas(16) char tile[34816];
  __shared__ float sm2[4][16][64];
  const int lane = threadIdx.x & 63;
  const int wv   = threadIdx.x >> 6;
  const int b    = blockIdx.x >> 4;
  const int tl   = blockIdx.x & 15;
  const int h0   = tl * 4;
  const int l15  = lane & 15;

  f32x4 acc[4][4];
#pragma unroll
  for (int mf = 0; mf < 4; mf++)
#pragma unroll
    for (int nf = 0; nf < 4; nf++) acc[mf][nf] = (f32x4){0.f, 0.f, 0.f, 0.f};

  const char* src0 = (const char*)p1T + (((size_t)b * 68 + h0) * 68) * 64;
  for (int i = wv; i < 34; i += 4) {
    __builtin_amdgcn_global_load_lds(
        (const __attribute__((address_space(1))) void*)(src0 + i * 1024 + lane * 16),
        (__attribute__((address_space(3))) void*)((char*)tile + i * 1024), 16, 0, 0);
  }
  __syncthreads();

  const bf16x8* wf = (const bf16x8*)w2frag;
  const char* tb = (const char*)tile;
  for (int tap = 0; tap < 25; tap++) {
    int ky = tap / 5, kx = tap - ky * 5;
    bf16x8 a0 = wf[(tap * 4 + 0) * 64 + lane];
    bf16x8 a1 = wf[(tap * 4 + 1) * 64 + lane];
    bf16x8 a2 = wf[(tap * 4 + 2) * 64 + lane];
    bf16x8 a3 = wf[(tap * 4 + 3) * 64 + lane];
    const char* bp = tb + (((wv + ky) * 68 + kx + l15) * 64) + (lane >> 4) * 16;
#pragma unroll
    for (int nf = 0; nf < 4; nf++) {
      bf16x8 bv = *(const bf16x8*)(bp + nf * 1024);
      acc[0][nf] = __builtin_amdgcn_mfma_f32_16x16x32_bf16(a0, bv, acc[0][nf], 0, 0, 0);
      acc[1][nf] = __builtin_amdgcn_mfma_f32_16x16x32_bf16(a1, bv, acc[1][nf], 0, 0, 0);
      acc[2][nf] = __builtin_amdgcn_mfma_f32_16x16x32_bf16(a2, bv, acc[2][nf], 0, 0, 0);
      acc[3][nf] = __builtin_amdgcn_mfma_f32_16x16x32_bf16(a3, bv, acc[3][nf], 0, 0, 0);
    }
  }

#pragma unroll
  for (int mf = 0; mf < 4; mf++) {
    int ob = mf * 16 + ((lane >> 4) << 2);
#pragma unroll
    for (int rr = 0; rr < 4; rr++) {
      float bb = b2s[ob + rr];
      float s = 0.f;
#pragma unroll
      for (int nf = 0; nf < 4; nf++)
        s += fmaxf(acc[mf][nf][rr] + bb, 0.f);
      sm2[wv][l15][ob + rr] = s;
    }
  }
  __syncthreads();
  if (threadIdx.x < 64) {
    float s = 0.f;
#pragma unroll
    for (int w2 = 0; w2 < 4; w2++)
      for (int l = 0; l < 16; l++) s += sm2[w2][l][threadIdx.x];
    partial[(size_t)(b * 16 + tl) * 64 + threadIdx.x] = s;
  }
}

// ---------------------------------------------------------------------------
// K4: theta.
// ---------------------------------------------------------------------------
__global__ __launch_bounds__(512) void k_theta(
    const float* __restrict__ partial, const float* __restrict__ fc_w,
    const float* __restrict__ fc_b, float* __restrict__ theta)
{
  __shared__ float featL[512];
  int tid = threadIdx.x;
  {
    int b = tid >> 6, co = tid & 63;
    float s = 0.f;
#pragma unroll
    for (int t = 0; t < 16; t++) s += partial[(size_t)(b * 16 + t) * 64 + co];
    featL[tid] = s;
  }
  __syncthreads();
  if (tid < 48) {
    int b = tid / 6, i = tid - b * 6;
    float s = 0.f;
    for (int k = 0; k < 64; k++) s = fmaf(featL[b * 64 + k], fc_w[i * 64 + k], s);
    theta[tid] = fmaf(s, 1.f / 4096.f, fc_b[i]);
  }
}

// ---------------------------------------------------------------------------
// Shared bilinear corner-address helper.
// ---------------------------------------------------------------------------
__device__ __forceinline__ void bilin_setup(
    const __bf16* __restrict__ xb, float sy, float sx,
    const __bf16*& c00, const __bf16*& c01,
    const __bf16*& c10, const __bf16*& c11,
    float& w00, float& w01, float& w10, float& w11)
{
  float y0f = floorf(sy), x0f = floorf(sx);
  float wy1 = sy - y0f, wy0 = 1.f - wy1;
  float wx1 = sx - x0f, wx0 = 1.f - wx1;
  bool vy0 = (y0f >= 0.f) && (y0f <= 127.f);
  bool vy1 = (y0f >= -1.f) && (y0f <= 126.f);
  bool vx0 = (x0f >= 0.f) && (x0f <= 127.f);
  bool vx1 = (x0f >= -1.f) && (x0f <= 126.f);
  int yi0 = (int)fminf(fmaxf(y0f, 0.f), 127.f);
  int yi1 = (int)fminf(fmaxf(y0f + 1.f, 0.f), 127.f);
  int xi0 = (int)fminf(fmaxf(x0f, 0.f), 127.f);
  int xi1 = (int)fminf(fmaxf(x0f + 1.f, 0.f), 127.f);
  w00 = wy0 * wx0 * ((vy0 && vx0) ? 1.f : 0.f);
  w01 = wy0 * wx1 * ((vy0 && vx1) ? 1.f : 0.f);
  w10 = wy1 * wx0 * ((vy1 && vx0) ? 1.f : 0.f);
  w11 = wy1 * wx1 * ((vy1 && vx1) ? 1.f : 0.f);
  c00 = xb + ((size_t)((yi0 + 3) * 134) + xi0 + 3) * 64;
  c01 = xb + ((size_t)((yi0 + 3) * 134) + xi1 + 3) * 64;
  c10 = xb + ((size_t)((yi1 + 3) * 134) + xi0 + 3) * 64;
  c11 = xb + ((size_t)((yi1 + 3) * 134) + xi1 + 3) * 64;
}

// ---------------------------------------------------------------------------
// K6: dcn + STN sample + fused softmax fusion -> fusedT.
// R17: fdb16 re-laid at stride-20 elements (40B rows): read banks
// q*16+j*10+(pg>>1) are <=2-way (free); 8B-aligned writes. Bank conflicts
// 2.36M -> ~1.2M expected.
// ---------------------------------------------------------------------------
__global__ __launch_bounds__(64) void k_dcnm(
    const __bf16* __restrict__ xT, const float* __restrict__ off,
    const float* __restrict__ theta,
    const __bf16* __restrict__ dcnD, const float* __restrict__ dcn_b,
    const float* __restrict__ wg_w, const float* __restrict__ wg_b,
    __bf16* __restrict__ fusedT)
{
  __shared__ alignas(16) char smem[4096];
  const int lane = threadIdx.x;
  const int swz  = xcd_swz(blockIdx.x, 1024);
  const int b    = swz >> 10;
  const int rem  = swz & 1023;
  const int h    = rem >> 3;
  const int px0  = (rem & 7) * 16;
  const int l15  = lane & 15;
  const int g    = lane >> 4;
  const int pg   = lane >> 2;
  const int q    = lane & 3;
  const int wg   = px0 + pg;

  const __bf16* xb = xT + (size_t)b * 134 * 134 * 64;

  const float* ob = off + (size_t)b * 18 * HWn + h * 128 + wg;
  float offs[18];
#pragma unroll
  for (int i = 0; i < 18; i++) offs[i] = ob[(size_t)i * HWn];

  // ---- STN sample: keep in registers, accumulate Fs logit partials ----
  bf16x8 fs0c, fs1c;
  float s0s = 0.f, s1s = 0.f;
  {
    const float* t = theta + b * 6;
    float xn = (float)(2 * wg + 1) * (1.f / 128.f) - 1.f;
    float yn = (float)(2 * h + 1) * (1.f / 128.f) - 1.f;
    float gxv = t[0] * xn + t[1] * yn + t[2];
    float gyv = t[3] * xn + t[4] * yn + t[5];
    float ix = fmaf(gxv, 64.f, 63.5f);
    float iy = fmaf(gyv, 64.f, 63.5f);
    const __bf16 *c00, *c01, *c10, *c11;
    float w00, w01, w10, w11;
    bilin_setup(xb, iy, ix, c00, c01, c10, c11, w00, w01, w10, w11);
    {
      int eo = q * 8;
      bf16x8 v00 = *(const bf16x8*)(c00 + eo);
      bf16x8 v01 = *(const bf16x8*)(c01 + eo);
      bf16x8 v10 = *(const bf16x8*)(c10 + eo);
      bf16x8 v11 = *(const bf16x8*)(c11 + eo);
#pragma unroll
      for (int j = 0; j < 8; j++) {
        float f = w00 * (float)v00[j] + w01 * (float)v01[j]
                + w10 * (float)v10[j] + w11 * (float)v11[j];
        fs0c[j] = (__bf16)f;
      }
    }
    {
      int eo = q * 8 + 32;
      bf16x8 v00 = *(const bf16x8*)(c00 + eo);
      bf16x8 v01 = *(const bf16x8*)(c01 + eo);
      bf16x8 v10 = *(const bf16x8*)(c10 + eo);
      bf16x8 v11 = *(const bf16x8*)(c11 + eo);
#pragma unroll
      for (int j = 0; j < 8; j++) {
        float f = w00 * (float)v00[j] + w01 * (float)v01[j]
                + w10 * (float)v10[j] + w11 * (float)v11[j];
        fs1c[j] = (__bf16)f;
      }
    }
#pragma unroll
    for (int j = 0; j < 8; j++) {
      float f0 = (float)fs0c[j], f1 = (float)fs1c[j];
      s0s = fmaf(wg_w[q * 8 + j],       f0, fmaf(wg_w[32 + q * 8 + j],  f1, s0s));
      s1s = fmaf(wg_w[128 + q * 8 + j], f0, fmaf(wg_w[160 + q * 8 + j], f1, s1s));
    }
    s0s += __shfl_xor(s0s, 1); s0s += __shfl_xor(s0s, 2);
    s1s += __shfl_xor(s1s, 1); s1s += __shfl_xor(s1s, 2);
  }

  // ---- deformable conv: 9 taps ----
  f32x4 acc[4];
#pragma unroll
  for (int mf = 0; mf < 4; mf++) acc[mf] = (f32x4){0.f, 0.f, 0.f, 0.f};
  const bf16x8* aD = (const bf16x8*)dcnD;

#pragma unroll
  for (int k = 0; k < 9; k++) {
    char* sm = smem + (k & 1) * 2048;
    float sy = (float)(h + k / 3 - 1) + offs[2 * k];
    float sx = (float)(wg + k % 3 - 1) + offs[2 * k + 1];
    const __bf16 *c00, *c01, *c10, *c11;
    float w00, w01, w10, w11;
    bilin_setup(xb, sy, sx, c00, c01, c10, c11, w00, w01, w10, w11);

#pragma unroll
    for (int s = 0; s < 2; s++) {
      int eo = q * 8 + s * 32;
      bf16x8 v00 = *(const bf16x8*)(c00 + eo);
      bf16x8 v01 = *(const bf16x8*)(c01 + eo);
      bf16x8 v10 = *(const bf16x8*)(c10 + eo);
      bf16x8 v11 = *(const bf16x8*)(c11 + eo);
      bf16x8 r;
#pragma unroll
      for (int j = 0; j < 8; j++) {
        float f = w00 * (float)v00[j] + w01 * (float)v01[j]
                + w10 * (float)v10[j] + w11 * (float)v11[j];
        r[j] = (__bf16)f;
      }
      int c = s * 4 + q;
      *(bf16x8*)(sm + pg * 128 + ((c ^ (pg & 7)) * 16)) = r;
    }

#pragma unroll
    for (int s = 0; s < 2; s++) {
      int c = s * 4 + g;
      bf16x8 a = *(const bf16x8*)(sm + l15 * 128 + ((c ^ (l15 & 7)) * 16));
      acc[0] = __builtin_amdgcn_mfma_f32_16x16x32_bf16(
          a, aD[((k * 2 + s) * 4 + 0) * 64 + lane], acc[0], 0, 0, 0);
      acc[1] = __builtin_amdgcn_mfma_f32_16x16x32_bf16(
          a, aD[((k * 2 + s) * 4 + 1) * 64 + lane], acc[1], 0, 0, 0);
      acc[2] = __builtin_amdgcn_mfma_f32_16x16x32_bf16(
          a, aD[((k * 2 + s) * 4 + 2) * 64 + lane], acc[2], 0, 0, 0);
      acc[3] = __builtin_amdgcn_mfma_f32_16x16x32_bf16(
          a, aD[((k * 2 + s) * 4 + 3) * 64 + lane], acc[3], 0, 0, 0);
    }
  }

  // ---- fused epilogue ----
  float fdb_f[4][4];
  float s0d[4] = {0.f, 0.f, 0.f, 0.f};
  float s1d[4] = {0.f, 0.f, 0.f, 0.f};
#pragma unroll
  for (int mf = 0; mf < 4; mf++) {
    int o = mf * 16 + l15;
    float bias = dcn_b[o];
    float w0 = wg_w[64 + o], w1 = wg_w[192 + o];
#pragma unroll
    for (int r = 0; r < 4; r++) {
      __bf16 fb = (__bf16)(acc[mf][r] + bias);
      float fv = (float)fb;
      fdb_f[mf][r] = fv;
      s0d[r] = fmaf(w0, fv, s0d[r]);
      s1d[r] = fmaf(w1, fv, s1d[r]);
    }
  }
#pragma unroll
  for (int m = 1; m < 16; m <<= 1) {
#pragma unroll
    for (int r = 0; r < 4; r++) {
      s0d[r] += __shfl_xor(s0d[r], m);
      s1d[r] += __shfl_xor(s1d[r], m);
    }
  }

  float p0v0, p0v1, p0v2, p0v3;
  {
    float ss0, ss1, S0, S1;
    ss0 = __shfl(s0s, (g * 4 + 0) * 4); ss1 = __shfl(s1s, (g * 4 + 0) * 4);
    S0 = ss0 + s0d[0] + wg_b[0]; S1 = ss1 + s1d[0] + wg_b[1];
    p0v0 = 1.f / (1.f + __expf(S1 - S0));
    ss0 = __shfl(s0s, (g * 4 + 1) * 4); ss1 = __shfl(s1s, (g * 4 + 1) * 4);
    S0 = ss0 + s0d[1] + wg_b[0]; S1 = ss1 + s1d[1] + wg_b[1];
    p0v1 = 1.f / (1.f + __expf(S1 - S0));
    ss0 = __shfl(s0s, (g * 4 + 2) * 4); ss1 = __shfl(s1s, (g * 4 + 2) * 4);
    S0 = ss0 + s0d[2] + wg_b[0]; S1 = ss1 + s1d[2] + wg_b[1];
    p0v2 = 1.f / (1.f + __expf(S1 - S0));
    ss0 = __shfl(s0s, (g * 4 + 3) * 4); ss1 = __shfl(s1s, (g * 4 + 3) * 4);
    S0 = ss0 + s0d[3] + wg_b[0]; S1 = ss1 + s1d[3] + wg_b[1];
    p0v3 = 1.f / (1.f + __expf(S1 - S0));
  }

  // fd -> LDS [ch64][stride 20] bf16 (2560B @ smem); p0 -> smem+2816
  __bf16* fdb16 = (__bf16*)smem;
#pragma unroll
  for (int mf = 0; mf < 4; mf++) {
    bf16x4 v;
#pragma unroll
    for (int r = 0; r < 4; r++) v[r] = (__bf16)fdb_f[mf][r];
    *(bf16x4*)(fdb16 + (mf * 16 + l15) * 20 + g * 4) = v;
  }
  float* p0b = (float*)(smem + 2816);
  if (l15 == 0) p0b[g * 4 + 0] = p0v0;
  if (l15 == 1) p0b[g * 4 + 1] = p0v1;
  if (l15 == 2) p0b[g * 4 + 2] = p0v2;
  if (l15 == 3) p0b[g * 4 + 3] = p0v3;

  float p0 = p0b[pg];
  float p1 = 1.f - p0;

  bf16x8 o0, o1;
#pragma unroll
  for (int j = 0; j < 8; j++) {
    float fd0 = (float)fdb16[(q * 8 + j) * 20 + pg];
    float fd1 = (float)fdb16[(32 + q * 8 + j) * 20 + pg];
    o0[j] = (__bf16)(p0 * (float)fs0c[j] + p1 * fd0);
    o1[j] = (__bf16)(p0 * (float)fs1c[j] + p1 * fd1);
  }
  size_t ppix = (size_t)((h + 2) * 132 + wg + 2) * 8;
  *(bf16x8*)(fusedT + ((size_t)b * 8 + q) * FPL + ppix) = o0;
  *(bf16x8*)(fusedT + ((size_t)b * 8 + 4 + q) * FPL + ppix) = o1;
}

// ---------------------------------------------------------------------------
// K8: collapsed ELK via MFMA, planar fusedT reads (unchanged).
// ---------------------------------------------------------------------------
__global__ __launch_bounds__(256) void k_elkm(
    const __bf16* __restrict__ fusedT, const __bf16* __restrict__ weffD,
    const float* __restrict__ beff, float* __restrict__ out)
{
  const int DY[13] = {-2,-1,-1,-1, 0, 0, 0, 0, 0, 1, 1, 1, 2};
  const int DX[13] = { 0,-1, 0, 1,-2,-1, 0, 1, 2,-1, 0, 1, 0};
  const int lane = threadIdx.x & 63;
  const int wv   = threadIdx.x >> 6;
  const int swz  = xcd_swz(blockIdx.x, 64);
  const int b    = swz >> 6;
  const int h    = (swz & 63) * 2 + (wv >> 1);
  const int half = wv & 1;
  const int l15  = lane & 15;
  const int g    = lane >> 4;

  f32x4 acc[4][4];
#pragma unroll
  for (int mf = 0; mf < 4; mf++)
#pragma unroll
    for (int nf = 0; nf < 4; nf++) acc[mf][nf] = (f32x4){0.f, 0.f, 0.f, 0.f};

  const bf16x8* aD = (const bf16x8*)weffD;
  const __bf16* pl0 = fusedT + ((size_t)b * 8 + g) * FPL;
  const __bf16* pl1 = pl0 + 4 * FPL;

  for (int t = 0; t < 13; t++) {
    int hp = h + 2 + DY[t];
    size_t rowb = (size_t)(hp * 132 + half * 64 + 2 + DX[t] + l15) * 8;
#pragma unroll
    for (int s = 0; s < 2; s++) {
      const __bf16* pl = s ? pl1 : pl0;
      bf16x8 a0 = aD[((t * 2 + s) * 4 + 0) * 64 + lane];
      bf16x8 a1 = aD[((t * 2 + s) * 4 + 1) * 64 + lane];
      bf16x8 a2 = aD[((t * 2 + s) * 4 + 2) * 64 + lane];
      bf16x8 a3 = aD[((t * 2 + s) * 4 + 3) * 64 + lane];
#pragma unroll
      for (int nf = 0; nf < 4; nf++) {
        bf16x8 bv = *(const bf16x8*)(pl + rowb + (size_t)nf * 128);
        acc[0][nf] = __builtin_amdgcn_mfma_f32_16x16x32_bf16(a0, bv, acc[0][nf], 0, 0, 0);
        acc[1][nf] = __builtin_amdgcn_mfma_f32_16x16x32_bf16(a1, bv, acc[1][nf], 0, 0, 0);
        acc[2][nf] = __builtin_amdgcn_mfma_f32_16x16x32_bf16(a2, bv, acc[2][nf], 0, 0, 0);
        acc[3][nf] = __builtin_amdgcn_mfma_f32_16x16x32_bf16(a3, bv, acc[3][nf], 0, 0, 0);
      }
    }
  }

#pragma unroll
  for (int mf = 0; mf < 4; mf++) {
    int ob = mf * 16 + (g << 2);
#pragma unroll
    for (int r = 0; r < 4; r++) {
      int o = ob + r;
      float bb = beff[o];
      float* orow = out + ((size_t)(b * 64 + o)) * HWn + h * 128 + half * 64 + l15;
#pragma unroll
      for (int nf = 0; nf < 4; nf++)
        orow[nf * 16] = acc[mf][nf][r] + bb;
    }
  }
}

// ---------------------------------------------------------------------------
// Workspace (FLOAT offsets, sizes verified; unchanged from R16):
// Region A [0, 4,596,736): xT (k_xt .. k_dcnm).
// Region B [4,596,736, 9,536,512): xC (k_xt .. conv1m) -> fusedT (pads zeroed
//   by conv2m's extra blocks; interior by k_dcnm) -> elkm.
// Region C: p1T @11,633,664 (591,872 fl); partial @12,225,536 (8,192 fl).
// Tail: theta @14,323,200 | wfrag @14,323,264 | w2frag @14,373,440 |
//       beff @14,399,040 | dcnD @14,399,104 | weffD @14,417,536.
// ---------------------------------------------------------------------------
extern "C" void kernel_launch(void* const* d_in, const int* in_sizes, int n_in,
                              void* d_out, int out_size, void* d_ws, size_t ws_size,
                              hipStream_t stream)
{
  (void)in_sizes; (void)n_in; (void)out_size; (void)ws_size;
  const float* x      = (const float*)d_in[0];
  const float* offset = (const float*)d_in[1];
  const float* stn_w1 = (const float*)d_in[2];
  const float* stn_b1 = (const float*)d_in[3];
  const float* stn_w2 = (const float*)d_in[4];
  const float* stn_b2 = (const float*)d_in[5];
  const float* fc_w   = (const float*)d_in[6];
  const float* fc_b   = (const float*)d_in[7];
  const float* dcn_w  = (const float*)d_in[8];
  const float* dcn_b  = (const float*)d_in[9];
  const float* wg_w   = (const float*)d_in[10];
  const float* wg_b   = (const float*)d_in[11];
  const float* w3     = (const float*)d_in[12];
  const float* b3     = (const float*)d_in[13];
  const float* w15    = (const float*)d_in[14];
  const float* b15    = (const float*)d_in[15];
  const float* w51    = (const float*)d_in[16];
  const float* b51    = (const float*)d_in[17];
  const float* w1     = (const float*)d_in[18];
  const float* b1     = (const float*)d_in[19];

  float* ws      = (float*)d_ws;
  __bf16* xT     = (__bf16*)ws;
  __bf16* xC     = (__bf16*)(ws + 4596736);
  __bf16* fusedT = (__bf16*)(ws + 4596736);
  __bf16* p1T    = (__bf16*)(ws + 11633664);
  float*  partial= ws + 12225536;
  float*  theta  = ws + 14323200;
  __bf16* wfrag  = (__bf16*)(ws + 14323264);
  __bf16* w2frag = (__bf16*)(ws + 14373440);
  float*  beff   = ws + 14399040;
  __bf16* dcnD   = (__bf16*)(ws + 14399104);
  __bf16* weffD  = (__bf16*)(ws + 14417536);
  float*  out    = (float*)d_out;

  k_wprep <<<1234, 256, 0, stream>>>(stn_w1, dcn_w, w1, w3, w15, w51, stn_w2,
                                     b3, b15, b51, b1,
                                     wfrag, dcnD, weffD, w2frag, beff, p1T);
  k_xt    <<<1124, 256, 0, stream>>>(x, xT, xC);
  k_conv1m<<<512,  256, 0, stream>>>(xC, wfrag, stn_b1, p1T);
  k_conv2m<<<388,  256, 0, stream>>>(p1T, w2frag, stn_b2, partial, fusedT);
  k_theta <<<1,    512, 0, stream>>>(partial, fc_w, fc_b, theta);
  k_dcnm  <<<8192, 64,  0, stream>>>(xT, offset, theta, dcnD, dcn_b,
                                     wg_w, wg_b, fusedT);
  k_elkm  <<<512,  256, 0, stream>>>(fusedT, weffD, beff, out);
}

// Round 19
// 164.455 us; speedup vs baseline: 1.2063x; 1.0060x over previous
//
#include <hip/hip_runtime.h>
#include <math.h>

// Problem dims
#define Bn 8
#define Cn 64
#define Hn 128
#define Wn 128
#define HWn 16384

typedef __attribute__((ext_vector_type(8))) __bf16 bf16x8;
typedef __attribute__((ext_vector_type(4))) __bf16 bf16x4;
typedef __attribute__((ext_vector_type(4))) float f32x4;

__device__ __forceinline__ int xcd_swz(int bid, int chunk) {
  return (bid & 7) * chunk + (bid >> 3);
}

// ---------------------------------------------------------------------------
// K-wprep (R19): weight prep + p1T zero + ABSORBED k_xt (blocks 1234..2357)
// + zeroes the conv2m completion counter.  The xt section runs concurrently
// with the prep sections in one grid (saves a launch + overlaps VALU/memory).
// ---------------------------------------------------------------------------
__global__ __launch_bounds__(256) void k_wprep(
    const float* __restrict__ stn_w1, const float* __restrict__ dcn_w,
    const float* __restrict__ w1, const float* __restrict__ w3,
    const float* __restrict__ w15, const float* __restrict__ w51,
    const float* __restrict__ stn_w2,
    const float* __restrict__ b3, const float* __restrict__ b15,
    const float* __restrict__ b51, const float* __restrict__ b1,
    const float* __restrict__ x,
    __bf16* __restrict__ wfrag, __bf16* __restrict__ dcnD,
    __bf16* __restrict__ weffD, __bf16* __restrict__ w2frag,
    float* __restrict__ beff, __bf16* __restrict__ p1T,
    __bf16* __restrict__ xT, __bf16* __restrict__ xC,
    unsigned* __restrict__ cnt)
{
  if (blockIdx.x >= 1234) {               // ---- k_xt section ----
    int xbid = blockIdx.x - 1234;
    int half = (xbid >= 562) ? 1 : 0;
    int p = (xbid - half * 562) * 256 + threadIdx.x;
    if (p >= 8 * 134 * 134) return;
    int wp = p % 134;
    int hp = (p / 134) % 134;
    int b  = p / (134 * 134);
    int h = hp - 3, w = wp - 3;
    bool inb = ((unsigned)h < 128u) && ((unsigned)w < 128u);
    const float* xb = x + (size_t)b * Cn * HWn + (size_t)(half * 32) * HWn + h * 128 + w;
    float v[32];
#pragma unroll
    for (int j = 0; j < 32; j++) v[j] = inb ? xb[(size_t)j * HWn] : 0.f;
    __bf16* dstT = xT + (size_t)p * 64 + half * 32;
#pragma unroll
    for (int g = 0; g < 4; g++) {
      bf16x8 r;
#pragma unroll
      for (int j = 0; j < 8; j++) r[j] = (__bf16)v[g * 8 + j];
      *(bf16x8*)(dstT + g * 8) = r;
      int oct = half * 4 + g;
      *(bf16x8*)(xC + ((((size_t)b * 8 + oct) * 134 + hp) * 144 + wp) * 8) = r;
    }
    return;
  }

  if (blockIdx.x == 0 && threadIdx.x == 0) *cnt = 0u;   // reset counter

  int t = blockIdx.x * 256 + threadIdx.x;
  if (t < 100352) {
    int e = t & 7, l = (t >> 3) & 63, o16 = (t >> 9) & 1, ck = (t >> 10) & 1;
    int tap = t >> 11;
    int o = o16 * 16 + (l & 15), c = ck * 32 + (l >> 4) * 8 + e;
    wfrag[t] = (__bf16)stn_w1[(o * 64 + c) * 49 + tap];
    return;
  }
  t -= 100352;
  if (t < 36864) {
    int e = t & 7, l = (t >> 3) & 63, mf = (t >> 9) & 3, s = (t >> 11) & 1;
    int tap = t >> 12;
    int o = mf * 16 + (l & 15), c = s * 32 + (l >> 4) * 8 + e;
    dcnD[t] = (__bf16)dcn_w[(o * 64 + c) * 9 + tap];
    return;
  }
  t -= 36864;
  if (t < 53248) {
    const int DY[13] = {-2,-1,-1,-1, 0, 0, 0, 0, 0, 1, 1, 1, 2};
    const int DX[13] = { 0,-1, 0, 1,-2,-1, 0, 1, 2,-1, 0, 1, 0};
    int e = t & 7, l = (t >> 3) & 63, mf = (t >> 9) & 3, s = (t >> 11) & 1;
    int tap = t >> 12;
    int o = mf * 16 + (l & 15), c = s * 32 + (l >> 4) * 8 + e;
    int dy = DY[tap], dx = DX[tap];
    float v = 0.f;
    if (dy >= -1 && dy <= 1 && dx >= -1 && dx <= 1) {
      int k3 = (dy + 1) * 3 + (dx + 1);
      for (int m = 0; m < 64; m++) v = fmaf(w1[o * 192 + m], w3[(m * 64 + c) * 9 + k3], v);
    }
    if (dy == 0) {
      int k15 = dx + 2;
      for (int m = 0; m < 64; m++) v = fmaf(w1[o * 192 + 64 + m], w15[(m * 64 + c) * 5 + k15], v);
    }
    if (dx == 0) {
      int k51 = dy + 2;
      for (int m = 0; m < 64; m++) v = fmaf(w1[o * 192 + 128 + m], w51[(m * 64 + c) * 5 + k51], v);
    }
    weffD[t] = (__bf16)v;
    return;
  }
  t -= 53248;
  if (t < 51200) {
    int e = t & 7, l = (t >> 3) & 63, mf = (t >> 9) & 3;
    int tap = t >> 11;
    int o = mf * 16 + (l & 15), c = (l >> 4) * 8 + e;
    w2frag[t] = (__bf16)stn_w2[(o * 32 + c) * 25 + tap];
    return;
  }
  t -= 51200;
  if (t < 64) {
    float s = b1[t];
    for (int m = 0; m < 64; m++) {
      s = fmaf(w1[t * 192 + m],       b3[m],  s);
      s = fmaf(w1[t * 192 + 64 + m],  b15[m], s);
      s = fmaf(w1[t * 192 + 128 + m], b51[m], s);
    }
    beff[t] = s;
    return;
  }
  t -= 64;
  if (t < 73984) {                        // zero all of p1T
    bf16x8 z = {};
    *(bf16x8*)(p1T + (size_t)t * 16) = z;
    *(bf16x8*)(p1T + (size_t)t * 16 + 8) = z;
  }
}

// ---------------------------------------------------------------------------
// K1: STN conv1 via MFMA + fused 2x2 maxpool (unchanged).
// ---------------------------------------------------------------------------
__global__ __launch_bounds__(256) void k_conv1m(
    const __bf16* __restrict__ xC, const __bf16* __restrict__ wfrag,
    const float* __restrict__ b1s, __bf16* __restrict__ p1T)
{
  __shared__ alignas(16) char tile[73728];
  const int lane = threadIdx.x & 63;
  const int wv   = threadIdx.x >> 6;
  const int swz  = xcd_swz(blockIdx.x, 64);
  const int b    = swz >> 6;
  const int h0   = (swz & 63) * 2;
  const int r    = wv >> 1;
  const int hf   = wv & 1;
  const int l15  = lane & 15;

  f32x4 acc[2][4];
#pragma unroll
  for (int o16 = 0; o16 < 2; o16++)
#pragma unroll
    for (int nf = 0; nf < 4; nf++) acc[o16][nf] = (f32x4){0.f, 0.f, 0.f, 0.f};

  const bf16x8* wf = (const bf16x8*)wfrag;
  const char* tb = (const char*)tile;
  const char* xCb = (const char*)xC;

  for (int ck = 0; ck < 2; ck++) {
    for (int i = wv; i < 72; i += 4) {
      int q = i / 18;
      int t = i - q * 18;
      const char* src = xCb
          + (((size_t)(b * 8 + ck * 4 + q) * 134 + h0) * 2304) + t * 1024 + lane * 16;
      char* dst = (char*)tile + i * 1024;
      __builtin_amdgcn_global_load_lds(
          (const __attribute__((address_space(1))) void*)src,
          (__attribute__((address_space(3))) void*)dst, 16, 0, 0);
    }
    __syncthreads();

    for (int tap = 0; tap < 49; tap++) {
      int dy7 = tap / 7;
      int dx7 = tap - dy7 * 7;
      bf16x8 a0 = wf[((tap * 2 + ck) * 2 + 0) * 64 + lane];
      bf16x8 a1 = wf[((tap * 2 + ck) * 2 + 1) * 64 + lane];
      const char* bp = tb + (lane >> 4) * 18432 + (r + dy7) * 2304
                          + (dx7 + hf * 64 + l15) * 16;
#pragma unroll
      for (int nf = 0; nf < 4; nf++) {
        bf16x8 bv = *(const bf16x8*)(bp + nf * 256);
        acc[0][nf] = __builtin_amdgcn_mfma_f32_16x16x32_bf16(a0, bv, acc[0][nf], 0, 0, 0);
        acc[1][nf] = __builtin_amdgcn_mfma_f32_16x16x32_bf16(a1, bv, acc[1][nf], 0, 0, 0);
      }
    }
    __syncthreads();
  }

#pragma unroll
  for (int o16 = 0; o16 < 2; o16++) {
    int ob = o16 * 16 + ((lane >> 4) << 2);
    float bb0 = b1s[ob], bb1 = b1s[ob + 1], bb2 = b1s[ob + 2], bb3 = b1s[ob + 3];
#pragma unroll
    for (int nf = 0; nf < 4; nf++) {
      int px = hf * 64 + nf * 16 + l15;
      bf16x4 rr;
      rr[0] = (__bf16)fmaxf(acc[o16][nf][0] + bb0, 0.f);
      rr[1] = (__bf16)fmaxf(acc[o16][nf][1] + bb1, 0.f);
      rr[2] = (__bf16)fmaxf(acc[o16][nf][2] + bb2, 0.f);
      rr[3] = (__bf16)fmaxf(acc[o16][nf][3] + bb3, 0.f);
      *(bf16x4*)((char*)tile + (size_t)(r * 128 + px) * 64 + ob * 2) = rr;
    }
  }
  __syncthreads();

  {
    int tid = threadIdx.x;
    int wp = tid >> 2, cg = tid & 3;
    const char* base = (const char*)tile;
    bf16x8 v00 = *(const bf16x8*)(base + (size_t)(0 * 128 + 2 * wp) * 64 + cg * 16);
    bf16x8 v01 = *(const bf16x8*)(base + (size_t)(0 * 128 + 2 * wp + 1) * 64 + cg * 16);
    bf16x8 v10 = *(const bf16x8*)(base + (size_t)(1 * 128 + 2 * wp) * 64 + cg * 16);
    bf16x8 v11 = *(const bf16x8*)(base + (size_t)(1 * 128 + 2 * wp + 1) * 64 + cg * 16);
    bf16x8 rr;
#pragma unroll
    for (int j = 0; j < 8; j++) {
      float m = fmaxf(fmaxf((float)v00[j], (float)v01[j]),
                      fmaxf((float)v10[j], (float)v11[j]));
      rr[j] = (__bf16)m;
    }
    int hp = (swz & 63) + 2;
    *(bf16x8*)(p1T + (((size_t)b * 68 + hp) * 68 + wp + 2) * 32 + cg * 8) = rr;
  }
}

// ---------------------------------------------------------------------------
// K3 (R19): conv2 MFMA + feat reduction + pad-zero blocks + LAST-BLOCK THETA.
// Each conv2 block (0..127): partial write -> threadfence -> atomicAdd(cnt).
// The 128th to finish recomputes feat (fixed order => deterministic) + theta,
// eliminating the k_theta launch.
// ---------------------------------------------------------------------------
#define FPL ((size_t)132 * 132 * 8)
__global__ __launch_bounds__(256) void k_conv2m(
    const __bf16* __restrict__ p1T, const __bf16* __restrict__ w2frag,
    const float* __restrict__ b2s, float* __restrict__ partial,
    __bf16* __restrict__ fusedT,
    const float* __restrict__ fc_w, const float* __restrict__ fc_b,
    float* __restrict__ theta, unsigned* __restrict__ cnt)
{
  if (blockIdx.x >= 128) {                // ---- pad-zero section ----
    int t = (blockIdx.x - 128) * 256 + threadIdx.x;
    if (t >= 66560) return;
    int pp = t % 1040;
    int po = (t / 1040) & 7;
    int b  = t / 8320;
    int row, col;
    if (pp < 528) {
      int rr = pp / 132;
      row = (rr < 2) ? rr : 128 + rr;
      col = pp % 132;
    } else {
      int q2 = pp - 528;
      row = 2 + (q2 >> 2);
      int cs = q2 & 3;
      col = (cs < 2) ? cs : 128 + cs;
    }
    bf16x8 z = {};
    *(bf16x8*)(fusedT + ((size_t)b * 8 + po) * FPL + ((size_t)(row * 132 + col)) * 8) = z;
    return;
  }

  __shared__ alignas(16) char tile[34816];
  __shared__ float sm2[4][16][64];
  __shared__ unsigned done;
  const int lane = threadIdx.x & 63;
  const int wv   = threadIdx.x >> 6;
  const int b    = blockIdx.x >> 4;
  const int tl   = blockIdx.x & 15;
  const int h0   = tl * 4;
  const int l15  = lane & 15;

  f32x4 acc[4][4];
#pragma unroll
  for (int mf = 0; mf < 4; mf++)
#pragma unroll
    for (int nf = 0; nf < 4; nf++) acc[mf][nf] = (f32x4){0.f, 0.f, 0.f, 0.f};

  const char* src0 = (const char*)p1T + (((size_t)b * 68 + h0) * 68) * 64;
  for (int i = wv; i < 34; i += 4) {
    __builtin_amdgcn_global_load_lds(
        (const __attribute__((address_space(1))) void*)(src0 + i * 1024 + lane * 16),
        (__attribute__((address_space(3))) void*)((char*)tile + i * 1024), 16, 0, 0);
  }
  __syncthreads();

  const bf16x8* wf = (const bf16x8*)w2frag;
  const char* tb = (const char*)tile;
  for (int tap = 0; tap < 25; tap++) {
    int ky = tap / 5, kx = tap - ky * 5;
    bf16x8 a0 = wf[(tap * 4 + 0) * 64 + lane];
    bf16x8 a1 = wf[(tap * 4 + 1) * 64 + lane];
    bf16x8 a2 = wf[(tap * 4 + 2) * 64 + lane];
    bf16x8 a3 = wf[(tap * 4 + 3) * 64 + lane];
    const char* bp = tb + (((wv + ky) * 68 + kx + l15) * 64) + (lane >> 4) * 16;
#pragma unroll
    for (int nf = 0; nf < 4; nf++) {
      bf16x8 bv = *(const bf16x8*)(bp + nf * 1024);
      acc[0][nf] = __builtin_amdgcn_mfma_f32_16x16x32_bf16(a0, bv, acc[0][nf], 0, 0, 0);
      acc[1][nf] = __builtin_amdgcn_mfma_f32_16x16x32_bf16(a1, bv, acc[1][nf], 0, 0, 0);
      acc[2][nf] = __builtin_amdgcn_mfma_f32_16x16x32_bf16(a2, bv, acc[2][nf], 0, 0, 0);
      acc[3][nf] = __builtin_amdgcn_mfma_f32_16x16x32_bf16(a3, bv, acc[3][nf], 0, 0, 0);
    }
  }

#pragma unroll
  for (int mf = 0; mf < 4; mf++) {
    int ob = mf * 16 + ((lane >> 4) << 2);
#pragma unroll
    for (int rr = 0; rr < 4; rr++) {
      float bb = b2s[ob + rr];
      float s = 0.f;
#pragma unroll
      for (int nf = 0; nf < 4; nf++)
        s += fmaxf(acc[mf][nf][rr] + bb, 0.f);
      sm2[wv][l15][ob + rr] = s;
    }
  }
  __syncthreads();
  if (threadIdx.x < 64) {
    float s = 0.f;
#pragma unroll
    for (int w2 = 0; w2 < 4; w2++)
      for (int l = 0; l < 16; l++) s += sm2[w2][l][threadIdx.x];
    partial[(size_t)(b * 16 + tl) * 64 + threadIdx.x] = s;
  }

  // ---- last-block theta ----
  __threadfence();
  if (threadIdx.x == 0) done = atomicAdd(cnt, 1u);
  __syncthreads();
  if (done == 127u) {
    __threadfence();
    float* featL = (float*)sm2;          // reuse (needs 2KB)
    for (int i = threadIdx.x; i < 512; i += 256) {
      int bb = i >> 6, co = i & 63;
      float s = 0.f;
#pragma unroll
      for (int t16 = 0; t16 < 16; t16++)
        s += partial[(size_t)(bb * 16 + t16) * 64 + co];
      featL[i] = s;
    }
    __syncthreads();
    if (threadIdx.x < 48) {
      int bb = threadIdx.x / 6, i = threadIdx.x - bb * 6;
      float s = 0.f;
      for (int k = 0; k < 64; k++) s = fmaf(featL[bb * 64 + k], fc_w[i * 64 + k], s);
      theta[threadIdx.x] = fmaf(s, 1.f / 4096.f, fc_b[i]);
    }
  }
}

// ---------------------------------------------------------------------------
// Shared bilinear corner-address helper.
// ---------------------------------------------------------------------------
__device__ __forceinline__ void bilin_setup(
    const __bf16* __restrict__ xb, float sy, float sx,
    const __bf16*& c00, const __bf16*& c01,
    const __bf16*& c10, const __bf16*& c11,
    float& w00, float& w01, float& w10, float& w11)
{
  float y0f = floorf(sy), x0f = floorf(sx);
  float wy1 = sy - y0f, wy0 = 1.f - wy1;
  float wx1 = sx - x0f, wx0 = 1.f - wx1;
  bool vy0 = (y0f >= 0.f) && (y0f <= 127.f);
  bool vy1 = (y0f >= -1.f) && (y0f <= 126.f);
  bool vx0 = (x0f >= 0.f) && (x0f <= 127.f);
  bool vx1 = (x0f >= -1.f) && (x0f <= 126.f);
  int yi0 = (int)fminf(fmaxf(y0f, 0.f), 127.f);
  int yi1 = (int)fminf(fmaxf(y0f + 1.f, 0.f), 127.f);
  int xi0 = (int)fminf(fmaxf(x0f, 0.f), 127.f);
  int xi1 = (int)fminf(fmaxf(x0f + 1.f, 0.f), 127.f);
  w00 = wy0 * wx0 * ((vy0 && vx0) ? 1.f : 0.f);
  w01 = wy0 * wx1 * ((vy0 && vx1) ? 1.f : 0.f);
  w10 = wy1 * wx0 * ((vy1 && vx0) ? 1.f : 0.f);
  w11 = wy1 * wx1 * ((vy1 && vx1) ? 1.f : 0.f);
  c00 = xb + ((size_t)((yi0 + 3) * 134) + xi0 + 3) * 64;
  c01 = xb + ((size_t)((yi0 + 3) * 134) + xi1 + 3) * 64;
  c10 = xb + ((size_t)((yi1 + 3) * 134) + xi0 + 3) * 64;
  c11 = xb + ((size_t)((yi1 + 3) * 134) + xi1 + 3) * 64;
}

// ---------------------------------------------------------------------------
// K6: dcn + STN sample + fused softmax fusion -> fusedT (unchanged from R18).
// ---------------------------------------------------------------------------
__global__ __launch_bounds__(64) void k_dcnm(
    const __bf16* __restrict__ xT, const float* __restrict__ off,
    const float* __restrict__ theta,
    const __bf16* __restrict__ dcnD, const float* __restrict__ dcn_b,
    const float* __restrict__ wg_w, const float* __restrict__ wg_b,
    __bf16* __restrict__ fusedT)
{
  __shared__ alignas(16) char smem[4096];
  const int lane = threadIdx.x;
  const int swz  = xcd_swz(blockIdx.x, 1024);
  const int b    = swz >> 10;
  const int rem  = swz & 1023;
  const int h    = rem >> 3;
  const int px0  = (rem & 7) * 16;
  const int l15  = lane & 15;
  const int g    = lane >> 4;
  const int pg   = lane >> 2;
  const int q    = lane & 3;
  const int wg   = px0 + pg;

  const __bf16* xb = xT + (size_t)b * 134 * 134 * 64;

  const float* ob = off + (size_t)b * 18 * HWn + h * 128 + wg;
  float offs[18];
#pragma unroll
  for (int i = 0; i < 18; i++) offs[i] = ob[(size_t)i * HWn];

  bf16x8 fs0c, fs1c;
  float s0s = 0.f, s1s = 0.f;
  {
    const float* t = theta + b * 6;
    float xn = (float)(2 * wg + 1) * (1.f / 128.f) - 1.f;
    float yn = (float)(2 * h + 1) * (1.f / 128.f) - 1.f;
    float gxv = t[0] * xn + t[1] * yn + t[2];
    float gyv = t[3] * xn + t[4] * yn + t[5];
    float ix = fmaf(gxv, 64.f, 63.5f);
    float iy = fmaf(gyv, 64.f, 63.5f);
    const __bf16 *c00, *c01, *c10, *c11;
    float w00, w01, w10, w11;
    bilin_setup(xb, iy, ix, c00, c01, c10, c11, w00, w01, w10, w11);
    {
      int eo = q * 8;
      bf16x8 v00 = *(const bf16x8*)(c00 + eo);
      bf16x8 v01 = *(const bf16x8*)(c01 + eo);
      bf16x8 v10 = *(const bf16x8*)(c10 + eo);
      bf16x8 v11 = *(const bf16x8*)(c11 + eo);
#pragma unroll
      for (int j = 0; j < 8; j++) {
        float f = w00 * (float)v00[j] + w01 * (float)v01[j]
                + w10 * (float)v10[j] + w11 * (float)v11[j];
        fs0c[j] = (__bf16)f;
      }
    }
    {
      int eo = q * 8 + 32;
      bf16x8 v00 = *(const bf16x8*)(c00 + eo);
      bf16x8 v01 = *(const bf16x8*)(c01 + eo);
      bf16x8 v10 = *(const bf16x8*)(c10 + eo);
      bf16x8 v11 = *(const bf16x8*)(c11 + eo);
#pragma unroll
      for (int j = 0; j < 8; j++) {
        float f = w00 * (float)v00[j] + w01 * (float)v01[j]
                + w10 * (float)v10[j] + w11 * (float)v11[j];
        fs1c[j] = (__bf16)f;
      }
    }
#pragma unroll
    for (int j = 0; j < 8; j++) {
      float f0 = (float)fs0c[j], f1 = (float)fs1c[j];
      s0s = fmaf(wg_w[q * 8 + j],       f0, fmaf(wg_w[32 + q * 8 + j],  f1, s0s));
      s1s = fmaf(wg_w[128 + q * 8 + j], f0, fmaf(wg_w[160 + q * 8 + j], f1, s1s));
    }
    s0s += __shfl_xor(s0s, 1); s0s += __shfl_xor(s0s, 2);
    s1s += __shfl_xor(s1s, 1); s1s += __shfl_xor(s1s, 2);
  }

  f32x4 acc[4];
#pragma unroll
  for (int mf = 0; mf < 4; mf++) acc[mf] = (f32x4){0.f, 0.f, 0.f, 0.f};
  const bf16x8* aD = (const bf16x8*)dcnD;

#pragma unroll
  for (int k = 0; k < 9; k++) {
    char* sm = smem + (k & 1) * 2048;
    float sy = (float)(h + k / 3 - 1) + offs[2 * k];
    float sx = (float)(wg + k % 3 - 1) + offs[2 * k + 1];
    const __bf16 *c00, *c01, *c10, *c11;
    float w00, w01, w10, w11;
    bilin_setup(xb, sy, sx, c00, c01, c10, c11, w00, w01, w10, w11);

#pragma unroll
    for (int s = 0; s < 2; s++) {
      int eo = q * 8 + s * 32;
      bf16x8 v00 = *(const bf16x8*)(c00 + eo);
      bf16x8 v01 = *(const bf16x8*)(c01 + eo);
      bf16x8 v10 = *(const bf16x8*)(c10 + eo);
      bf16x8 v11 = *(const bf16x8*)(c11 + eo);
      bf16x8 r;
#pragma unroll
      for (int j = 0; j < 8; j++) {
        float f = w00 * (float)v00[j] + w01 * (float)v01[j]
                + w10 * (float)v10[j] + w11 * (float)v11[j];
        r[j] = (__bf16)f;
      }
      int c = s * 4 + q;
      *(bf16x8*)(sm + pg * 128 + ((c ^ (pg & 7)) * 16)) = r;
    }

#pragma unroll
    for (int s = 0; s < 2; s++) {
      int c = s * 4 + g;
      bf16x8 a = *(const bf16x8*)(sm + l15 * 128 + ((c ^ (l15 & 7)) * 16));
      acc[0] = __builtin_amdgcn_mfma_f32_16x16x32_bf16(
          a, aD[((k * 2 + s) * 4 + 0) * 64 + lane], acc[0], 0, 0, 0);
      acc[1] = __builtin_amdgcn_mfma_f32_16x16x32_bf16(
          a, aD[((k * 2 + s) * 4 + 1) * 64 + lane], acc[1], 0, 0, 0);
      acc[2] = __builtin_amdgcn_mfma_f32_16x16x32_bf16(
          a, aD[((k * 2 + s) * 4 + 2) * 64 + lane], acc[2], 0, 0, 0);
      acc[3] = __builtin_amdgcn_mfma_f32_16x16x32_bf16(
          a, aD[((k * 2 + s) * 4 + 3) * 64 + lane], acc[3], 0, 0, 0);
    }
  }

  float fdb_f[4][4];
  float s0d[4] = {0.f, 0.f, 0.f, 0.f};
  float s1d[4] = {0.f, 0.f, 0.f, 0.f};
#pragma unroll
  for (int mf = 0; mf < 4; mf++) {
    int o = mf * 16 + l15;
    float bias = dcn_b[o];
    float w0 = wg_w[64 + o], w1 = wg_w[192 + o];
#pragma unroll
    for (int r = 0; r < 4; r++) {
      __bf16 fb = (__bf16)(acc[mf][r] + bias);
      float fv = (float)fb;
      fdb_f[mf][r] = fv;
      s0d[r] = fmaf(w0, fv, s0d[r]);
      s1d[r] = fmaf(w1, fv, s1d[r]);
    }
  }
#pragma unroll
  for (int m = 1; m < 16; m <<= 1) {
#pragma unroll
    for (int r = 0; r < 4; r++) {
      s0d[r] += __shfl_xor(s0d[r], m);
      s1d[r] += __shfl_xor(s1d[r], m);
    }
  }

  float p0v0, p0v1, p0v2, p0v3;
  {
    float ss0, ss1, S0, S1;
    ss0 = __shfl(s0s, (g * 4 + 0) * 4); ss1 = __shfl(s1s, (g * 4 + 0) * 4);
    S0 = ss0 + s0d[0] + wg_b[0]; S1 = ss1 + s1d[0] + wg_b[1];
    p0v0 = 1.f / (1.f + __expf(S1 - S0));
    ss0 = __shfl(s0s, (g * 4 + 1) * 4); ss1 = __shfl(s1s, (g * 4 + 1) * 4);
    S0 = ss0 + s0d[1] + wg_b[0]; S1 = ss1 + s1d[1] + wg_b[1];
    p0v1 = 1.f / (1.f + __expf(S1 - S0));
    ss0 = __shfl(s0s, (g * 4 + 2) * 4); ss1 = __shfl(s1s, (g * 4 + 2) * 4);
    S0 = ss0 + s0d[2] + wg_b[0]; S1 = ss1 + s1d[2] + wg_b[1];
    p0v2 = 1.f / (1.f + __expf(S1 - S0));
    ss0 = __shfl(s0s, (g * 4 + 3) * 4); ss1 = __shfl(s1s, (g * 4 + 3) * 4);
    S0 = ss0 + s0d[3] + wg_b[0]; S1 = ss1 + s1d[3] + wg_b[1];
    p0v3 = 1.f / (1.f + __expf(S1 - S0));
  }

  __bf16* fdb16 = (__bf16*)smem;
#pragma unroll
  for (int mf = 0; mf < 4; mf++) {
    bf16x4 v;
#pragma unroll
    for (int r = 0; r < 4; r++) v[r] = (__bf16)fdb_f[mf][r];
    *(bf16x4*)(fdb16 + (mf * 16 + l15) * 20 + g * 4) = v;
  }
  float* p0b = (float*)(smem + 2816);
  if (l15 == 0) p0b[g * 4 + 0] = p0v0;
  if (l15 == 1) p0b[g * 4 + 1] = p0v1;
  if (l15 == 2) p0b[g * 4 + 2] = p0v2;
  if (l15 == 3) p0b[g * 4 + 3] = p0v3;

  float p0 = p0b[pg];
  float p1 = 1.f - p0;

  bf16x8 o0, o1;
#pragma unroll
  for (int j = 0; j < 8; j++) {
    float fd0 = (float)fdb16[(q * 8 + j) * 20 + pg];
    float fd1 = (float)fdb16[(32 + q * 8 + j) * 20 + pg];
    o0[j] = (__bf16)(p0 * (float)fs0c[j] + p1 * fd0);
    o1[j] = (__bf16)(p0 * (float)fs1c[j] + p1 * fd1);
  }
  size_t ppix = (size_t)((h + 2) * 132 + wg + 2) * 8;
  *(bf16x8*)(fusedT + ((size_t)b * 8 + q) * FPL + ppix) = o0;
  *(bf16x8*)(fusedT + ((size_t)b * 8 + 4 + q) * FPL + ppix) = o1;
}

// ---------------------------------------------------------------------------
// K8: collapsed ELK via MFMA, planar fusedT reads (unchanged).
// ---------------------------------------------------------------------------
__global__ __launch_bounds__(256) void k_elkm(
    const __bf16* __restrict__ fusedT, const __bf16* __restrict__ weffD,
    const float* __restrict__ beff, float* __restrict__ out)
{
  const int DY[13] = {-2,-1,-1,-1, 0, 0, 0, 0, 0, 1, 1, 1, 2};
  const int DX[13] = { 0,-1, 0, 1,-2,-1, 0, 1, 2,-1, 0, 1, 0};
  const int lane = threadIdx.x & 63;
  const int wv   = threadIdx.x >> 6;
  const int swz  = xcd_swz(blockIdx.x, 64);
  const int b    = swz >> 6;
  const int h    = (swz & 63) * 2 + (wv >> 1);
  const int half = wv & 1;
  const int l15  = lane & 15;
  const int g    = lane >> 4;

  f32x4 acc[4][4];
#pragma unroll
  for (int mf = 0; mf < 4; mf++)
#pragma unroll
    for (int nf = 0; nf < 4; nf++) acc[mf][nf] = (f32x4){0.f, 0.f, 0.f, 0.f};

  const bf16x8* aD = (const bf16x8*)weffD;
  const __bf16* pl0 = fusedT + ((size_t)b * 8 + g) * FPL;
  const __bf16* pl1 = pl0 + 4 * FPL;

  for (int t = 0; t < 13; t++) {
    int hp = h + 2 + DY[t];
    size_t rowb = (size_t)(hp * 132 + half * 64 + 2 + DX[t] + l15) * 8;
#pragma unroll
    for (int s = 0; s < 2; s++) {
      const __bf16* pl = s ? pl1 : pl0;
      bf16x8 a0 = aD[((t * 2 + s) * 4 + 0) * 64 + lane];
      bf16x8 a1 = aD[((t * 2 + s) * 4 + 1) * 64 + lane];
      bf16x8 a2 = aD[((t * 2 + s) * 4 + 2) * 64 + lane];
      bf16x8 a3 = aD[((t * 2 + s) * 4 + 3) * 64 + lane];
#pragma unroll
      for (int nf = 0; nf < 4; nf++) {
        bf16x8 bv = *(const bf16x8*)(pl + rowb + (size_t)nf * 128);
        acc[0][nf] = __builtin_amdgcn_mfma_f32_16x16x32_bf16(a0, bv, acc[0][nf], 0, 0, 0);
        acc[1][nf] = __builtin_amdgcn_mfma_f32_16x16x32_bf16(a1, bv, acc[1][nf], 0, 0, 0);
        acc[2][nf] = __builtin_amdgcn_mfma_f32_16x16x32_bf16(a2, bv, acc[2][nf], 0, 0, 0);
        acc[3][nf] = __builtin_amdgcn_mfma_f32_16x16x32_bf16(a3, bv, acc[3][nf], 0, 0, 0);
      }
    }
  }

#pragma unroll
  for (int mf = 0; mf < 4; mf++) {
    int ob = mf * 16 + (g << 2);
#pragma unroll
    for (int r = 0; r < 4; r++) {
      int o = ob + r;
      float bb = beff[o];
      float* orow = out + ((size_t)(b * 64 + o)) * HWn + h * 128 + half * 64 + l15;
#pragma unroll
      for (int nf = 0; nf < 4; nf++)
        orow[nf * 16] = acc[mf][nf][r] + bb;
    }
  }
}

// ---------------------------------------------------------------------------
// Workspace (FLOAT offsets, sizes verified; R18 layout + cnt):
// Region A [0, 4,596,736): xT (wprep .. k_dcnm).
// Region B [4,596,736, 9,536,512): xC (wprep .. conv1m) -> fusedT -> elkm.
// Region C: p1T @11,633,664 (591,872 fl); partial @12,225,536 (8,192 fl).
// Tail: theta @14,323,200 | wfrag @14,323,264 | w2frag @14,373,440 |
//       beff @14,399,040 | dcnD @14,399,104 | weffD @14,417,536 |
//       cnt @14,444,160 (1 u32).  End 14,444,161 fl = 57.8 MB.
// ---------------------------------------------------------------------------
extern "C" void kernel_launch(void* const* d_in, const int* in_sizes, int n_in,
                              void* d_out, int out_size, void* d_ws, size_t ws_size,
                              hipStream_t stream)
{
  (void)in_sizes; (void)n_in; (void)out_size; (void)ws_size;
  const float* x      = (const float*)d_in[0];
  const float* offset = (const float*)d_in[1];
  const float* stn_w1 = (const float*)d_in[2];
  const float* stn_b1 = (const float*)d_in[3];
  const float* stn_w2 = (const float*)d_in[4];
  const float* stn_b2 = (const float*)d_in[5];
  const float* fc_w   = (const float*)d_in[6];
  const float* fc_b   = (const float*)d_in[7];
  const float* dcn_w  = (const float*)d_in[8];
  const float* dcn_b  = (const float*)d_in[9];
  const float* wg_w   = (const float*)d_in[10];
  const float* wg_b   = (const float*)d_in[11];
  const float* w3     = (const float*)d_in[12];
  const float* b3     = (const float*)d_in[13];
  const float* w15    = (const float*)d_in[14];
  const float* b15    = (const float*)d_in[15];
  const float* w51    = (const float*)d_in[16];
  const float* b51    = (const float*)d_in[17];
  const float* w1     = (const float*)d_in[18];
  const float* b1     = (const float*)d_in[19];

  float* ws      = (float*)d_ws;
  __bf16* xT     = (__bf16*)ws;
  __bf16* xC     = (__bf16*)(ws + 4596736);
  __bf16* fusedT = (__bf16*)(ws + 4596736);
  __bf16* p1T    = (__bf16*)(ws + 11633664);
  float*  partial= ws + 12225536;
  float*  theta  = ws + 14323200;
  __bf16* wfrag  = (__bf16*)(ws + 14323264);
  __bf16* w2frag = (__bf16*)(ws + 14373440);
  float*  beff   = ws + 14399040;
  __bf16* dcnD   = (__bf16*)(ws + 14399104);
  __bf16* weffD  = (__bf16*)(ws + 14417536);
  unsigned* cnt  = (unsigned*)(ws + 14444160);
  float*  out    = (float*)d_out;

  k_wprep <<<2358, 256, 0, stream>>>(stn_w1, dcn_w, w1, w3, w15, w51, stn_w2,
                                     b3, b15, b51, b1, x,
                                     wfrag, dcnD, weffD, w2frag, beff, p1T,
                                     xT, xC, cnt);
  k_conv1m<<<512,  256, 0, stream>>>(xC, wfrag, stn_b1, p1T);
  k_conv2m<<<388,  256, 0, stream>>>(p1T, w2frag, stn_b2, partial, fusedT,
                                     fc_w, fc_b, theta, cnt);
  k_dcnm  <<<8192, 64,  0, stream>>>(xT, offset, theta, dcnD, dcn_b,
                                     wg_w, wg_b, fusedT);
  k_elkm  <<<512,  256, 0, stream>>>(fusedT, weffD, beff, out);
}